// Round 11
// baseline (102.582 us; speedup 1.0000x reference)
//
#include <hip/hip_runtime.h>
#include <math.h>
#include <string.h>

#define HH 2048
#define WW 2048
#define TSC 128
#define TSR 32
#define NBX (WW / TSC)                 // 16
#define NBY (HH / TSR)                 // 64
#define NINT1 ((NBX - 2) * (NBY - 2))  // 868
#define NBND1 (NBX * NBY - NINT1)      // 156

// LDS strides (floats). 4-row lane offset mod 32 banks: LST0: 576=0 (known
// 2-way on A reads, budget-blocked); LST1/LST2: 560=16 -> conflict-free.
#define LST0 144
#define LST1 140
#define LST2 140

struct W3 { float wA[17][5]; float wC[17][5]; float wB[17]; float knA, knB, knC; };
struct Wts { float w[17][5]; float knorm; };   // fallback path

// angle index a: 0 -> -10deg, 1 -> 0deg, 2 -> +10deg
__host__ __device__ constexpr int js_fn(int a, int i) {
  return (a == 1) ? 2
       : (a == 2) ? ((i < 3) ? 0 : (i < 9) ? 1 : (i < 14) ? 2 : 3)
                  : ((i < 3) ? 3 : (i < 8) ? 2 : (i < 14) ? 1 : 0);
}
__host__ __device__ constexpr int nt_fn(int a, int i) {
  return (a == 1) ? 1 : (i == 8) ? 3 : 2;
}

__device__ __forceinline__ float fastrcp(float x) {
#if __has_builtin(__builtin_amdgcn_rcpf)
  return __builtin_amdgcn_rcpf(x);
#else
  return 1.0f / x;
#endif
}

// =============== FUSED interior kernel: 3 passes in one tile ===============
// buf0: D0 = Y-X, 80 x 144, anchored (y0-24, x0-8).
// buf1: D1, 64 x [136 used], idx j1 (global x0-4+j1)  -- ALIGNED f4 stores.
// buf2 (alias buf0): D2, 48 x [132 used], idx j2 (global x0-2+j2) -- aligned.
__global__ __launch_bounds__(256, 2)
void fused_int(const float* __restrict__ Xg, const float* __restrict__ Yg,
               float* __restrict__ Out, W3 w)
{
  __shared__ float buf0[80 * LST0];   // 46080 B
  __shared__ float buf1[64 * LST1];   // 35840 B  (total = 81920 exactly)
  float* buf2 = buf0;                 // 48*140*4 = 26880 <= 46080, buf0 dead

  const int bid = blockIdx.x, nwg = gridDim.x;
  const int wg = ((nwg & 7) == 0) ? ((bid & 7) * (nwg >> 3) + (bid >> 3)) : bid;
  const int bz = wg / NINT1;
  const int t0 = wg - bz * NINT1;
  const int bx = 1 + t0 / (NBY - 2);
  const int by = 1 + t0 % (NBY - 2);       // by-fastest: vertical halo L2 hits

  const int tid = threadIdx.x;
  const int x0 = bx * TSC, y0 = by * TSR;
  const size_t img = (size_t)bz * ((size_t)HH * WW);

  // ---- stage: D0 = Y - X (unchecked; window provably in-bounds) ----
#pragma unroll
  for (int s = 0; s < 12; ++s) {
    const int idx = s * 256 + tid;
    if (idx < 80 * 36) {
      const int r = idx / 36, c4 = idx - r * 36;
      const size_t g = img + (size_t)(y0 - 24 + r) * WW + (x0 - 8 + c4 * 4);
      const float4 xv = *(const float4*)(Xg + g);
      const float4 yv = *(const float4*)(Yg + g);
      *(float4*)&buf0[r * LST0 + c4 * 4] =
          make_float4(yv.x - xv.x, yv.y - xv.y, yv.z - xv.z, yv.w - xv.w);
    }
  }
  __syncthreads();

  // ---- pass A (-10deg): D1[j1] = cen - conv(D0), window floats c0+2..c0+9 ----
#pragma unroll 1
  for (int tt = tid; tt < 544; tt += 256) {        // 16 rg x 34 cg
    const int rg = tt / 34, cg = tt - rg * 34;
    const int r0 = rg * 4, c0 = cg * 4;
    float acc[4][4] = {};
#pragma unroll
    for (int rr = 0; rr < 20; ++rr) {
      const float* lp = &buf0[(r0 + rr) * LST0 + c0];
      const float2 a = *(const float2*)(lp + 2);
      const float4 b = *(const float4*)(lp + 4);
      const float2 c2 = *(const float2*)(lp + 8);
      const float win[8] = {a.x, a.y, b.x, b.y, b.z, b.w, c2.x, c2.y};
#pragma unroll
      for (int t = 0; t < 4; ++t) {
        const int i = rr - t;
        if (i >= 0 && i <= 16) {
          const int js = js_fn(0, i), nt = nt_fn(0, i);
#pragma unroll
          for (int jj = 0; jj < nt; ++jj) {
            const float wv = w.wA[i][js + jj];
#pragma unroll
            for (int c = 0; c < 4; ++c)
              acc[t][c] = fmaf(wv, win[c + js + jj], acc[t][c]);
          }
        }
      }
    }
#pragma unroll
    for (int t = 0; t < 4; ++t) {
      const float4 cen = *(const float4*)&buf0[(r0 + t + 8) * LST0 + c0 + 4];
      *(float4*)&buf1[(r0 + t) * LST1 + c0] =
          make_float4(cen.x - acc[t][0], cen.y - acc[t][1],
                      cen.z - acc[t][2], cen.w - acc[t][3]);
    }
  }
  __syncthreads();

  // ---- pass B (0deg, vertical 17-tap): D2[j2] = cen - conv(D1[j2+2]) ----
#pragma unroll 1
  for (int tt = tid; tt < 396; tt += 256) {        // 12 rg x 33 cg
    const int rg = tt / 33, cg = tt - rg * 33;
    const int r0 = rg * 4, c0 = cg * 4;
    float acc[4][4] = {};
#pragma unroll
    for (int rr = 0; rr < 20; ++rr) {
      const float* lp = &buf1[(r0 + rr) * LST1 + c0];
      const float2 a = *(const float2*)(lp + 2);
      const float2 b = *(const float2*)(lp + 4);
      const float win[4] = {a.x, a.y, b.x, b.y};
#pragma unroll
      for (int t = 0; t < 4; ++t) {
        const int i = rr - t;
        if (i >= 0 && i <= 16) {
          const float wv = w.wB[i];
          acc[t][0] = fmaf(wv, win[0], acc[t][0]);
          acc[t][1] = fmaf(wv, win[1], acc[t][1]);
          acc[t][2] = fmaf(wv, win[2], acc[t][2]);
          acc[t][3] = fmaf(wv, win[3], acc[t][3]);
        }
      }
    }
#pragma unroll
    for (int t = 0; t < 4; ++t) {
      const float* cp = &buf1[(r0 + t + 8) * LST1 + c0];
      const float2 ca = *(const float2*)(cp + 2);
      const float2 cb = *(const float2*)(cp + 4);
      *(float4*)&buf2[(r0 + t) * LST2 + c0] =
          make_float4(ca.x - acc[t][0], ca.y - acc[t][1],
                      cb.x - acc[t][2], cb.y - acc[t][3]);
    }
  }
  __syncthreads();

  // ---- pass C (+10deg): X3[p] = y - cen2 + conv(D2), window = 2 x b128 ----
  {
    const int tg = tid >> 5, tc = tid & 31;        // 8 rg x 32 cg = 256 exactly
    const int r0 = tg * 4, c0 = tc * 4;
    float acc[4][4] = {};
#pragma unroll
    for (int rr = 0; rr < 20; ++rr) {
      const float* lp = &buf2[(r0 + rr) * LST2 + c0];
      const float4 a = *(const float4*)(lp);
      const float4 b = *(const float4*)(lp + 4);
      const float win[8] = {a.x, a.y, a.z, a.w, b.x, b.y, b.z, b.w};
#pragma unroll
      for (int t = 0; t < 4; ++t) {
        const int i = rr - t;
        if (i >= 0 && i <= 16) {
          const int js = js_fn(2, i), nt = nt_fn(2, i);
#pragma unroll
          for (int jj = 0; jj < nt; ++jj) {
            const float wv = w.wC[i][js + jj];
#pragma unroll
            for (int c = 0; c < 4; ++c)
              acc[t][c] = fmaf(wv, win[c + js + jj], acc[t][c]);
          }
        }
      }
    }
#pragma unroll
    for (int t = 0; t < 4; ++t) {
      const float* cp = &buf2[(r0 + t + 8) * LST2 + c0];
      const float2 ca = *(const float2*)(cp + 2);
      const float2 cb = *(const float2*)(cp + 4);
      const int gy = y0 + r0 + t, gx = x0 + c0;
      const float4 yv = *(const float4*)(Yg + img + (size_t)gy * WW + gx);
      *(float4*)(Out + img + (size_t)gy * WW + gx) = make_float4(
          yv.x - ca.x + acc[t][0], yv.y - ca.y + acc[t][1],
          yv.z - cb.x + acc[t][2], yv.w - cb.y + acc[t][3]);
    }
  }
}

// =============== FUSED boundary kernel: checked + N-normalized ===============
__global__ __launch_bounds__(256, 2)
void fused_bnd(const float* __restrict__ Xg, const float* __restrict__ Yg,
               const float* __restrict__ Nn, float* __restrict__ Out, W3 w)
{
  __shared__ float buf0[80 * LST0];
  __shared__ float buf1[64 * LST1];
  float* buf2 = buf0;

  const int u = blockIdx.x;
  int bx, by;
  if (u < NBX)          { bx = u;       by = 0; }
  else if (u < 2 * NBX) { bx = u - NBX; by = NBY - 1; }
  else { const int v = u - 2 * NBX; by = 1 + (v >> 1); bx = (v & 1) ? NBX - 1 : 0; }
  const int bz = blockIdx.y;

  const int tid = threadIdx.x;
  const int x0 = bx * TSC, y0 = by * TSR;
  const size_t img = (size_t)bz * ((size_t)HH * WW);
  const float* N0 = Nn;
  const float* N1 = Nn + (size_t)HH * WW;
  const float* N2 = Nn + 2 * (size_t)HH * WW;

  // ---- checked staging of D0, zero-filled OOB ----
#pragma unroll
  for (int s = 0; s < 12; ++s) {
    const int idx = s * 256 + tid;
    if (idx < 80 * 36) {
      const int r = idx / 36, c4 = idx - r * 36;
      const int gy = y0 - 24 + r;
      const int gx = x0 - 8 + c4 * 4;
      float4 v = make_float4(0.f, 0.f, 0.f, 0.f);
      if (gy >= 0 && gy < HH) {
        const float* xr = Xg + img + (size_t)gy * WW;
        const float* yr = Yg + img + (size_t)gy * WW;
        if (gx >= 0 && gx + 4 <= WW) {
          const float4 xv = *(const float4*)(xr + gx);
          const float4 yv = *(const float4*)(yr + gx);
          v = make_float4(yv.x - xv.x, yv.y - xv.y, yv.z - xv.z, yv.w - xv.w);
        } else {
          float tv[4] = {0.f, 0.f, 0.f, 0.f};
#pragma unroll
          for (int e = 0; e < 4; ++e) {
            const int gxe = gx + e;
            if (gxe >= 0 && gxe < WW) tv[e] = yr[gxe] - xr[gxe];
          }
          v = make_float4(tv[0], tv[1], tv[2], tv[3]);
        }
      }
      *(float4*)&buf0[r * LST0 + c4 * 4] = v;
    }
  }
  __syncthreads();

  // ---- pass A with per-pixel N0 ----
#pragma unroll 1
  for (int tt = tid; tt < 544; tt += 256) {
    const int rg = tt / 34, cg = tt - rg * 34;
    const int r0 = rg * 4, c0 = cg * 4;
    float acc[4][4] = {};
#pragma unroll
    for (int rr = 0; rr < 20; ++rr) {
      const float* lp = &buf0[(r0 + rr) * LST0 + c0];
      const float2 a = *(const float2*)(lp + 2);
      const float4 b = *(const float4*)(lp + 4);
      const float2 c2 = *(const float2*)(lp + 8);
      const float win[8] = {a.x, a.y, b.x, b.y, b.z, b.w, c2.x, c2.y};
#pragma unroll
      for (int t = 0; t < 4; ++t) {
        const int i = rr - t;
        if (i >= 0 && i <= 16) {
          const int js = js_fn(0, i), nt = nt_fn(0, i);
#pragma unroll
          for (int jj = 0; jj < nt; ++jj) {
            const float wv = w.wA[i][js + jj];
#pragma unroll
            for (int c = 0; c < 4; ++c)
              acc[t][c] = fmaf(wv, win[c + js + jj], acc[t][c]);
          }
        }
      }
    }
#pragma unroll
    for (int t = 0; t < 4; ++t) {
      const int gy = y0 - 16 + r0 + t;
      const bool rok = (gy >= 0) && (gy < HH);
      const float4 cen = *(const float4*)&buf0[(r0 + t + 8) * LST0 + c0 + 4];
      const float cenv[4] = {cen.x, cen.y, cen.z, cen.w};
      float d[4];
#pragma unroll
      for (int c = 0; c < 4; ++c) {
        const int gxc = x0 - 4 + c0 + c;
        const bool ok = rok && (gxc >= 0) && (gxc < WW);
        float r = 0.0f;
        if (ok) {
          const float n = N0[(size_t)gy * WW + gxc];
          r = cenv[c] - acc[t][c] * w.knA * fastrcp(n);
        }
        d[c] = r;
      }
      *(float4*)&buf1[(r0 + t) * LST1 + c0] = make_float4(d[0], d[1], d[2], d[3]);
    }
  }
  __syncthreads();

  // ---- pass B with per-pixel N1 ----
#pragma unroll 1
  for (int tt = tid; tt < 396; tt += 256) {
    const int rg = tt / 33, cg = tt - rg * 33;
    const int r0 = rg * 4, c0 = cg * 4;
    float acc[4][4] = {};
#pragma unroll
    for (int rr = 0; rr < 20; ++rr) {
      const float* lp = &buf1[(r0 + rr) * LST1 + c0];
      const float2 a = *(const float2*)(lp + 2);
      const float2 b = *(const float2*)(lp + 4);
      const float win[4] = {a.x, a.y, b.x, b.y};
#pragma unroll
      for (int t = 0; t < 4; ++t) {
        const int i = rr - t;
        if (i >= 0 && i <= 16) {
          const float wv = w.wB[i];
          acc[t][0] = fmaf(wv, win[0], acc[t][0]);
          acc[t][1] = fmaf(wv, win[1], acc[t][1]);
          acc[t][2] = fmaf(wv, win[2], acc[t][2]);
          acc[t][3] = fmaf(wv, win[3], acc[t][3]);
        }
      }
    }
#pragma unroll
    for (int t = 0; t < 4; ++t) {
      const int gy = y0 - 8 + r0 + t;
      const bool rok = (gy >= 0) && (gy < HH);
      const float* cp = &buf1[(r0 + t + 8) * LST1 + c0];
      const float2 ca = *(const float2*)(cp + 2);
      const float2 cb = *(const float2*)(cp + 4);
      const float cenv[4] = {ca.x, ca.y, cb.x, cb.y};
      float d[4];
#pragma unroll
      for (int c = 0; c < 4; ++c) {
        const int gxc = x0 - 2 + c0 + c;
        const bool ok = rok && (gxc >= 0) && (gxc < WW);
        float r = 0.0f;
        if (ok) {
          const float n = N1[(size_t)gy * WW + gxc];
          r = cenv[c] - acc[t][c] * w.knB * fastrcp(n);
        }
        d[c] = r;
      }
      *(float4*)&buf2[(r0 + t) * LST2 + c0] = make_float4(d[0], d[1], d[2], d[3]);
    }
  }
  __syncthreads();

  // ---- pass C with per-pixel N2 (output pixels always in-image) ----
  {
    const int tg = tid >> 5, tc = tid & 31;
    const int r0 = tg * 4, c0 = tc * 4;
    float acc[4][4] = {};
#pragma unroll
    for (int rr = 0; rr < 20; ++rr) {
      const float* lp = &buf2[(r0 + rr) * LST2 + c0];
      const float4 a = *(const float4*)(lp);
      const float4 b = *(const float4*)(lp + 4);
      const float win[8] = {a.x, a.y, a.z, a.w, b.x, b.y, b.z, b.w};
#pragma unroll
      for (int t = 0; t < 4; ++t) {
        const int i = rr - t;
        if (i >= 0 && i <= 16) {
          const int js = js_fn(2, i), nt = nt_fn(2, i);
#pragma unroll
          for (int jj = 0; jj < nt; ++jj) {
            const float wv = w.wC[i][js + jj];
#pragma unroll
            for (int c = 0; c < 4; ++c)
              acc[t][c] = fmaf(wv, win[c + js + jj], acc[t][c]);
          }
        }
      }
    }
#pragma unroll
    for (int t = 0; t < 4; ++t) {
      const float* cp = &buf2[(r0 + t + 8) * LST2 + c0];
      const float2 ca = *(const float2*)(cp + 2);
      const float2 cb = *(const float2*)(cp + 4);
      const int gy = y0 + r0 + t, gx = x0 + c0;
      const float4 yv = *(const float4*)(Yg + img + (size_t)gy * WW + gx);
      const float4 nv = *(const float4*)(N2 + (size_t)gy * WW + gx);
      *(float4*)(Out + img + (size_t)gy * WW + gx) = make_float4(
          yv.x - ca.x + acc[t][0] * w.knC * fastrcp(nv.x),
          yv.y - ca.y + acc[t][1] * w.knC * fastrcp(nv.y),
          yv.z - cb.x + acc[t][2] * w.knC * fastrcp(nv.z),
          yv.w - cb.y + acc[t][3] * w.knC * fastrcp(nv.w));
    }
  }
}

// ===================== fallback path (r9, dense-capable) =====================
__global__ __launch_bounds__(256)
void diff_kernel(const float* __restrict__ X, const float* __restrict__ Y,
                 float* __restrict__ D, int n4)
{
  const int stride = gridDim.x * 256;
  for (int i = blockIdx.x * 256 + threadIdx.x; i < n4; i += stride) {
    const float4 x = ((const float4*)X)[i];
    const float4 y = ((const float4*)Y)[i];
    ((float4*)D)[i] = make_float4(y.x - x.x, y.y - x.y, y.z - x.z, y.w - x.w);
  }
}

template <int MODE>
__global__ __launch_bounds__(256, 3)
void conv_dense(const float* __restrict__ P0, const float* __restrict__ P1,
                const float* __restrict__ Nrm, float* __restrict__ Out, Wts wts)
{
  constexpr int LSTR = 148, LCW = 36, XOFF = 8, CH = 48 * LCW;
  __shared__ float lds[48 * 148];
  const int bx = blockIdx.x, by = blockIdx.y, bz = blockIdx.z;
  const int tid = threadIdx.x;
  const int x0 = bx * TSC, y0 = by * TSR;
  const size_t img = (size_t)bz * ((size_t)HH * WW);
  const float* A = P0 + img;
#pragma unroll
  for (int s = 0; s < (CH + 255) / 256; ++s) {
    const int idx = s * 256 + tid;
    if (idx < CH) {
      const int r = idx / LCW, c4 = idx - r * LCW;
      const int gy = y0 - 8 + r, gx = x0 - XOFF + c4 * 4;
      float4 v = make_float4(0.f, 0.f, 0.f, 0.f);
      if (gy >= 0 && gy < HH) {
        const float* ar = A + (size_t)gy * WW;
        if (gx >= 0 && gx + 4 <= WW) v = *(const float4*)(ar + gx);
        else {
          float tv[4] = {0.f, 0.f, 0.f, 0.f};
#pragma unroll
          for (int e = 0; e < 4; ++e) {
            const int gxe = gx + e;
            if (gxe >= 0 && gxe < WW) tv[e] = ar[gxe];
          }
          v = make_float4(tv[0], tv[1], tv[2], tv[3]);
        }
      }
      *(float4*)&lds[r * LSTR + c4 * 4] = v;
    }
  }
  __syncthreads();
  const int tc = tid & 31, tg = tid >> 5, lc = tc * 4;
  float acc[4][4] = {};
#pragma unroll
  for (int rr = 0; rr < 20; ++rr) {
    const float* lp = &lds[(tg * 4 + rr) * LSTR];
    const float4 w0 = *(const float4*)(lp + 4 + lc);
    const float4 w1 = *(const float4*)(lp + 8 + lc);
    const float4 w2 = *(const float4*)(lp + 12 + lc);
    const float win[8] = {w0.z, w0.w, w1.x, w1.y, w1.z, w1.w, w2.x, w2.y};
#pragma unroll
    for (int t = 0; t < 4; ++t) {
      const int i = rr - t;
      if (i >= 0 && i <= 16) {
#pragma unroll
        for (int jj = 0; jj < 5; ++jj) {
          const float wv = wts.w[i][jj];
#pragma unroll
          for (int c = 0; c < 4; ++c)
            acc[t][c] = fmaf(wv, win[c + jj], acc[t][c]);
        }
      }
    }
  }
  float* Ob = Out + img;
  const int gx = x0 + lc;
  const float kn = wts.knorm;
#pragma unroll
  for (int t = 0; t < 4; ++t) {
    const int yo = y0 + tg * 4 + t;
    const float4 cv = *(const float4*)&lds[(tg * 4 + t + 8) * LSTR + XOFF + lc];
    const float4 nv = *(const float4*)(Nrm + (size_t)yo * WW + gx);
    const float a0 = acc[t][0] * kn * fastrcp(nv.x);
    const float a1 = acc[t][1] * kn * fastrcp(nv.y);
    const float a2 = acc[t][2] * kn * fastrcp(nv.z);
    const float a3 = acc[t][3] * kn * fastrcp(nv.w);
    float4 o;
    if (MODE == 2) {
      const float4 yv = *(const float4*)(P1 + img + (size_t)yo * WW + gx);
      o = make_float4(yv.x - cv.x + a0, yv.y - cv.y + a1,
                      yv.z - cv.z + a2, yv.w - cv.w + a3);
    } else {
      o = make_float4(cv.x - a0, cv.y - a1, cv.z - a2, cv.w - a3);
    }
    *(float4*)(Ob + (size_t)yo * WW + gx) = o;
  }
}

// ---------------- host-side replication of _build_kernels ----------------
static void rotate33(const double* src, double* dst, double ang_deg) {
  const int n = 33;
  const double t = ang_deg * 3.14159265358979323846 / 180.0;
  const double cs = cos(t), sn = sin(t);
  for (int y = 0; y < n; ++y) {
    for (int x = 0; x < n; ++x) {
      const double y0 = y - 16.0, x0 = x - 16.0;
      const double sy = cs * y0 + sn * x0 + 16.0;
      const double sx = -sn * y0 + cs * x0 + 16.0;
      const double fy = floor(sy), fx = floor(sx);
      const int y0i = (int)fy, x0i = (int)fx;
      const double wy = sy - fy, wx = sx - fx;
      double o = 0.0;
      for (int dy = 0; dy < 2; ++dy)
        for (int dx = 0; dx < 2; ++dx) {
          const int yy = y0i + dy, xx = x0i + dx;
          if (yy < 0 || yy >= n || xx < 0 || xx >= n) continue;
          const double wgt = (dy ? wy : 1.0 - wy) * (dx ? wx : 1.0 - wx);
          o += wgt * src[yy * n + xx];
        }
      dst[y * n + x] = o;
    }
  }
}

static void build_K(float K[3][17][5]) {
  const double angs[3] = {-10.0, 0.0, 10.0};
  double base[33 * 33], rot[33 * 33];
  for (int i = 0; i < 33 * 33; ++i) base[i] = 0.0;
  for (int y = 0; y < 33; ++y) base[y * 33 + 16] = 1.0;
  for (int a = 0; a < 3; ++a) {
    if (a == 1) memcpy(rot, base, sizeof(rot));
    else        rotate33(base, rot, angs[a]);
    double k17[17][17];
    for (int y = 0; y < 17; ++y)
      for (int x = 0; x < 17; ++x) k17[y][x] = rot[(y + 8) * 33 + (x + 8)];
    int r = 0, c = 0;
    for (int y = 0; y < 17; ++y) { bool nz = false; for (int x = 0; x < 17; ++x) if (k17[y][x] != 0.0) nz = true; r += nz; }
    for (int x = 0; x < 17; ++x) { bool nz = false; for (int y = 0; y < 17; ++y) if (k17[y][x] != 0.0) nz = true; c += nz; }
    r = r / 2 * 2; c = c / 2 * 2;
    const int kh = r + 1, kw = c + 1;
    for (int y = 0; y < 17; ++y)
      for (int x = 0; x < 5; ++x) K[a][y][x] = 0.0f;
    if (kh <= 17 && kw <= 5) {
      const int oh = (17 - kh) / 2, ow = (5 - kw) / 2;
      for (int y = 0; y < kh; ++y)
        for (int x = 0; x < kw; ++x)
          K[a][oh + y][ow + x] = (float)k17[8 - r / 2 + y][8 - c / 2 + x];
    }
  }
}

static int pick_mode(int a, const float K[17][5]) {
  for (int i = 0; i < 17; ++i) {
    const int js = js_fn(a, i), nt = nt_fn(a, i);
    for (int j = 0; j < 5; ++j)
      if ((j < js || j >= js + nt) && K[i][j] != 0.0f) return 1;
  }
  return 0;
}

extern "C" void kernel_launch(void* const* d_in, const int* in_sizes, int n_in,
                              void* d_out, int out_size, void* d_ws, size_t ws_size,
                              hipStream_t stream) {
  const float* X  = (const float*)d_in[0];
  const float* Y  = (const float*)d_in[1];
  const float* Nn = (const float*)d_in[3];
  float* out = (float*)d_out;
  float* tmp = (float*)d_ws;
  const size_t HW = (size_t)HH * WW;
  const int B = in_sizes[0] / (int)HW;   // 2

  float K[3][17][5];
  build_K(K);
  double ks[3];
  for (int a = 0; a < 3; ++a) {
    ks[a] = 0.0;
    for (int i = 0; i < 17; ++i)
      for (int j = 0; j < 5; ++j) ks[a] += K[a][i][j];
  }
  const int dense = pick_mode(0, K[0]) | pick_mode(1, K[1]) | pick_mode(2, K[2]);

  if (!dense) {
    W3 w;
    for (int i = 0; i < 17; ++i)
      for (int j = 0; j < 5; ++j) {
        w.wA[i][j] = (float)(K[0][i][j] / ks[0]);
        w.wC[i][j] = (float)(K[2][i][j] / ks[2]);
      }
    for (int i = 0; i < 17; ++i) w.wB[i] = (float)(K[1][i][2] / ks[1]);
    w.knA = (float)ks[0]; w.knB = (float)ks[1]; w.knC = (float)ks[2];

    fused_int<<<dim3(NINT1 * B), dim3(256), 0, stream>>>(X, Y, out, w);
    fused_bnd<<<dim3(NBND1, B), dim3(256), 0, stream>>>(X, Y, Nn, out, w);
  } else {
    Wts w[3];
    for (int a = 0; a < 3; ++a) {
      for (int i = 0; i < 17; ++i)
        for (int j = 0; j < 5; ++j) w[a].w[i][j] = (float)(K[a][i][j] / ks[a]);
      w[a].knorm = (float)ks[a];
    }
    const int n4 = (int)(B * HW / 4);
    const int dg = (n4 + 255) / 256;
    diff_kernel<<<dim3(dg > 8192 ? 8192 : dg), dim3(256), 0, stream>>>(X, Y, tmp, n4);
    dim3 g(NBX, NBY, B), blk(256);
    conv_dense<1><<<g, blk, 0, stream>>>(tmp, nullptr, Nn,          out, w[0]);
    conv_dense<1><<<g, blk, 0, stream>>>(out, nullptr, Nn + HW,     tmp, w[1]);
    conv_dense<2><<<g, blk, 0, stream>>>(tmp, Y,       Nn + 2 * HW, out, w[2]);
  }
}

// Round 12
// 85.977 us; speedup vs baseline: 1.1931x; 1.1931x over previous
//
#include <hip/hip_runtime.h>
#include <hip/hip_fp16.h>
#include <math.h>
#include <string.h>

#define HH 2048
#define WW 2048
#define TSC 128
#define TSR 32
#define NBX (WW / TSC)                 // 16
#define NBY (HH / TSR)                 // 64
#define NINT1 ((NBX - 2) * (NBY - 2))  // 868
#define NBND1 (NBX * NBY - NINT1)      // 156

// half2 row strides (in half2 units): buf0 144 halfs = 72, buf1/2 140 = 70
#define H0 72
#define H1 70

struct W3 { float wA[17][5]; float wC[17][5]; float wB[17]; float knA, knB, knC; };
struct Wts { float w[17][5]; float knorm; };   // fallback path

// angle index a: 0 -> -10deg, 1 -> 0deg, 2 -> +10deg
__host__ __device__ constexpr int js_fn(int a, int i) {
  return (a == 1) ? 2
       : (a == 2) ? ((i < 3) ? 0 : (i < 9) ? 1 : (i < 14) ? 2 : 3)
                  : ((i < 3) ? 3 : (i < 8) ? 2 : (i < 14) ? 1 : 0);
}
__host__ __device__ constexpr int nt_fn(int a, int i) {
  return (a == 1) ? 1 : (i == 8) ? 3 : 2;
}

__device__ __forceinline__ float fastrcp(float x) {
#if __has_builtin(__builtin_amdgcn_rcpf)
  return __builtin_amdgcn_rcpf(x);
#else
  return 1.0f / x;
#endif
}

__device__ __forceinline__ __half2 pack2(float a, float b) {
  return __float22half2_rn(make_float2(a, b));
}

// =============== FUSED interior kernel: 3 passes, fp16 LDS ===============
// buf0: D0 = Y-X, 80 x 144 halfs, anchored (y0-24, x0-8).
// buf1: D1, 64 x 136 used, idx j1 (global x0-4+j1).
// buf2 (alias buf0): D2, 48 x 132 used, idx j2 (global x0-2+j2).
// fp32 accumulation; fp16 only for storage (|D| < 2, quant err ~1e-3).
__global__ __launch_bounds__(256, 4)
void fused_int(const float* __restrict__ Xg, const float* __restrict__ Yg,
               float* __restrict__ Out, W3 w)
{
  __shared__ __half2 buf0h[80 * H0];   // 23040 B
  __shared__ __half2 buf1h[64 * H1];   // 17920 B (total 40960 -> 4 blocks/CU)
  __half2* buf2h = buf0h;              // 48*70*4 = 13440 <= 23040

  const int bid = blockIdx.x, nwg = gridDim.x;
  const int wg = ((nwg & 7) == 0) ? ((bid & 7) * (nwg >> 3) + (bid >> 3)) : bid;
  const int bz = wg / NINT1;
  const int t0 = wg - bz * NINT1;
  const int bx = 1 + t0 / (NBY - 2);
  const int by = 1 + t0 % (NBY - 2);       // by-fastest: vertical halo L2 hits

  const int tid = threadIdx.x;
  const int x0 = bx * TSC, y0 = by * TSR;
  const size_t img = (size_t)bz * ((size_t)HH * WW);

  // ---- stage: D0 = Y - X (unchecked; window provably in-bounds) ----
#pragma unroll
  for (int s = 0; s < 12; ++s) {
    const int idx = s * 256 + tid;
    if (idx < 80 * 36) {
      const int r = idx / 36, c4 = idx - r * 36;
      const size_t g = img + (size_t)(y0 - 24 + r) * WW + (x0 - 8 + c4 * 4);
      const float4 xv = *(const float4*)(Xg + g);
      const float4 yv = *(const float4*)(Yg + g);
      buf0h[r * H0 + c4 * 2]     = pack2(yv.x - xv.x, yv.y - xv.y);
      buf0h[r * H0 + c4 * 2 + 1] = pack2(yv.z - xv.z, yv.w - xv.w);
    }
  }
  __syncthreads();

  // ---- pass A (-10deg): D1[j1] = cen - conv(D0), window halfs c0+2..c0+9 ----
#pragma unroll 1
  for (int tt = tid; tt < 544; tt += 256) {        // 16 rg x 34 cg
    const int rg = tt / 34, cg = tt - rg * 34;
    const int r0 = rg * 4, c0 = cg * 4;
    float acc[4][4] = {};
#pragma unroll
    for (int rr = 0; rr < 20; ++rr) {
      const __half2* lp = &buf0h[(r0 + rr) * H0 + (c0 >> 1)];
      const float2 p0 = __half22float2(lp[1]);
      const float2 p1 = __half22float2(lp[2]);
      const float2 p2 = __half22float2(lp[3]);
      const float2 p3 = __half22float2(lp[4]);
      const float win[8] = {p0.x, p0.y, p1.x, p1.y, p2.x, p2.y, p3.x, p3.y};
#pragma unroll
      for (int t = 0; t < 4; ++t) {
        const int i = rr - t;
        if (i >= 0 && i <= 16) {
          const int js = js_fn(0, i), nt = nt_fn(0, i);
#pragma unroll
          for (int jj = 0; jj < nt; ++jj) {
            const float wv = w.wA[i][js + jj];
#pragma unroll
            for (int c = 0; c < 4; ++c)
              acc[t][c] = fmaf(wv, win[c + js + jj], acc[t][c]);
          }
        }
      }
    }
#pragma unroll
    for (int t = 0; t < 4; ++t) {
      const __half2* cp = &buf0h[(r0 + t + 8) * H0 + (c0 >> 1)];
      const float2 c01 = __half22float2(cp[2]);
      const float2 c23 = __half22float2(cp[3]);
      buf1h[(r0 + t) * H1 + (c0 >> 1)]     = pack2(c01.x - acc[t][0], c01.y - acc[t][1]);
      buf1h[(r0 + t) * H1 + (c0 >> 1) + 1] = pack2(c23.x - acc[t][2], c23.y - acc[t][3]);
    }
  }
  __syncthreads();

  // ---- pass B (0deg, vertical 17-tap): D2[j2] = cen - conv(D1[j2+2]) ----
#pragma unroll 1
  for (int tt = tid; tt < 396; tt += 256) {        // 12 rg x 33 cg
    const int rg = tt / 33, cg = tt - rg * 33;
    const int r0 = rg * 4, c0 = cg * 4;
    float acc[4][4] = {};
#pragma unroll
    for (int rr = 0; rr < 20; ++rr) {
      const __half2* lp = &buf1h[(r0 + rr) * H1 + (c0 >> 1)];
      const float2 a = __half22float2(lp[1]);
      const float2 b = __half22float2(lp[2]);
      const float win[4] = {a.x, a.y, b.x, b.y};
#pragma unroll
      for (int t = 0; t < 4; ++t) {
        const int i = rr - t;
        if (i >= 0 && i <= 16) {
          const float wv = w.wB[i];
          acc[t][0] = fmaf(wv, win[0], acc[t][0]);
          acc[t][1] = fmaf(wv, win[1], acc[t][1]);
          acc[t][2] = fmaf(wv, win[2], acc[t][2]);
          acc[t][3] = fmaf(wv, win[3], acc[t][3]);
        }
      }
    }
#pragma unroll
    for (int t = 0; t < 4; ++t) {
      const __half2* cp = &buf1h[(r0 + t + 8) * H1 + (c0 >> 1)];
      const float2 ca = __half22float2(cp[1]);
      const float2 cb = __half22float2(cp[2]);
      buf2h[(r0 + t) * H1 + (c0 >> 1)]     = pack2(ca.x - acc[t][0], ca.y - acc[t][1]);
      buf2h[(r0 + t) * H1 + (c0 >> 1) + 1] = pack2(cb.x - acc[t][2], cb.y - acc[t][3]);
    }
  }
  __syncthreads();

  // ---- pass C (+10deg): X3 = y - cen2 + conv(D2), window halfs c0..c0+7 ----
  {
    const int tg = tid >> 5, tc = tid & 31;        // 8 rg x 32 cg = 256 exactly
    const int r0 = tg * 4, c0 = tc * 4;
    float acc[4][4] = {};
#pragma unroll
    for (int rr = 0; rr < 20; ++rr) {
      const __half2* lp = &buf2h[(r0 + rr) * H1 + (c0 >> 1)];
      const float2 p0 = __half22float2(lp[0]);
      const float2 p1 = __half22float2(lp[1]);
      const float2 p2 = __half22float2(lp[2]);
      const float2 p3 = __half22float2(lp[3]);
      const float win[8] = {p0.x, p0.y, p1.x, p1.y, p2.x, p2.y, p3.x, p3.y};
#pragma unroll
      for (int t = 0; t < 4; ++t) {
        const int i = rr - t;
        if (i >= 0 && i <= 16) {
          const int js = js_fn(2, i), nt = nt_fn(2, i);
#pragma unroll
          for (int jj = 0; jj < nt; ++jj) {
            const float wv = w.wC[i][js + jj];
#pragma unroll
            for (int c = 0; c < 4; ++c)
              acc[t][c] = fmaf(wv, win[c + js + jj], acc[t][c]);
          }
        }
      }
    }
#pragma unroll
    for (int t = 0; t < 4; ++t) {
      const __half2* cp = &buf2h[(r0 + t + 8) * H1 + (c0 >> 1)];
      const float2 ca = __half22float2(cp[1]);
      const float2 cb = __half22float2(cp[2]);
      const int gy = y0 + r0 + t, gx = x0 + c0;
      const float4 yv = *(const float4*)(Yg + img + (size_t)gy * WW + gx);
      *(float4*)(Out + img + (size_t)gy * WW + gx) = make_float4(
          yv.x - ca.x + acc[t][0], yv.y - ca.y + acc[t][1],
          yv.z - cb.x + acc[t][2], yv.w - cb.y + acc[t][3]);
    }
  }
}

// =============== FUSED boundary kernel: checked + N-normalized ===============
__global__ __launch_bounds__(256, 4)
void fused_bnd(const float* __restrict__ Xg, const float* __restrict__ Yg,
               const float* __restrict__ Nn, float* __restrict__ Out, W3 w)
{
  __shared__ __half2 buf0h[80 * H0];
  __shared__ __half2 buf1h[64 * H1];
  __half2* buf2h = buf0h;

  const int u = blockIdx.x;
  int bx, by;
  if (u < NBX)          { bx = u;       by = 0; }
  else if (u < 2 * NBX) { bx = u - NBX; by = NBY - 1; }
  else { const int v = u - 2 * NBX; by = 1 + (v >> 1); bx = (v & 1) ? NBX - 1 : 0; }
  const int bz = blockIdx.y;

  const int tid = threadIdx.x;
  const int x0 = bx * TSC, y0 = by * TSR;
  const size_t img = (size_t)bz * ((size_t)HH * WW);
  const float* N0 = Nn;
  const float* N1 = Nn + (size_t)HH * WW;
  const float* N2 = Nn + 2 * (size_t)HH * WW;

  // ---- checked staging of D0, zero-filled OOB ----
#pragma unroll
  for (int s = 0; s < 12; ++s) {
    const int idx = s * 256 + tid;
    if (idx < 80 * 36) {
      const int r = idx / 36, c4 = idx - r * 36;
      const int gy = y0 - 24 + r;
      const int gx = x0 - 8 + c4 * 4;
      float4 v = make_float4(0.f, 0.f, 0.f, 0.f);
      if (gy >= 0 && gy < HH) {
        const float* xr = Xg + img + (size_t)gy * WW;
        const float* yr = Yg + img + (size_t)gy * WW;
        if (gx >= 0 && gx + 4 <= WW) {
          const float4 xv = *(const float4*)(xr + gx);
          const float4 yv = *(const float4*)(yr + gx);
          v = make_float4(yv.x - xv.x, yv.y - xv.y, yv.z - xv.z, yv.w - xv.w);
        } else {
          float tv[4] = {0.f, 0.f, 0.f, 0.f};
#pragma unroll
          for (int e = 0; e < 4; ++e) {
            const int gxe = gx + e;
            if (gxe >= 0 && gxe < WW) tv[e] = yr[gxe] - xr[gxe];
          }
          v = make_float4(tv[0], tv[1], tv[2], tv[3]);
        }
      }
      buf0h[r * H0 + c4 * 2]     = pack2(v.x, v.y);
      buf0h[r * H0 + c4 * 2 + 1] = pack2(v.z, v.w);
    }
  }
  __syncthreads();

  // ---- pass A with per-pixel N0 ----
#pragma unroll 1
  for (int tt = tid; tt < 544; tt += 256) {
    const int rg = tt / 34, cg = tt - rg * 34;
    const int r0 = rg * 4, c0 = cg * 4;
    float acc[4][4] = {};
#pragma unroll
    for (int rr = 0; rr < 20; ++rr) {
      const __half2* lp = &buf0h[(r0 + rr) * H0 + (c0 >> 1)];
      const float2 p0 = __half22float2(lp[1]);
      const float2 p1 = __half22float2(lp[2]);
      const float2 p2 = __half22float2(lp[3]);
      const float2 p3 = __half22float2(lp[4]);
      const float win[8] = {p0.x, p0.y, p1.x, p1.y, p2.x, p2.y, p3.x, p3.y};
#pragma unroll
      for (int t = 0; t < 4; ++t) {
        const int i = rr - t;
        if (i >= 0 && i <= 16) {
          const int js = js_fn(0, i), nt = nt_fn(0, i);
#pragma unroll
          for (int jj = 0; jj < nt; ++jj) {
            const float wv = w.wA[i][js + jj];
#pragma unroll
            for (int c = 0; c < 4; ++c)
              acc[t][c] = fmaf(wv, win[c + js + jj], acc[t][c]);
          }
        }
      }
    }
#pragma unroll
    for (int t = 0; t < 4; ++t) {
      const int gy = y0 - 16 + r0 + t;
      const bool rok = (gy >= 0) && (gy < HH);
      const __half2* cp = &buf0h[(r0 + t + 8) * H0 + (c0 >> 1)];
      const float2 c01 = __half22float2(cp[2]);
      const float2 c23 = __half22float2(cp[3]);
      const float cenv[4] = {c01.x, c01.y, c23.x, c23.y};
      float d[4];
#pragma unroll
      for (int c = 0; c < 4; ++c) {
        const int gxc = x0 - 4 + c0 + c;
        const bool ok = rok && (gxc >= 0) && (gxc < WW);
        float r = 0.0f;
        if (ok) {
          const float n = N0[(size_t)gy * WW + gxc];
          r = cenv[c] - acc[t][c] * w.knA * fastrcp(n);
        }
        d[c] = r;
      }
      buf1h[(r0 + t) * H1 + (c0 >> 1)]     = pack2(d[0], d[1]);
      buf1h[(r0 + t) * H1 + (c0 >> 1) + 1] = pack2(d[2], d[3]);
    }
  }
  __syncthreads();

  // ---- pass B with per-pixel N1 ----
#pragma unroll 1
  for (int tt = tid; tt < 396; tt += 256) {
    const int rg = tt / 33, cg = tt - rg * 33;
    const int r0 = rg * 4, c0 = cg * 4;
    float acc[4][4] = {};
#pragma unroll
    for (int rr = 0; rr < 20; ++rr) {
      const __half2* lp = &buf1h[(r0 + rr) * H1 + (c0 >> 1)];
      const float2 a = __half22float2(lp[1]);
      const float2 b = __half22float2(lp[2]);
      const float win[4] = {a.x, a.y, b.x, b.y};
#pragma unroll
      for (int t = 0; t < 4; ++t) {
        const int i = rr - t;
        if (i >= 0 && i <= 16) {
          const float wv = w.wB[i];
          acc[t][0] = fmaf(wv, win[0], acc[t][0]);
          acc[t][1] = fmaf(wv, win[1], acc[t][1]);
          acc[t][2] = fmaf(wv, win[2], acc[t][2]);
          acc[t][3] = fmaf(wv, win[3], acc[t][3]);
        }
      }
    }
#pragma unroll
    for (int t = 0; t < 4; ++t) {
      const int gy = y0 - 8 + r0 + t;
      const bool rok = (gy >= 0) && (gy < HH);
      const __half2* cp = &buf1h[(r0 + t + 8) * H1 + (c0 >> 1)];
      const float2 ca = __half22float2(cp[1]);
      const float2 cb = __half22float2(cp[2]);
      const float cenv[4] = {ca.x, ca.y, cb.x, cb.y};
      float d[4];
#pragma unroll
      for (int c = 0; c < 4; ++c) {
        const int gxc = x0 - 2 + c0 + c;
        const bool ok = rok && (gxc >= 0) && (gxc < WW);
        float r = 0.0f;
        if (ok) {
          const float n = N1[(size_t)gy * WW + gxc];
          r = cenv[c] - acc[t][c] * w.knB * fastrcp(n);
        }
        d[c] = r;
      }
      buf2h[(r0 + t) * H1 + (c0 >> 1)]     = pack2(d[0], d[1]);
      buf2h[(r0 + t) * H1 + (c0 >> 1) + 1] = pack2(d[2], d[3]);
    }
  }
  __syncthreads();

  // ---- pass C with per-pixel N2 (output pixels always in-image) ----
  {
    const int tg = tid >> 5, tc = tid & 31;
    const int r0 = tg * 4, c0 = tc * 4;
    float acc[4][4] = {};
#pragma unroll
    for (int rr = 0; rr < 20; ++rr) {
      const __half2* lp = &buf2h[(r0 + rr) * H1 + (c0 >> 1)];
      const float2 p0 = __half22float2(lp[0]);
      const float2 p1 = __half22float2(lp[1]);
      const float2 p2 = __half22float2(lp[2]);
      const float2 p3 = __half22float2(lp[3]);
      const float win[8] = {p0.x, p0.y, p1.x, p1.y, p2.x, p2.y, p3.x, p3.y};
#pragma unroll
      for (int t = 0; t < 4; ++t) {
        const int i = rr - t;
        if (i >= 0 && i <= 16) {
          const int js = js_fn(2, i), nt = nt_fn(2, i);
#pragma unroll
          for (int jj = 0; jj < nt; ++jj) {
            const float wv = w.wC[i][js + jj];
#pragma unroll
            for (int c = 0; c < 4; ++c)
              acc[t][c] = fmaf(wv, win[c + js + jj], acc[t][c]);
          }
        }
      }
    }
#pragma unroll
    for (int t = 0; t < 4; ++t) {
      const __half2* cp = &buf2h[(r0 + t + 8) * H1 + (c0 >> 1)];
      const float2 ca = __half22float2(cp[1]);
      const float2 cb = __half22float2(cp[2]);
      const int gy = y0 + r0 + t, gx = x0 + c0;
      const float4 yv = *(const float4*)(Yg + img + (size_t)gy * WW + gx);
      const float4 nv = *(const float4*)(N2 + (size_t)gy * WW + gx);
      *(float4*)(Out + img + (size_t)gy * WW + gx) = make_float4(
          yv.x - ca.x + acc[t][0] * w.knC * fastrcp(nv.x),
          yv.y - ca.y + acc[t][1] * w.knC * fastrcp(nv.y),
          yv.z - cb.x + acc[t][2] * w.knC * fastrcp(nv.z),
          yv.w - cb.y + acc[t][3] * w.knC * fastrcp(nv.w));
    }
  }
}

// ===================== fallback path (r9, dense-capable, fp32) ==============
__global__ __launch_bounds__(256)
void diff_kernel(const float* __restrict__ X, const float* __restrict__ Y,
                 float* __restrict__ D, int n4)
{
  const int stride = gridDim.x * 256;
  for (int i = blockIdx.x * 256 + threadIdx.x; i < n4; i += stride) {
    const float4 x = ((const float4*)X)[i];
    const float4 y = ((const float4*)Y)[i];
    ((float4*)D)[i] = make_float4(y.x - x.x, y.y - x.y, y.z - x.z, y.w - x.w);
  }
}

template <int MODE>
__global__ __launch_bounds__(256, 3)
void conv_dense(const float* __restrict__ P0, const float* __restrict__ P1,
                const float* __restrict__ Nrm, float* __restrict__ Out, Wts wts)
{
  constexpr int LSTR = 148, LCW = 36, XOFF = 8, CH = 48 * LCW;
  __shared__ float lds[48 * 148];
  const int bx = blockIdx.x, by = blockIdx.y, bz = blockIdx.z;
  const int tid = threadIdx.x;
  const int x0 = bx * TSC, y0 = by * TSR;
  const size_t img = (size_t)bz * ((size_t)HH * WW);
  const float* A = P0 + img;
#pragma unroll
  for (int s = 0; s < (CH + 255) / 256; ++s) {
    const int idx = s * 256 + tid;
    if (idx < CH) {
      const int r = idx / LCW, c4 = idx - r * LCW;
      const int gy = y0 - 8 + r, gx = x0 - XOFF + c4 * 4;
      float4 v = make_float4(0.f, 0.f, 0.f, 0.f);
      if (gy >= 0 && gy < HH) {
        const float* ar = A + (size_t)gy * WW;
        if (gx >= 0 && gx + 4 <= WW) v = *(const float4*)(ar + gx);
        else {
          float tv[4] = {0.f, 0.f, 0.f, 0.f};
#pragma unroll
          for (int e = 0; e < 4; ++e) {
            const int gxe = gx + e;
            if (gxe >= 0 && gxe < WW) tv[e] = ar[gxe];
          }
          v = make_float4(tv[0], tv[1], tv[2], tv[3]);
        }
      }
      *(float4*)&lds[r * LSTR + c4 * 4] = v;
    }
  }
  __syncthreads();
  const int tc = tid & 31, tg = tid >> 5, lc = tc * 4;
  float acc[4][4] = {};
#pragma unroll
  for (int rr = 0; rr < 20; ++rr) {
    const float* lp = &lds[(tg * 4 + rr) * LSTR];
    const float4 w0 = *(const float4*)(lp + 4 + lc);
    const float4 w1 = *(const float4*)(lp + 8 + lc);
    const float4 w2 = *(const float4*)(lp + 12 + lc);
    const float win[8] = {w0.z, w0.w, w1.x, w1.y, w1.z, w1.w, w2.x, w2.y};
#pragma unroll
    for (int t = 0; t < 4; ++t) {
      const int i = rr - t;
      if (i >= 0 && i <= 16) {
#pragma unroll
        for (int jj = 0; jj < 5; ++jj) {
          const float wv = wts.w[i][jj];
#pragma unroll
          for (int c = 0; c < 4; ++c)
            acc[t][c] = fmaf(wv, win[c + jj], acc[t][c]);
        }
      }
    }
  }
  float* Ob = Out + img;
  const int gx = x0 + lc;
  const float kn = wts.knorm;
#pragma unroll
  for (int t = 0; t < 4; ++t) {
    const int yo = y0 + tg * 4 + t;
    const float4 cv = *(const float4*)&lds[(tg * 4 + t + 8) * LSTR + XOFF + lc];
    const float4 nv = *(const float4*)(Nrm + (size_t)yo * WW + gx);
    const float a0 = acc[t][0] * kn * fastrcp(nv.x);
    const float a1 = acc[t][1] * kn * fastrcp(nv.y);
    const float a2 = acc[t][2] * kn * fastrcp(nv.z);
    const float a3 = acc[t][3] * kn * fastrcp(nv.w);
    float4 o;
    if (MODE == 2) {
      const float4 yv = *(const float4*)(P1 + img + (size_t)yo * WW + gx);
      o = make_float4(yv.x - cv.x + a0, yv.y - cv.y + a1,
                      yv.z - cv.z + a2, yv.w - cv.w + a3);
    } else {
      o = make_float4(cv.x - a0, cv.y - a1, cv.z - a2, cv.w - a3);
    }
    *(float4*)(Ob + (size_t)yo * WW + gx) = o;
  }
}

// ---------------- host-side replication of _build_kernels ----------------
static void rotate33(const double* src, double* dst, double ang_deg) {
  const int n = 33;
  const double t = ang_deg * 3.14159265358979323846 / 180.0;
  const double cs = cos(t), sn = sin(t);
  for (int y = 0; y < n; ++y) {
    for (int x = 0; x < n; ++x) {
      const double y0 = y - 16.0, x0 = x - 16.0;
      const double sy = cs * y0 + sn * x0 + 16.0;
      const double sx = -sn * y0 + cs * x0 + 16.0;
      const double fy = floor(sy), fx = floor(sx);
      const int y0i = (int)fy, x0i = (int)fx;
      const double wy = sy - fy, wx = sx - fx;
      double o = 0.0;
      for (int dy = 0; dy < 2; ++dy)
        for (int dx = 0; dx < 2; ++dx) {
          const int yy = y0i + dy, xx = x0i + dx;
          if (yy < 0 || yy >= n || xx < 0 || xx >= n) continue;
          const double wgt = (dy ? wy : 1.0 - wy) * (dx ? wx : 1.0 - wx);
          o += wgt * src[yy * n + xx];
        }
      dst[y * n + x] = o;
    }
  }
}

static void build_K(float K[3][17][5]) {
  const double angs[3] = {-10.0, 0.0, 10.0};
  double base[33 * 33], rot[33 * 33];
  for (int i = 0; i < 33 * 33; ++i) base[i] = 0.0;
  for (int y = 0; y < 33; ++y) base[y * 33 + 16] = 1.0;
  for (int a = 0; a < 3; ++a) {
    if (a == 1) memcpy(rot, base, sizeof(rot));
    else        rotate33(base, rot, angs[a]);
    double k17[17][17];
    for (int y = 0; y < 17; ++y)
      for (int x = 0; x < 17; ++x) k17[y][x] = rot[(y + 8) * 33 + (x + 8)];
    int r = 0, c = 0;
    for (int y = 0; y < 17; ++y) { bool nz = false; for (int x = 0; x < 17; ++x) if (k17[y][x] != 0.0) nz = true; r += nz; }
    for (int x = 0; x < 17; ++x) { bool nz = false; for (int y = 0; y < 17; ++y) if (k17[y][x] != 0.0) nz = true; c += nz; }
    r = r / 2 * 2; c = c / 2 * 2;
    const int kh = r + 1, kw = c + 1;
    for (int y = 0; y < 17; ++y)
      for (int x = 0; x < 5; ++x) K[a][y][x] = 0.0f;
    if (kh <= 17 && kw <= 5) {
      const int oh = (17 - kh) / 2, ow = (5 - kw) / 2;
      for (int y = 0; y < kh; ++y)
        for (int x = 0; x < kw; ++x)
          K[a][oh + y][ow + x] = (float)k17[8 - r / 2 + y][8 - c / 2 + x];
    }
  }
}

static int pick_mode(int a, const float K[17][5]) {
  for (int i = 0; i < 17; ++i) {
    const int js = js_fn(a, i), nt = nt_fn(a, i);
    for (int j = 0; j < 5; ++j)
      if ((j < js || j >= js + nt) && K[i][j] != 0.0f) return 1;
  }
  return 0;
}

extern "C" void kernel_launch(void* const* d_in, const int* in_sizes, int n_in,
                              void* d_out, int out_size, void* d_ws, size_t ws_size,
                              hipStream_t stream) {
  const float* X  = (const float*)d_in[0];
  const float* Y  = (const float*)d_in[1];
  const float* Nn = (const float*)d_in[3];
  float* out = (float*)d_out;
  float* tmp = (float*)d_ws;
  const size_t HW = (size_t)HH * WW;
  const int B = in_sizes[0] / (int)HW;   // 2

  float K[3][17][5];
  build_K(K);
  double ks[3];
  for (int a = 0; a < 3; ++a) {
    ks[a] = 0.0;
    for (int i = 0; i < 17; ++i)
      for (int j = 0; j < 5; ++j) ks[a] += K[a][i][j];
  }
  const int dense = pick_mode(0, K[0]) | pick_mode(1, K[1]) | pick_mode(2, K[2]);

  if (!dense) {
    W3 w;
    for (int i = 0; i < 17; ++i)
      for (int j = 0; j < 5; ++j) {
        w.wA[i][j] = (float)(K[0][i][j] / ks[0]);
        w.wC[i][j] = (float)(K[2][i][j] / ks[2]);
      }
    for (int i = 0; i < 17; ++i) w.wB[i] = (float)(K[1][i][2] / ks[1]);
    w.knA = (float)ks[0]; w.knB = (float)ks[1]; w.knC = (float)ks[2];

    fused_int<<<dim3(NINT1 * B), dim3(256), 0, stream>>>(X, Y, out, w);
    fused_bnd<<<dim3(NBND1, B), dim3(256), 0, stream>>>(X, Y, Nn, out, w);
  } else {
    Wts w[3];
    for (int a = 0; a < 3; ++a) {
      for (int i = 0; i < 17; ++i)
        for (int j = 0; j < 5; ++j) w[a].w[i][j] = (float)(K[a][i][j] / ks[a]);
      w[a].knorm = (float)ks[a];
    }
    const int n4 = (int)(B * HW / 4);
    const int dg = (n4 + 255) / 256;
    diff_kernel<<<dim3(dg > 8192 ? 8192 : dg), dim3(256), 0, stream>>>(X, Y, tmp, n4);
    dim3 g(NBX, NBY, B), blk(256);
    conv_dense<1><<<g, blk, 0, stream>>>(tmp, nullptr, Nn,          out, w[0]);
    conv_dense<1><<<g, blk, 0, stream>>>(out, nullptr, Nn + HW,     tmp, w[1]);
    conv_dense<2><<<g, blk, 0, stream>>>(tmp, Y,       Nn + 2 * HW, out, w[2]);
  }
}

// Round 13
// 80.977 us; speedup vs baseline: 1.2668x; 1.0617x over previous
//
#include <hip/hip_runtime.h>
#include <hip/hip_fp16.h>
#include <math.h>
#include <string.h>

#define HH 2048
#define WW 2048
#define TSC 128
#define TSR 32
#define NBX (WW / TSC)                 // 16
#define NBY (HH / TSR)                 // 64
#define NINT1 ((NBX - 2) * (NBY - 2))  // 868

// interior half2 row strides: buf0 144 halfs = 72, buf1/2 140 halfs = 70
#define H0 72
#define H1 70
// boundary (64x16 tiles): buf0 80 halfs = 40, buf1/2 76 halfs = 38
#define G0 40
#define G1 38
#define NB64 624                       // boundary 64x16 tiles per image

struct W3 { float wA[17][5]; float wC[17][5]; float wB[17]; float knA, knB, knC; };
struct Wts { float w[17][5]; float knorm; };   // fallback path

// angle index a: 0 -> -10deg, 1 -> 0deg, 2 -> +10deg
__host__ __device__ constexpr int js_fn(int a, int i) {
  return (a == 1) ? 2
       : (a == 2) ? ((i < 3) ? 0 : (i < 9) ? 1 : (i < 14) ? 2 : 3)
                  : ((i < 3) ? 3 : (i < 8) ? 2 : (i < 14) ? 1 : 0);
}
__host__ __device__ constexpr int nt_fn(int a, int i) {
  return (a == 1) ? 1 : (i == 8) ? 3 : 2;
}

__device__ __forceinline__ float fastrcp(float x) {
#if __has_builtin(__builtin_amdgcn_rcpf)
  return __builtin_amdgcn_rcpf(x);
#else
  return 1.0f / x;
#endif
}

__device__ __forceinline__ __half2 pack2(float a, float b) {
  return __float22half2_rn(make_float2(a, b));
}

// =============== FUSED interior kernel (r12, proven 60us) ===============
__global__ __launch_bounds__(256, 4)
void fused_int(const float* __restrict__ Xg, const float* __restrict__ Yg,
               float* __restrict__ Out, W3 w)
{
  __shared__ __half2 buf0h[80 * H0];   // 23040 B
  __shared__ __half2 buf1h[64 * H1];   // 17920 B (total 40960 -> 4 blocks/CU)
  __half2* buf2h = buf0h;

  const int bid = blockIdx.x, nwg = gridDim.x;
  const int wg = ((nwg & 7) == 0) ? ((bid & 7) * (nwg >> 3) + (bid >> 3)) : bid;
  const int bz = wg / NINT1;
  const int t0 = wg - bz * NINT1;
  const int bx = 1 + t0 / (NBY - 2);
  const int by = 1 + t0 % (NBY - 2);

  const int tid = threadIdx.x;
  const int x0 = bx * TSC, y0 = by * TSR;
  const size_t img = (size_t)bz * ((size_t)HH * WW);

#pragma unroll
  for (int s = 0; s < 12; ++s) {
    const int idx = s * 256 + tid;
    if (idx < 80 * 36) {
      const int r = idx / 36, c4 = idx - r * 36;
      const size_t g = img + (size_t)(y0 - 24 + r) * WW + (x0 - 8 + c4 * 4);
      const float4 xv = *(const float4*)(Xg + g);
      const float4 yv = *(const float4*)(Yg + g);
      buf0h[r * H0 + c4 * 2]     = pack2(yv.x - xv.x, yv.y - xv.y);
      buf0h[r * H0 + c4 * 2 + 1] = pack2(yv.z - xv.z, yv.w - xv.w);
    }
  }
  __syncthreads();

#pragma unroll 1
  for (int tt = tid; tt < 544; tt += 256) {
    const int rg = tt / 34, cg = tt - rg * 34;
    const int r0 = rg * 4, c0 = cg * 4;
    float acc[4][4] = {};
#pragma unroll
    for (int rr = 0; rr < 20; ++rr) {
      const __half2* lp = &buf0h[(r0 + rr) * H0 + (c0 >> 1)];
      const float2 p0 = __half22float2(lp[1]);
      const float2 p1 = __half22float2(lp[2]);
      const float2 p2 = __half22float2(lp[3]);
      const float2 p3 = __half22float2(lp[4]);
      const float win[8] = {p0.x, p0.y, p1.x, p1.y, p2.x, p2.y, p3.x, p3.y};
#pragma unroll
      for (int t = 0; t < 4; ++t) {
        const int i = rr - t;
        if (i >= 0 && i <= 16) {
          const int js = js_fn(0, i), nt = nt_fn(0, i);
#pragma unroll
          for (int jj = 0; jj < nt; ++jj) {
            const float wv = w.wA[i][js + jj];
#pragma unroll
            for (int c = 0; c < 4; ++c)
              acc[t][c] = fmaf(wv, win[c + js + jj], acc[t][c]);
          }
        }
      }
    }
#pragma unroll
    for (int t = 0; t < 4; ++t) {
      const __half2* cp = &buf0h[(r0 + t + 8) * H0 + (c0 >> 1)];
      const float2 c01 = __half22float2(cp[2]);
      const float2 c23 = __half22float2(cp[3]);
      buf1h[(r0 + t) * H1 + (c0 >> 1)]     = pack2(c01.x - acc[t][0], c01.y - acc[t][1]);
      buf1h[(r0 + t) * H1 + (c0 >> 1) + 1] = pack2(c23.x - acc[t][2], c23.y - acc[t][3]);
    }
  }
  __syncthreads();

#pragma unroll 1
  for (int tt = tid; tt < 396; tt += 256) {
    const int rg = tt / 33, cg = tt - rg * 33;
    const int r0 = rg * 4, c0 = cg * 4;
    float acc[4][4] = {};
#pragma unroll
    for (int rr = 0; rr < 20; ++rr) {
      const __half2* lp = &buf1h[(r0 + rr) * H1 + (c0 >> 1)];
      const float2 a = __half22float2(lp[1]);
      const float2 b = __half22float2(lp[2]);
      const float win[4] = {a.x, a.y, b.x, b.y};
#pragma unroll
      for (int t = 0; t < 4; ++t) {
        const int i = rr - t;
        if (i >= 0 && i <= 16) {
          const float wv = w.wB[i];
          acc[t][0] = fmaf(wv, win[0], acc[t][0]);
          acc[t][1] = fmaf(wv, win[1], acc[t][1]);
          acc[t][2] = fmaf(wv, win[2], acc[t][2]);
          acc[t][3] = fmaf(wv, win[3], acc[t][3]);
        }
      }
    }
#pragma unroll
    for (int t = 0; t < 4; ++t) {
      const __half2* cp = &buf1h[(r0 + t + 8) * H1 + (c0 >> 1)];
      const float2 ca = __half22float2(cp[1]);
      const float2 cb = __half22float2(cp[2]);
      buf2h[(r0 + t) * H1 + (c0 >> 1)]     = pack2(ca.x - acc[t][0], ca.y - acc[t][1]);
      buf2h[(r0 + t) * H1 + (c0 >> 1) + 1] = pack2(cb.x - acc[t][2], cb.y - acc[t][3]);
    }
  }
  __syncthreads();

  {
    const int tg = tid >> 5, tc = tid & 31;
    const int r0 = tg * 4, c0 = tc * 4;
    float acc[4][4] = {};
#pragma unroll
    for (int rr = 0; rr < 20; ++rr) {
      const __half2* lp = &buf2h[(r0 + rr) * H1 + (c0 >> 1)];
      const float2 p0 = __half22float2(lp[0]);
      const float2 p1 = __half22float2(lp[1]);
      const float2 p2 = __half22float2(lp[2]);
      const float2 p3 = __half22float2(lp[3]);
      const float win[8] = {p0.x, p0.y, p1.x, p1.y, p2.x, p2.y, p3.x, p3.y};
#pragma unroll
      for (int t = 0; t < 4; ++t) {
        const int i = rr - t;
        if (i >= 0 && i <= 16) {
          const int js = js_fn(2, i), nt = nt_fn(2, i);
#pragma unroll
          for (int jj = 0; jj < nt; ++jj) {
            const float wv = w.wC[i][js + jj];
#pragma unroll
            for (int c = 0; c < 4; ++c)
              acc[t][c] = fmaf(wv, win[c + js + jj], acc[t][c]);
          }
        }
      }
    }
#pragma unroll
    for (int t = 0; t < 4; ++t) {
      const __half2* cp = &buf2h[(r0 + t + 8) * H1 + (c0 >> 1)];
      const float2 ca = __half22float2(cp[1]);
      const float2 cb = __half22float2(cp[2]);
      const int gy = y0 + r0 + t, gx = x0 + c0;
      const float4 yv = *(const float4*)(Yg + img + (size_t)gy * WW + gx);
      *(float4*)(Out + img + (size_t)gy * WW + gx) = make_float4(
          yv.x - ca.x + acc[t][0], yv.y - ca.y + acc[t][1],
          yv.z - cb.x + acc[t][2], yv.w - cb.y + acc[t][3]);
    }
  }
}

// ====== FUSED boundary kernel, 64x16 tiles (low-latency, high-parallel) ======
// Tile layout of the boundary ring (rows 0..31, 2016..2047; cols 0..127,
// 1920..2047 for middle rows). buf0: D0 64 x 80 halfs; buf1: D1 48 x 76;
// buf2 (alias): D2 32 x 76. Same anchoring scheme as interior, TSC=64, TSR=16.
__global__ __launch_bounds__(256, 4)
void fused_bnd64(const float* __restrict__ Xg, const float* __restrict__ Yg,
                 const float* __restrict__ Nn, float* __restrict__ Out, W3 w)
{
  __shared__ __half2 buf0h[64 * G0];   // 10240 B
  __shared__ __half2 buf1h[48 * G1];   //  7296 B
  __half2* buf2h = buf0h;              // 32*38*4 = 4864 <= 10240

  const int u = blockIdx.x;            // 0..623
  int x0, y0;
  if (u < 64)       { y0 = (u >> 5) * 16;          x0 = (u & 31) * 64; }
  else if (u < 128) { const int v = u - 64;
                      y0 = 2016 + (v >> 5) * 16;   x0 = (v & 31) * 64; }
  else              { const int v = u - 128;       // 496 side tiles
                      const int side = v & 1, idx = v >> 1;   // idx 0..247
                      const int col = idx & 1, row = idx >> 1; // row 0..123
                      y0 = 32 + row * 16;
                      x0 = side ? (1920 + col * 64) : (col * 64); }
  const int bz = blockIdx.y;

  const int tid = threadIdx.x;
  const size_t img = (size_t)bz * ((size_t)HH * WW);
  const float* N0 = Nn;
  const float* N1 = Nn + (size_t)HH * WW;
  const float* N2 = Nn + 2 * (size_t)HH * WW;

  // ---- checked staging of D0: 64 rows x 20 float4 cols, zero-filled OOB ----
#pragma unroll
  for (int s = 0; s < 5; ++s) {
    const int idx = s * 256 + tid;
    // 64*20 = 1280 = 5*256 exactly
    const int r = idx / 20, c4 = idx - r * 20;
    const int gy = y0 - 24 + r;
    const int gx = x0 - 8 + c4 * 4;
    float4 v = make_float4(0.f, 0.f, 0.f, 0.f);
    if (gy >= 0 && gy < HH) {
      const float* xr = Xg + img + (size_t)gy * WW;
      const float* yr = Yg + img + (size_t)gy * WW;
      if (gx >= 0 && gx + 4 <= WW) {
        const float4 xv = *(const float4*)(xr + gx);
        const float4 yv = *(const float4*)(yr + gx);
        v = make_float4(yv.x - xv.x, yv.y - xv.y, yv.z - xv.z, yv.w - xv.w);
      } else {
        float tv[4] = {0.f, 0.f, 0.f, 0.f};
#pragma unroll
        for (int e = 0; e < 4; ++e) {
          const int gxe = gx + e;
          if (gxe >= 0 && gxe < WW) tv[e] = yr[gxe] - xr[gxe];
        }
        v = make_float4(tv[0], tv[1], tv[2], tv[3]);
      }
    }
    buf0h[r * G0 + c4 * 2]     = pack2(v.x, v.y);
    buf0h[r * G0 + c4 * 2 + 1] = pack2(v.z, v.w);
  }
  __syncthreads();

  // ---- pass A: D1 48 rows x 72 cols, per-pixel N0 ---- (12rg x 18cg = 216)
  if (tid < 216) {
    const int rg = tid / 18, cg = tid - rg * 18;
    const int r0 = rg * 4, c0 = cg * 4;
    float acc[4][4] = {};
#pragma unroll
    for (int rr = 0; rr < 20; ++rr) {
      const __half2* lp = &buf0h[(r0 + rr) * G0 + (c0 >> 1)];
      const float2 p0 = __half22float2(lp[1]);
      const float2 p1 = __half22float2(lp[2]);
      const float2 p2 = __half22float2(lp[3]);
      const float2 p3 = __half22float2(lp[4]);
      const float win[8] = {p0.x, p0.y, p1.x, p1.y, p2.x, p2.y, p3.x, p3.y};
#pragma unroll
      for (int t = 0; t < 4; ++t) {
        const int i = rr - t;
        if (i >= 0 && i <= 16) {
          const int js = js_fn(0, i), nt = nt_fn(0, i);
#pragma unroll
          for (int jj = 0; jj < nt; ++jj) {
            const float wv = w.wA[i][js + jj];
#pragma unroll
            for (int c = 0; c < 4; ++c)
              acc[t][c] = fmaf(wv, win[c + js + jj], acc[t][c]);
          }
        }
      }
    }
#pragma unroll
    for (int t = 0; t < 4; ++t) {
      const int gy = y0 - 16 + r0 + t;
      const bool rok = (gy >= 0) && (gy < HH);
      const __half2* cp = &buf0h[(r0 + t + 8) * G0 + (c0 >> 1)];
      const float2 c01 = __half22float2(cp[2]);
      const float2 c23 = __half22float2(cp[3]);
      const float cenv[4] = {c01.x, c01.y, c23.x, c23.y};
      float d[4];
#pragma unroll
      for (int c = 0; c < 4; ++c) {
        const int gxc = x0 - 4 + c0 + c;
        const bool ok = rok && (gxc >= 0) && (gxc < WW);
        float r = 0.0f;
        if (ok) {
          const float n = N0[(size_t)gy * WW + gxc];
          r = cenv[c] - acc[t][c] * w.knA * fastrcp(n);
        }
        d[c] = r;
      }
      buf1h[(r0 + t) * G1 + (c0 >> 1)]     = pack2(d[0], d[1]);
      buf1h[(r0 + t) * G1 + (c0 >> 1) + 1] = pack2(d[2], d[3]);
    }
  }
  __syncthreads();

  // ---- pass B: D2 32 rows x 68 cols, per-pixel N1 ---- (8rg x 17cg = 136)
  if (tid < 136) {
    const int rg = tid / 17, cg = tid - rg * 17;
    const int r0 = rg * 4, c0 = cg * 4;
    float acc[4][4] = {};
#pragma unroll
    for (int rr = 0; rr < 20; ++rr) {
      const __half2* lp = &buf1h[(r0 + rr) * G1 + (c0 >> 1)];
      const float2 a = __half22float2(lp[1]);
      const float2 b = __half22float2(lp[2]);
      const float win[4] = {a.x, a.y, b.x, b.y};
#pragma unroll
      for (int t = 0; t < 4; ++t) {
        const int i = rr - t;
        if (i >= 0 && i <= 16) {
          const float wv = w.wB[i];
          acc[t][0] = fmaf(wv, win[0], acc[t][0]);
          acc[t][1] = fmaf(wv, win[1], acc[t][1]);
          acc[t][2] = fmaf(wv, win[2], acc[t][2]);
          acc[t][3] = fmaf(wv, win[3], acc[t][3]);
        }
      }
    }
#pragma unroll
    for (int t = 0; t < 4; ++t) {
      const int gy = y0 - 8 + r0 + t;
      const bool rok = (gy >= 0) && (gy < HH);
      const __half2* cp = &buf1h[(r0 + t + 8) * G1 + (c0 >> 1)];
      const float2 ca = __half22float2(cp[1]);
      const float2 cb = __half22float2(cp[2]);
      const float cenv[4] = {ca.x, ca.y, cb.x, cb.y};
      float d[4];
#pragma unroll
      for (int c = 0; c < 4; ++c) {
        const int gxc = x0 - 2 + c0 + c;
        const bool ok = rok && (gxc >= 0) && (gxc < WW);
        float r = 0.0f;
        if (ok) {
          const float n = N1[(size_t)gy * WW + gxc];
          r = cenv[c] - acc[t][c] * w.knB * fastrcp(n);
        }
        d[c] = r;
      }
      buf2h[(r0 + t) * G1 + (c0 >> 1)]     = pack2(d[0], d[1]);
      buf2h[(r0 + t) * G1 + (c0 >> 1) + 1] = pack2(d[2], d[3]);
    }
  }
  __syncthreads();

  // ---- pass C: out 16 x 64, per-pixel N2 ---- (4rg x 16cg = 64)
  if (tid < 64) {
    const int rg = tid >> 4, tc = tid & 15;
    const int r0 = rg * 4, c0 = tc * 4;
    float acc[4][4] = {};
#pragma unroll
    for (int rr = 0; rr < 20; ++rr) {
      const __half2* lp = &buf2h[(r0 + rr) * G1 + (c0 >> 1)];
      const float2 p0 = __half22float2(lp[0]);
      const float2 p1 = __half22float2(lp[1]);
      const float2 p2 = __half22float2(lp[2]);
      const float2 p3 = __half22float2(lp[3]);
      const float win[8] = {p0.x, p0.y, p1.x, p1.y, p2.x, p2.y, p3.x, p3.y};
#pragma unroll
      for (int t = 0; t < 4; ++t) {
        const int i = rr - t;
        if (i >= 0 && i <= 16) {
          const int js = js_fn(2, i), nt = nt_fn(2, i);
#pragma unroll
          for (int jj = 0; jj < nt; ++jj) {
            const float wv = w.wC[i][js + jj];
#pragma unroll
            for (int c = 0; c < 4; ++c)
              acc[t][c] = fmaf(wv, win[c + js + jj], acc[t][c]);
          }
        }
      }
    }
#pragma unroll
    for (int t = 0; t < 4; ++t) {
      const __half2* cp = &buf2h[(r0 + t + 8) * G1 + (c0 >> 1)];
      const float2 ca = __half22float2(cp[1]);
      const float2 cb = __half22float2(cp[2]);
      const int gy = y0 + r0 + t, gx = x0 + c0;
      const float4 yv = *(const float4*)(Yg + img + (size_t)gy * WW + gx);
      const float4 nv = *(const float4*)(N2 + (size_t)gy * WW + gx);
      *(float4*)(Out + img + (size_t)gy * WW + gx) = make_float4(
          yv.x - ca.x + acc[t][0] * w.knC * fastrcp(nv.x),
          yv.y - ca.y + acc[t][1] * w.knC * fastrcp(nv.y),
          yv.z - cb.x + acc[t][2] * w.knC * fastrcp(nv.z),
          yv.w - cb.y + acc[t][3] * w.knC * fastrcp(nv.w));
    }
  }
}

// ===================== fallback path (r9, dense-capable, fp32) ==============
__global__ __launch_bounds__(256)
void diff_kernel(const float* __restrict__ X, const float* __restrict__ Y,
                 float* __restrict__ D, int n4)
{
  const int stride = gridDim.x * 256;
  for (int i = blockIdx.x * 256 + threadIdx.x; i < n4; i += stride) {
    const float4 x = ((const float4*)X)[i];
    const float4 y = ((const float4*)Y)[i];
    ((float4*)D)[i] = make_float4(y.x - x.x, y.y - x.y, y.z - x.z, y.w - x.w);
  }
}

template <int MODE>
__global__ __launch_bounds__(256, 3)
void conv_dense(const float* __restrict__ P0, const float* __restrict__ P1,
                const float* __restrict__ Nrm, float* __restrict__ Out, Wts wts)
{
  constexpr int LSTR = 148, LCW = 36, XOFF = 8, CH = 48 * LCW;
  __shared__ float lds[48 * 148];
  const int bx = blockIdx.x, by = blockIdx.y, bz = blockIdx.z;
  const int tid = threadIdx.x;
  const int x0 = bx * TSC, y0 = by * TSR;
  const size_t img = (size_t)bz * ((size_t)HH * WW);
  const float* A = P0 + img;
#pragma unroll
  for (int s = 0; s < (CH + 255) / 256; ++s) {
    const int idx = s * 256 + tid;
    if (idx < CH) {
      const int r = idx / LCW, c4 = idx - r * LCW;
      const int gy = y0 - 8 + r, gx = x0 - XOFF + c4 * 4;
      float4 v = make_float4(0.f, 0.f, 0.f, 0.f);
      if (gy >= 0 && gy < HH) {
        const float* ar = A + (size_t)gy * WW;
        if (gx >= 0 && gx + 4 <= WW) v = *(const float4*)(ar + gx);
        else {
          float tv[4] = {0.f, 0.f, 0.f, 0.f};
#pragma unroll
          for (int e = 0; e < 4; ++e) {
            const int gxe = gx + e;
            if (gxe >= 0 && gxe < WW) tv[e] = ar[gxe];
          }
          v = make_float4(tv[0], tv[1], tv[2], tv[3]);
        }
      }
      *(float4*)&lds[r * LSTR + c4 * 4] = v;
    }
  }
  __syncthreads();
  const int tc = tid & 31, tg = tid >> 5, lc = tc * 4;
  float acc[4][4] = {};
#pragma unroll
  for (int rr = 0; rr < 20; ++rr) {
    const float* lp = &lds[(tg * 4 + rr) * LSTR];
    const float4 w0 = *(const float4*)(lp + 4 + lc);
    const float4 w1 = *(const float4*)(lp + 8 + lc);
    const float4 w2 = *(const float4*)(lp + 12 + lc);
    const float win[8] = {w0.z, w0.w, w1.x, w1.y, w1.z, w1.w, w2.x, w2.y};
#pragma unroll
    for (int t = 0; t < 4; ++t) {
      const int i = rr - t;
      if (i >= 0 && i <= 16) {
#pragma unroll
        for (int jj = 0; jj < 5; ++jj) {
          const float wv = wts.w[i][jj];
#pragma unroll
          for (int c = 0; c < 4; ++c)
            acc[t][c] = fmaf(wv, win[c + jj], acc[t][c]);
        }
      }
    }
  }
  float* Ob = Out + img;
  const int gx = x0 + lc;
  const float kn = wts.knorm;
#pragma unroll
  for (int t = 0; t < 4; ++t) {
    const int yo = y0 + tg * 4 + t;
    const float4 cv = *(const float4*)&lds[(tg * 4 + t + 8) * LSTR + XOFF + lc];
    const float4 nv = *(const float4*)(Nrm + (size_t)yo * WW + gx);
    const float a0 = acc[t][0] * kn * fastrcp(nv.x);
    const float a1 = acc[t][1] * kn * fastrcp(nv.y);
    const float a2 = acc[t][2] * kn * fastrcp(nv.z);
    const float a3 = acc[t][3] * kn * fastrcp(nv.w);
    float4 o;
    if (MODE == 2) {
      const float4 yv = *(const float4*)(P1 + img + (size_t)yo * WW + gx);
      o = make_float4(yv.x - cv.x + a0, yv.y - cv.y + a1,
                      yv.z - cv.z + a2, yv.w - cv.w + a3);
    } else {
      o = make_float4(cv.x - a0, cv.y - a1, cv.z - a2, cv.w - a3);
    }
    *(float4*)(Ob + (size_t)yo * WW + gx) = o;
  }
}

// ---------------- host-side replication of _build_kernels ----------------
static void rotate33(const double* src, double* dst, double ang_deg) {
  const int n = 33;
  const double t = ang_deg * 3.14159265358979323846 / 180.0;
  const double cs = cos(t), sn = sin(t);
  for (int y = 0; y < n; ++y) {
    for (int x = 0; x < n; ++x) {
      const double y0 = y - 16.0, x0 = x - 16.0;
      const double sy = cs * y0 + sn * x0 + 16.0;
      const double sx = -sn * y0 + cs * x0 + 16.0;
      const double fy = floor(sy), fx = floor(sx);
      const int y0i = (int)fy, x0i = (int)fx;
      const double wy = sy - fy, wx = sx - fx;
      double o = 0.0;
      for (int dy = 0; dy < 2; ++dy)
        for (int dx = 0; dx < 2; ++dx) {
          const int yy = y0i + dy, xx = x0i + dx;
          if (yy < 0 || yy >= n || xx < 0 || xx >= n) continue;
          const double wgt = (dy ? wy : 1.0 - wy) * (dx ? wx : 1.0 - wx);
          o += wgt * src[yy * n + xx];
        }
      dst[y * n + x] = o;
    }
  }
}

static void build_K(float K[3][17][5]) {
  const double angs[3] = {-10.0, 0.0, 10.0};
  double base[33 * 33], rot[33 * 33];
  for (int i = 0; i < 33 * 33; ++i) base[i] = 0.0;
  for (int y = 0; y < 33; ++y) base[y * 33 + 16] = 1.0;
  for (int a = 0; a < 3; ++a) {
    if (a == 1) memcpy(rot, base, sizeof(rot));
    else        rotate33(base, rot, angs[a]);
    double k17[17][17];
    for (int y = 0; y < 17; ++y)
      for (int x = 0; x < 17; ++x) k17[y][x] = rot[(y + 8) * 33 + (x + 8)];
    int r = 0, c = 0;
    for (int y = 0; y < 17; ++y) { bool nz = false; for (int x = 0; x < 17; ++x) if (k17[y][x] != 0.0) nz = true; r += nz; }
    for (int x = 0; x < 17; ++x) { bool nz = false; for (int y = 0; y < 17; ++y) if (k17[y][x] != 0.0) nz = true; c += nz; }
    r = r / 2 * 2; c = c / 2 * 2;
    const int kh = r + 1, kw = c + 1;
    for (int y = 0; y < 17; ++y)
      for (int x = 0; x < 5; ++x) K[a][y][x] = 0.0f;
    if (kh <= 17 && kw <= 5) {
      const int oh = (17 - kh) / 2, ow = (5 - kw) / 2;
      for (int y = 0; y < kh; ++y)
        for (int x = 0; x < kw; ++x)
          K[a][oh + y][ow + x] = (float)k17[8 - r / 2 + y][8 - c / 2 + x];
    }
  }
}

static int pick_mode(int a, const float K[17][5]) {
  for (int i = 0; i < 17; ++i) {
    const int js = js_fn(a, i), nt = nt_fn(a, i);
    for (int j = 0; j < 5; ++j)
      if ((j < js || j >= js + nt) && K[i][j] != 0.0f) return 1;
  }
  return 0;
}

extern "C" void kernel_launch(void* const* d_in, const int* in_sizes, int n_in,
                              void* d_out, int out_size, void* d_ws, size_t ws_size,
                              hipStream_t stream) {
  const float* X  = (const float*)d_in[0];
  const float* Y  = (const float*)d_in[1];
  const float* Nn = (const float*)d_in[3];
  float* out = (float*)d_out;
  float* tmp = (float*)d_ws;
  const size_t HW = (size_t)HH * WW;
  const int B = in_sizes[0] / (int)HW;   // 2

  float K[3][17][5];
  build_K(K);
  double ks[3];
  for (int a = 0; a < 3; ++a) {
    ks[a] = 0.0;
    for (int i = 0; i < 17; ++i)
      for (int j = 0; j < 5; ++j) ks[a] += K[a][i][j];
  }
  const int dense = pick_mode(0, K[0]) | pick_mode(1, K[1]) | pick_mode(2, K[2]);

  if (!dense) {
    W3 w;
    for (int i = 0; i < 17; ++i)
      for (int j = 0; j < 5; ++j) {
        w.wA[i][j] = (float)(K[0][i][j] / ks[0]);
        w.wC[i][j] = (float)(K[2][i][j] / ks[2]);
      }
    for (int i = 0; i < 17; ++i) w.wB[i] = (float)(K[1][i][2] / ks[1]);
    w.knA = (float)ks[0]; w.knB = (float)ks[1]; w.knC = (float)ks[2];

    fused_bnd64<<<dim3(NB64, B), dim3(256), 0, stream>>>(X, Y, Nn, out, w);
    fused_int<<<dim3(NINT1 * B), dim3(256), 0, stream>>>(X, Y, out, w);
  } else {
    Wts w[3];
    for (int a = 0; a < 3; ++a) {
      for (int i = 0; i < 17; ++i)
        for (int j = 0; j < 5; ++j) w[a].w[i][j] = (float)(K[a][i][j] / ks[a]);
      w[a].knorm = (float)ks[a];
    }
    const int n4 = (int)(B * HW / 4);
    const int dg = (n4 + 255) / 256;
    diff_kernel<<<dim3(dg > 8192 ? 8192 : dg), dim3(256), 0, stream>>>(X, Y, tmp, n4);
    dim3 g(NBX, NBY, B), blk(256);
    conv_dense<1><<<g, blk, 0, stream>>>(tmp, nullptr, Nn,          out, w[0]);
    conv_dense<1><<<g, blk, 0, stream>>>(out, nullptr, Nn + HW,     tmp, w[1]);
    conv_dense<2><<<g, blk, 0, stream>>>(tmp, Y,       Nn + 2 * HW, out, w[2]);
  }
}

// Round 14
// 74.622 us; speedup vs baseline: 1.3747x; 1.0852x over previous
//
#include <hip/hip_runtime.h>
#include <hip/hip_fp16.h>
#include <math.h>
#include <string.h>

#define HH 2048
#define WW 2048
#define TSC 128
#define TSR 32
#define NBX (WW / TSC)                 // 16
#define NBY (HH / TSR)                 // 64
#define NINT1 ((NBX - 2) * (NBY - 2))  // 868 interior 128x32 tiles per image
#define NB64 624                       // boundary 64x16 tiles per image
#define TOT1 (NINT1 + NB64)            // 1492 blocks per image

// interior half2 row strides: buf0 144 halfs = 72, buf1/2 140 halfs = 70
#define H0 72
#define H1 70
// boundary half2 strides: buf0 80 halfs = 40, buf1/2 76 halfs = 38
#define G0 40
#define G1 38

struct W3 { float wA[17][5]; float wC[17][5]; float wB[17]; float knA, knB, knC; };
struct Wts { float w[17][5]; float knorm; };   // fallback path

// angle index a: 0 -> -10deg, 1 -> 0deg, 2 -> +10deg
__host__ __device__ constexpr int js_fn(int a, int i) {
  return (a == 1) ? 2
       : (a == 2) ? ((i < 3) ? 0 : (i < 9) ? 1 : (i < 14) ? 2 : 3)
                  : ((i < 3) ? 3 : (i < 8) ? 2 : (i < 14) ? 1 : 0);
}
__host__ __device__ constexpr int nt_fn(int a, int i) {
  return (a == 1) ? 1 : (i == 8) ? 3 : 2;
}

__device__ __forceinline__ float fastrcp(float x) {
#if __has_builtin(__builtin_amdgcn_rcpf)
  return __builtin_amdgcn_rcpf(x);
#else
  return 1.0f / x;
#endif
}

__device__ __forceinline__ __half2 pack2(float a, float b) {
  return __float22half2_rn(make_float2(a, b));
}

// ====== ONE dispatch: interior (r12 body) + boundary (r13 body) blocks ======
// Top-level block-uniform branch; each path fully self-contained (disjoint
// register regions -> no r6/r7-style live-range-union spill). LDS arena 40960B
// shared between paths.
__global__ __launch_bounds__(256, 4)
void fused_all(const float* __restrict__ Xg, const float* __restrict__ Yg,
               const float* __restrict__ Nn, float* __restrict__ Out, W3 w)
{
  __shared__ __half2 ldsh[10240];      // 40960 B -> 4 blocks/CU

  const int bid = blockIdx.x, nwg = gridDim.x;
  const int wg = ((nwg & 7) == 0) ? ((bid & 7) * (nwg >> 3) + (bid >> 3)) : bid;
  const int bz = wg / TOT1;
  const int t0 = wg - bz * TOT1;
  const int tid = threadIdx.x;
  const size_t img = (size_t)bz * ((size_t)HH * WW);

  if (t0 < NINT1) {
    // ==================== INTERIOR 128x32 (r12, proven) ====================
    __half2* buf0h = ldsh;             // 80 x H0 = 5760
    __half2* buf1h = ldsh + 5760;      // 64 x H1 = 4480 (total 10240)
    __half2* buf2h = buf0h;

    const int bx = 1 + t0 / (NBY - 2);
    const int by = 1 + t0 % (NBY - 2);
    const int x0 = bx * TSC, y0 = by * TSR;

#pragma unroll
    for (int s = 0; s < 12; ++s) {
      const int idx = s * 256 + tid;
      if (idx < 80 * 36) {
        const int r = idx / 36, c4 = idx - r * 36;
        const size_t g = img + (size_t)(y0 - 24 + r) * WW + (x0 - 8 + c4 * 4);
        const float4 xv = *(const float4*)(Xg + g);
        const float4 yv = *(const float4*)(Yg + g);
        buf0h[r * H0 + c4 * 2]     = pack2(yv.x - xv.x, yv.y - xv.y);
        buf0h[r * H0 + c4 * 2 + 1] = pack2(yv.z - xv.z, yv.w - xv.w);
      }
    }
    __syncthreads();

#pragma unroll 1
    for (int tt = tid; tt < 544; tt += 256) {
      const int rg = tt / 34, cg = tt - rg * 34;
      const int r0 = rg * 4, c0 = cg * 4;
      float acc[4][4] = {};
#pragma unroll
      for (int rr = 0; rr < 20; ++rr) {
        const __half2* lp = &buf0h[(r0 + rr) * H0 + (c0 >> 1)];
        const float2 p0 = __half22float2(lp[1]);
        const float2 p1 = __half22float2(lp[2]);
        const float2 p2 = __half22float2(lp[3]);
        const float2 p3 = __half22float2(lp[4]);
        const float win[8] = {p0.x, p0.y, p1.x, p1.y, p2.x, p2.y, p3.x, p3.y};
#pragma unroll
        for (int t = 0; t < 4; ++t) {
          const int i = rr - t;
          if (i >= 0 && i <= 16) {
            const int js = js_fn(0, i), nt = nt_fn(0, i);
#pragma unroll
            for (int jj = 0; jj < nt; ++jj) {
              const float wv = w.wA[i][js + jj];
#pragma unroll
              for (int c = 0; c < 4; ++c)
                acc[t][c] = fmaf(wv, win[c + js + jj], acc[t][c]);
            }
          }
        }
      }
#pragma unroll
      for (int t = 0; t < 4; ++t) {
        const __half2* cp = &buf0h[(r0 + t + 8) * H0 + (c0 >> 1)];
        const float2 c01 = __half22float2(cp[2]);
        const float2 c23 = __half22float2(cp[3]);
        buf1h[(r0 + t) * H1 + (c0 >> 1)]     = pack2(c01.x - acc[t][0], c01.y - acc[t][1]);
        buf1h[(r0 + t) * H1 + (c0 >> 1) + 1] = pack2(c23.x - acc[t][2], c23.y - acc[t][3]);
      }
    }
    __syncthreads();

#pragma unroll 1
    for (int tt = tid; tt < 396; tt += 256) {
      const int rg = tt / 33, cg = tt - rg * 33;
      const int r0 = rg * 4, c0 = cg * 4;
      float acc[4][4] = {};
#pragma unroll
      for (int rr = 0; rr < 20; ++rr) {
        const __half2* lp = &buf1h[(r0 + rr) * H1 + (c0 >> 1)];
        const float2 a = __half22float2(lp[1]);
        const float2 b = __half22float2(lp[2]);
        const float win[4] = {a.x, a.y, b.x, b.y};
#pragma unroll
        for (int t = 0; t < 4; ++t) {
          const int i = rr - t;
          if (i >= 0 && i <= 16) {
            const float wv = w.wB[i];
            acc[t][0] = fmaf(wv, win[0], acc[t][0]);
            acc[t][1] = fmaf(wv, win[1], acc[t][1]);
            acc[t][2] = fmaf(wv, win[2], acc[t][2]);
            acc[t][3] = fmaf(wv, win[3], acc[t][3]);
          }
        }
      }
#pragma unroll
      for (int t = 0; t < 4; ++t) {
        const __half2* cp = &buf1h[(r0 + t + 8) * H1 + (c0 >> 1)];
        const float2 ca = __half22float2(cp[1]);
        const float2 cb = __half22float2(cp[2]);
        buf2h[(r0 + t) * H1 + (c0 >> 1)]     = pack2(ca.x - acc[t][0], ca.y - acc[t][1]);
        buf2h[(r0 + t) * H1 + (c0 >> 1) + 1] = pack2(cb.x - acc[t][2], cb.y - acc[t][3]);
      }
    }
    __syncthreads();

    {
      const int tg = tid >> 5, tc = tid & 31;
      const int r0 = tg * 4, c0 = tc * 4;
      float acc[4][4] = {};
#pragma unroll
      for (int rr = 0; rr < 20; ++rr) {
        const __half2* lp = &buf2h[(r0 + rr) * H1 + (c0 >> 1)];
        const float2 p0 = __half22float2(lp[0]);
        const float2 p1 = __half22float2(lp[1]);
        const float2 p2 = __half22float2(lp[2]);
        const float2 p3 = __half22float2(lp[3]);
        const float win[8] = {p0.x, p0.y, p1.x, p1.y, p2.x, p2.y, p3.x, p3.y};
#pragma unroll
        for (int t = 0; t < 4; ++t) {
          const int i = rr - t;
          if (i >= 0 && i <= 16) {
            const int js = js_fn(2, i), nt = nt_fn(2, i);
#pragma unroll
            for (int jj = 0; jj < nt; ++jj) {
              const float wv = w.wC[i][js + jj];
#pragma unroll
              for (int c = 0; c < 4; ++c)
                acc[t][c] = fmaf(wv, win[c + js + jj], acc[t][c]);
            }
          }
        }
      }
#pragma unroll
      for (int t = 0; t < 4; ++t) {
        const __half2* cp = &buf2h[(r0 + t + 8) * H1 + (c0 >> 1)];
        const float2 ca = __half22float2(cp[1]);
        const float2 cb = __half22float2(cp[2]);
        const int gy = y0 + r0 + t, gx = x0 + c0;
        const float4 yv = *(const float4*)(Yg + img + (size_t)gy * WW + gx);
        *(float4*)(Out + img + (size_t)gy * WW + gx) = make_float4(
            yv.x - ca.x + acc[t][0], yv.y - ca.y + acc[t][1],
            yv.z - cb.x + acc[t][2], yv.w - cb.y + acc[t][3]);
      }
    }
  } else {
    // ==================== BOUNDARY 64x16 (r13, proven) ====================
    __half2* buf0h = ldsh;             // 64 x G0 = 2560
    __half2* buf1h = ldsh + 2560;      // 48 x G1 = 1824
    __half2* buf2h = buf0h;            // 32*G1 = 1216 <= 2560

    const int u = t0 - NINT1;          // 0..623
    int x0, y0;
    if (u < 64)       { y0 = (u >> 5) * 16;          x0 = (u & 31) * 64; }
    else if (u < 128) { const int v = u - 64;
                        y0 = 2016 + (v >> 5) * 16;   x0 = (v & 31) * 64; }
    else              { const int v = u - 128;
                        const int side = v & 1, idx = v >> 1;
                        const int col = idx & 1, row = idx >> 1;
                        y0 = 32 + row * 16;
                        x0 = side ? (1920 + col * 64) : (col * 64); }

    const float* N0 = Nn;
    const float* N1 = Nn + (size_t)HH * WW;
    const float* N2 = Nn + 2 * (size_t)HH * WW;

#pragma unroll
    for (int s = 0; s < 5; ++s) {
      const int idx = s * 256 + tid;
      const int r = idx / 20, c4 = idx - r * 20;
      const int gy = y0 - 24 + r;
      const int gx = x0 - 8 + c4 * 4;
      float4 v = make_float4(0.f, 0.f, 0.f, 0.f);
      if (gy >= 0 && gy < HH) {
        const float* xr = Xg + img + (size_t)gy * WW;
        const float* yr = Yg + img + (size_t)gy * WW;
        if (gx >= 0 && gx + 4 <= WW) {
          const float4 xv = *(const float4*)(xr + gx);
          const float4 yv = *(const float4*)(yr + gx);
          v = make_float4(yv.x - xv.x, yv.y - xv.y, yv.z - xv.z, yv.w - xv.w);
        } else {
          float tv[4] = {0.f, 0.f, 0.f, 0.f};
#pragma unroll
          for (int e = 0; e < 4; ++e) {
            const int gxe = gx + e;
            if (gxe >= 0 && gxe < WW) tv[e] = yr[gxe] - xr[gxe];
          }
          v = make_float4(tv[0], tv[1], tv[2], tv[3]);
        }
      }
      buf0h[r * G0 + c4 * 2]     = pack2(v.x, v.y);
      buf0h[r * G0 + c4 * 2 + 1] = pack2(v.z, v.w);
    }
    __syncthreads();

    if (tid < 216) {
      const int rg = tid / 18, cg = tid - rg * 18;
      const int r0 = rg * 4, c0 = cg * 4;
      float acc[4][4] = {};
#pragma unroll
      for (int rr = 0; rr < 20; ++rr) {
        const __half2* lp = &buf0h[(r0 + rr) * G0 + (c0 >> 1)];
        const float2 p0 = __half22float2(lp[1]);
        const float2 p1 = __half22float2(lp[2]);
        const float2 p2 = __half22float2(lp[3]);
        const float2 p3 = __half22float2(lp[4]);
        const float win[8] = {p0.x, p0.y, p1.x, p1.y, p2.x, p2.y, p3.x, p3.y};
#pragma unroll
        for (int t = 0; t < 4; ++t) {
          const int i = rr - t;
          if (i >= 0 && i <= 16) {
            const int js = js_fn(0, i), nt = nt_fn(0, i);
#pragma unroll
            for (int jj = 0; jj < nt; ++jj) {
              const float wv = w.wA[i][js + jj];
#pragma unroll
              for (int c = 0; c < 4; ++c)
                acc[t][c] = fmaf(wv, win[c + js + jj], acc[t][c]);
            }
          }
        }
      }
#pragma unroll
      for (int t = 0; t < 4; ++t) {
        const int gy = y0 - 16 + r0 + t;
        const bool rok = (gy >= 0) && (gy < HH);
        const __half2* cp = &buf0h[(r0 + t + 8) * G0 + (c0 >> 1)];
        const float2 c01 = __half22float2(cp[2]);
        const float2 c23 = __half22float2(cp[3]);
        const float cenv[4] = {c01.x, c01.y, c23.x, c23.y};
        float d[4];
#pragma unroll
        for (int c = 0; c < 4; ++c) {
          const int gxc = x0 - 4 + c0 + c;
          const bool ok = rok && (gxc >= 0) && (gxc < WW);
          float r = 0.0f;
          if (ok) {
            const float n = N0[(size_t)gy * WW + gxc];
            r = cenv[c] - acc[t][c] * w.knA * fastrcp(n);
          }
          d[c] = r;
        }
        buf1h[(r0 + t) * G1 + (c0 >> 1)]     = pack2(d[0], d[1]);
        buf1h[(r0 + t) * G1 + (c0 >> 1) + 1] = pack2(d[2], d[3]);
      }
    }
    __syncthreads();

    if (tid < 136) {
      const int rg = tid / 17, cg = tid - rg * 17;
      const int r0 = rg * 4, c0 = cg * 4;
      float acc[4][4] = {};
#pragma unroll
      for (int rr = 0; rr < 20; ++rr) {
        const __half2* lp = &buf1h[(r0 + rr) * G1 + (c0 >> 1)];
        const float2 a = __half22float2(lp[1]);
        const float2 b = __half22float2(lp[2]);
        const float win[4] = {a.x, a.y, b.x, b.y};
#pragma unroll
        for (int t = 0; t < 4; ++t) {
          const int i = rr - t;
          if (i >= 0 && i <= 16) {
            const float wv = w.wB[i];
            acc[t][0] = fmaf(wv, win[0], acc[t][0]);
            acc[t][1] = fmaf(wv, win[1], acc[t][1]);
            acc[t][2] = fmaf(wv, win[2], acc[t][2]);
            acc[t][3] = fmaf(wv, win[3], acc[t][3]);
          }
        }
      }
#pragma unroll
      for (int t = 0; t < 4; ++t) {
        const int gy = y0 - 8 + r0 + t;
        const bool rok = (gy >= 0) && (gy < HH);
        const __half2* cp = &buf1h[(r0 + t + 8) * G1 + (c0 >> 1)];
        const float2 ca = __half22float2(cp[1]);
        const float2 cb = __half22float2(cp[2]);
        const float cenv[4] = {ca.x, ca.y, cb.x, cb.y};
        float d[4];
#pragma unroll
        for (int c = 0; c < 4; ++c) {
          const int gxc = x0 - 2 + c0 + c;
          const bool ok = rok && (gxc >= 0) && (gxc < WW);
          float r = 0.0f;
          if (ok) {
            const float n = N1[(size_t)gy * WW + gxc];
            r = cenv[c] - acc[t][c] * w.knB * fastrcp(n);
          }
          d[c] = r;
        }
        buf2h[(r0 + t) * G1 + (c0 >> 1)]     = pack2(d[0], d[1]);
        buf2h[(r0 + t) * G1 + (c0 >> 1) + 1] = pack2(d[2], d[3]);
      }
    }
    __syncthreads();

    if (tid < 64) {
      const int rg = tid >> 4, tc = tid & 15;
      const int r0 = rg * 4, c0 = tc * 4;
      float acc[4][4] = {};
#pragma unroll
      for (int rr = 0; rr < 20; ++rr) {
        const __half2* lp = &buf2h[(r0 + rr) * G1 + (c0 >> 1)];
        const float2 p0 = __half22float2(lp[0]);
        const float2 p1 = __half22float2(lp[1]);
        const float2 p2 = __half22float2(lp[2]);
        const float2 p3 = __half22float2(lp[3]);
        const float win[8] = {p0.x, p0.y, p1.x, p1.y, p2.x, p2.y, p3.x, p3.y};
#pragma unroll
        for (int t = 0; t < 4; ++t) {
          const int i = rr - t;
          if (i >= 0 && i <= 16) {
            const int js = js_fn(2, i), nt = nt_fn(2, i);
#pragma unroll
            for (int jj = 0; jj < nt; ++jj) {
              const float wv = w.wC[i][js + jj];
#pragma unroll
              for (int c = 0; c < 4; ++c)
                acc[t][c] = fmaf(wv, win[c + js + jj], acc[t][c]);
            }
          }
        }
      }
#pragma unroll
      for (int t = 0; t < 4; ++t) {
        const __half2* cp = &buf2h[(r0 + t + 8) * G1 + (c0 >> 1)];
        const float2 ca = __half22float2(cp[1]);
        const float2 cb = __half22float2(cp[2]);
        const int gy = y0 + r0 + t, gx = x0 + c0;
        const float4 yv = *(const float4*)(Yg + img + (size_t)gy * WW + gx);
        const float4 nv = *(const float4*)(N2 + (size_t)gy * WW + gx);
        *(float4*)(Out + img + (size_t)gy * WW + gx) = make_float4(
            yv.x - ca.x + acc[t][0] * w.knC * fastrcp(nv.x),
            yv.y - ca.y + acc[t][1] * w.knC * fastrcp(nv.y),
            yv.z - cb.x + acc[t][2] * w.knC * fastrcp(nv.z),
            yv.w - cb.y + acc[t][3] * w.knC * fastrcp(nv.w));
      }
    }
  }
}

// ===================== fallback path (r9, dense-capable, fp32) ==============
__global__ __launch_bounds__(256)
void diff_kernel(const float* __restrict__ X, const float* __restrict__ Y,
                 float* __restrict__ D, int n4)
{
  const int stride = gridDim.x * 256;
  for (int i = blockIdx.x * 256 + threadIdx.x; i < n4; i += stride) {
    const float4 x = ((const float4*)X)[i];
    const float4 y = ((const float4*)Y)[i];
    ((float4*)D)[i] = make_float4(y.x - x.x, y.y - x.y, y.z - x.z, y.w - x.w);
  }
}

template <int MODE>
__global__ __launch_bounds__(256, 3)
void conv_dense(const float* __restrict__ P0, const float* __restrict__ P1,
                const float* __restrict__ Nrm, float* __restrict__ Out, Wts wts)
{
  constexpr int LSTR = 148, LCW = 36, XOFF = 8, CH = 48 * LCW;
  __shared__ float lds[48 * 148];
  const int bx = blockIdx.x, by = blockIdx.y, bz = blockIdx.z;
  const int tid = threadIdx.x;
  const int x0 = bx * TSC, y0 = by * TSR;
  const size_t img = (size_t)bz * ((size_t)HH * WW);
  const float* A = P0 + img;
#pragma unroll
  for (int s = 0; s < (CH + 255) / 256; ++s) {
    const int idx = s * 256 + tid;
    if (idx < CH) {
      const int r = idx / LCW, c4 = idx - r * LCW;
      const int gy = y0 - 8 + r, gx = x0 - XOFF + c4 * 4;
      float4 v = make_float4(0.f, 0.f, 0.f, 0.f);
      if (gy >= 0 && gy < HH) {
        const float* ar = A + (size_t)gy * WW;
        if (gx >= 0 && gx + 4 <= WW) v = *(const float4*)(ar + gx);
        else {
          float tv[4] = {0.f, 0.f, 0.f, 0.f};
#pragma unroll
          for (int e = 0; e < 4; ++e) {
            const int gxe = gx + e;
            if (gxe >= 0 && gxe < WW) tv[e] = ar[gxe];
          }
          v = make_float4(tv[0], tv[1], tv[2], tv[3]);
        }
      }
      *(float4*)&lds[r * LSTR + c4 * 4] = v;
    }
  }
  __syncthreads();
  const int tc = tid & 31, tg = tid >> 5, lc = tc * 4;
  float acc[4][4] = {};
#pragma unroll
  for (int rr = 0; rr < 20; ++rr) {
    const float* lp = &lds[(tg * 4 + rr) * LSTR];
    const float4 w0 = *(const float4*)(lp + 4 + lc);
    const float4 w1 = *(const float4*)(lp + 8 + lc);
    const float4 w2 = *(const float4*)(lp + 12 + lc);
    const float win[8] = {w0.z, w0.w, w1.x, w1.y, w1.z, w1.w, w2.x, w2.y};
#pragma unroll
    for (int t = 0; t < 4; ++t) {
      const int i = rr - t;
      if (i >= 0 && i <= 16) {
#pragma unroll
        for (int jj = 0; jj < 5; ++jj) {
          const float wv = wts.w[i][jj];
#pragma unroll
          for (int c = 0; c < 4; ++c)
            acc[t][c] = fmaf(wv, win[c + jj], acc[t][c]);
        }
      }
    }
  }
  float* Ob = Out + img;
  const int gx = x0 + lc;
  const float kn = wts.knorm;
#pragma unroll
  for (int t = 0; t < 4; ++t) {
    const int yo = y0 + tg * 4 + t;
    const float4 cv = *(const float4*)&lds[(tg * 4 + t + 8) * LSTR + XOFF + lc];
    const float4 nv = *(const float4*)(Nrm + (size_t)yo * WW + gx);
    const float a0 = acc[t][0] * kn * fastrcp(nv.x);
    const float a1 = acc[t][1] * kn * fastrcp(nv.y);
    const float a2 = acc[t][2] * kn * fastrcp(nv.z);
    const float a3 = acc[t][3] * kn * fastrcp(nv.w);
    float4 o;
    if (MODE == 2) {
      const float4 yv = *(const float4*)(P1 + img + (size_t)yo * WW + gx);
      o = make_float4(yv.x - cv.x + a0, yv.y - cv.y + a1,
                      yv.z - cv.z + a2, yv.w - cv.w + a3);
    } else {
      o = make_float4(cv.x - a0, cv.y - a1, cv.z - a2, cv.w - a3);
    }
    *(float4*)(Ob + (size_t)yo * WW + gx) = o;
  }
}

// ---------------- host-side replication of _build_kernels ----------------
static void rotate33(const double* src, double* dst, double ang_deg) {
  const int n = 33;
  const double t = ang_deg * 3.14159265358979323846 / 180.0;
  const double cs = cos(t), sn = sin(t);
  for (int y = 0; y < n; ++y) {
    for (int x = 0; x < n; ++x) {
      const double y0 = y - 16.0, x0 = x - 16.0;
      const double sy = cs * y0 + sn * x0 + 16.0;
      const double sx = -sn * y0 + cs * x0 + 16.0;
      const double fy = floor(sy), fx = floor(sx);
      const int y0i = (int)fy, x0i = (int)fx;
      const double wy = sy - fy, wx = sx - fx;
      double o = 0.0;
      for (int dy = 0; dy < 2; ++dy)
        for (int dx = 0; dx < 2; ++dx) {
          const int yy = y0i + dy, xx = x0i + dx;
          if (yy < 0 || yy >= n || xx < 0 || xx >= n) continue;
          const double wgt = (dy ? wy : 1.0 - wy) * (dx ? wx : 1.0 - wx);
          o += wgt * src[yy * n + xx];
        }
      dst[y * n + x] = o;
    }
  }
}

static void build_K(float K[3][17][5]) {
  const double angs[3] = {-10.0, 0.0, 10.0};
  double base[33 * 33], rot[33 * 33];
  for (int i = 0; i < 33 * 33; ++i) base[i] = 0.0;
  for (int y = 0; y < 33; ++y) base[y * 33 + 16] = 1.0;
  for (int a = 0; a < 3; ++a) {
    if (a == 1) memcpy(rot, base, sizeof(rot));
    else        rotate33(base, rot, angs[a]);
    double k17[17][17];
    for (int y = 0; y < 17; ++y)
      for (int x = 0; x < 17; ++x) k17[y][x] = rot[(y + 8) * 33 + (x + 8)];
    int r = 0, c = 0;
    for (int y = 0; y < 17; ++y) { bool nz = false; for (int x = 0; x < 17; ++x) if (k17[y][x] != 0.0) nz = true; r += nz; }
    for (int x = 0; x < 17; ++x) { bool nz = false; for (int y = 0; y < 17; ++y) if (k17[y][x] != 0.0) nz = true; c += nz; }
    r = r / 2 * 2; c = c / 2 * 2;
    const int kh = r + 1, kw = c + 1;
    for (int y = 0; y < 17; ++y)
      for (int x = 0; x < 5; ++x) K[a][y][x] = 0.0f;
    if (kh <= 17 && kw <= 5) {
      const int oh = (17 - kh) / 2, ow = (5 - kw) / 2;
      for (int y = 0; y < kh; ++y)
        for (int x = 0; x < kw; ++x)
          K[a][oh + y][ow + x] = (float)k17[8 - r / 2 + y][8 - c / 2 + x];
    }
  }
}

static int pick_mode(int a, const float K[17][5]) {
  for (int i = 0; i < 17; ++i) {
    const int js = js_fn(a, i), nt = nt_fn(a, i);
    for (int j = 0; j < 5; ++j)
      if ((j < js || j >= js + nt) && K[i][j] != 0.0f) return 1;
  }
  return 0;
}

extern "C" void kernel_launch(void* const* d_in, const int* in_sizes, int n_in,
                              void* d_out, int out_size, void* d_ws, size_t ws_size,
                              hipStream_t stream) {
  const float* X  = (const float*)d_in[0];
  const float* Y  = (const float*)d_in[1];
  const float* Nn = (const float*)d_in[3];
  float* out = (float*)d_out;
  float* tmp = (float*)d_ws;
  const size_t HW = (size_t)HH * WW;
  const int B = in_sizes[0] / (int)HW;   // 2

  float K[3][17][5];
  build_K(K);
  double ks[3];
  for (int a = 0; a < 3; ++a) {
    ks[a] = 0.0;
    for (int i = 0; i < 17; ++i)
      for (int j = 0; j < 5; ++j) ks[a] += K[a][i][j];
  }
  const int dense = pick_mode(0, K[0]) | pick_mode(1, K[1]) | pick_mode(2, K[2]);

  if (!dense) {
    W3 w;
    for (int i = 0; i < 17; ++i)
      for (int j = 0; j < 5; ++j) {
        w.wA[i][j] = (float)(K[0][i][j] / ks[0]);
        w.wC[i][j] = (float)(K[2][i][j] / ks[2]);
      }
    for (int i = 0; i < 17; ++i) w.wB[i] = (float)(K[1][i][2] / ks[1]);
    w.knA = (float)ks[0]; w.knB = (float)ks[1]; w.knC = (float)ks[2];

    fused_all<<<dim3(TOT1 * B), dim3(256), 0, stream>>>(X, Y, Nn, out, w);
  } else {
    Wts w[3];
    for (int a = 0; a < 3; ++a) {
      for (int i = 0; i < 17; ++i)
        for (int j = 0; j < 5; ++j) w[a].w[i][j] = (float)(K[a][i][j] / ks[a]);
      w[a].knorm = (float)ks[a];
    }
    const int n4 = (int)(B * HW / 4);
    const int dg = (n4 + 255) / 256;
    diff_kernel<<<dim3(dg > 8192 ? 8192 : dg), dim3(256), 0, stream>>>(X, Y, tmp, n4);
    dim3 g(NBX, NBY, B), blk(256);
    conv_dense<1><<<g, blk, 0, stream>>>(tmp, nullptr, Nn,          out, w[0]);
    conv_dense<1><<<g, blk, 0, stream>>>(out, nullptr, Nn + HW,     tmp, w[1]);
    conv_dense<2><<<g, blk, 0, stream>>>(tmp, Y,       Nn + 2 * HW, out, w[2]);
  }
}

// Round 15
// 67.213 us; speedup vs baseline: 1.5262x; 1.1102x over previous
//
#include <hip/hip_runtime.h>
#include <hip/hip_fp16.h>
#include <math.h>
#include <string.h>
#include <stdint.h>

#define HH 2048
#define WW 2048
#define TSC 128
#define TSR 32
#define NBX (WW / TSC)                 // 16
#define NBY (HH / TSR)                 // 64
#define NINT1 ((NBX - 2) * (NBY - 2))  // 868 interior 128x32 tiles per image
#define NB64 624                       // boundary 64x16 tiles per image
#define TOT1 (NINT1 + NB64)            // 1492 blocks per image

// interior half2 row strides: buf0 144 halfs = 72, buf1/2 140 halfs = 70
#define H0 72
#define H1 70
// boundary half2 strides
#define G0 40
#define G1 38

struct W3 {
  float wA[17][5]; float wC[17][5]; float wB[17];
  float knA, knB, knC;
  unsigned uA[17], uC[17], uA8b, uC8b;   // packed half2 weight pairs
};
struct Wts { float w[17][5]; float knorm; };   // fallback path

// angle index a: 0 -> -10deg, 1 -> 0deg, 2 -> +10deg
__host__ __device__ constexpr int js_fn(int a, int i) {
  return (a == 1) ? 2
       : (a == 2) ? ((i < 3) ? 0 : (i < 9) ? 1 : (i < 14) ? 2 : 3)
                  : ((i < 3) ? 3 : (i < 8) ? 2 : (i < 14) ? 1 : 0);
}
__host__ __device__ constexpr int nt_fn(int a, int i) {
  return (a == 1) ? 1 : (i == 8) ? 3 : 2;
}

__device__ __forceinline__ float fastrcp(float x) {
#if __has_builtin(__builtin_amdgcn_rcpf)
  return __builtin_amdgcn_rcpf(x);
#else
  return 1.0f / x;
#endif
}

__device__ __forceinline__ __half2 pack2(float a, float b) {
  return __float22half2_rn(make_float2(a, b));
}

typedef _Float16 h2vec __attribute__((ext_vector_type(2)));

// acc += win.x*wgt.x + win.y*wgt.y  (fp16 pairs, fp32 accumulate)
__device__ __forceinline__ float fdot2h(unsigned win, unsigned wgt, float acc) {
#if __has_builtin(__builtin_amdgcn_fdot2)
  return __builtin_amdgcn_fdot2(__builtin_bit_cast(h2vec, win),
                                __builtin_bit_cast(h2vec, wgt), acc, false);
#else
  const __half2 ha = __builtin_bit_cast(__half2, win);
  const __half2 hb = __builtin_bit_cast(__half2, wgt);
  const float2 fa = __half22float2(ha), fb = __half22float2(hb);
  return fmaf(fa.y, fb.y, fmaf(fa.x, fb.x, acc));
#endif
}

// ====== ONE dispatch: interior + boundary blocks (r14 structure) ======
__global__ __launch_bounds__(256, 4)
void fused_all(const float* __restrict__ Xg, const float* __restrict__ Yg,
               const float* __restrict__ Nn, float* __restrict__ Out, W3 w)
{
  __shared__ __half2 ldsh[10240];      // 40960 B -> 4 blocks/CU

  const int bid = blockIdx.x, nwg = gridDim.x;
  const int wg = ((nwg & 7) == 0) ? ((bid & 7) * (nwg >> 3) + (bid >> 3)) : bid;
  const int bz = wg / TOT1;
  const int t0 = wg - bz * TOT1;
  const int tid = threadIdx.x;
  const size_t img = (size_t)bz * ((size_t)HH * WW);

  if (t0 < NINT1) {
    // ==================== INTERIOR 128x32 (dot2 conv) ====================
    __half2* buf0h = ldsh;             // 80 x H0 = 5760
    __half2* buf1h = ldsh + 5760;      // 64 x H1 = 4480
    __half2* buf2h = buf0h;

    const int bx = 1 + t0 / (NBY - 2);
    const int by = 1 + t0 % (NBY - 2);
    const int x0 = bx * TSC, y0 = by * TSR;

#pragma unroll
    for (int s = 0; s < 12; ++s) {
      const int idx = s * 256 + tid;
      if (idx < 80 * 36) {
        const int r = idx / 36, c4 = idx - r * 36;
        const size_t g = img + (size_t)(y0 - 24 + r) * WW + (x0 - 8 + c4 * 4);
        const float4 xv = *(const float4*)(Xg + g);
        const float4 yv = *(const float4*)(Yg + g);
        buf0h[r * H0 + c4 * 2]     = pack2(yv.x - xv.x, yv.y - xv.y);
        buf0h[r * H0 + c4 * 2 + 1] = pack2(yv.z - xv.z, yv.w - xv.w);
      }
    }
    __syncthreads();

    // ---- pass A (-10deg): dot2 pairs; window half offsets js+2+c ----
#pragma unroll 1
    for (int tt = tid; tt < 544; tt += 256) {
      const int rg = tt / 34, cg = tt - rg * 34;
      const int r0 = rg * 4, c0 = cg * 4;
      float acc[4][4] = {};
#pragma unroll
      for (int rr = 0; rr < 20; ++rr) {
        const unsigned* lp = (const unsigned*)&buf0h[(r0 + rr) * H0 + (c0 >> 1)];
        const uint2 qa = *(const uint2*)(lp);
        const uint2 qb = *(const uint2*)(lp + 2);
        const unsigned a4 = lp[4];
        unsigned p[9];
        p[2] = qa.y;  p[4] = qb.x;  p[6] = qb.y;  p[8] = a4;
        p[3] = __builtin_amdgcn_alignbit(qb.x, qa.y, 16);
        p[5] = __builtin_amdgcn_alignbit(qb.y, qb.x, 16);
        p[7] = __builtin_amdgcn_alignbit(a4, qb.y, 16);
#pragma unroll
        for (int t = 0; t < 4; ++t) {
          const int i = rr - t;
          if (i >= 0 && i <= 16) {
            const int js = js_fn(0, i);
            if (i != 8) {
              const unsigned w2 = w.uA[i];
              const int b = js + 2;           // b in [2,5], b+3 <= 8
#pragma unroll
              for (int c = 0; c < 4; ++c)
                acc[t][c] = fdot2h(p[b + c], w2, acc[t][c]);
            } else {                          // js=1, taps 1..3 padded
              const unsigned w2a = w.uA[8], w2b = w.uA8b;
#pragma unroll
              for (int c = 0; c < 4; ++c) {
                acc[t][c] = fdot2h(p[3 + c], w2a, acc[t][c]);
                acc[t][c] = fdot2h(p[5 + c], w2b, acc[t][c]);
              }
            }
          }
        }
      }
#pragma unroll
      for (int t = 0; t < 4; ++t) {
        const __half2* cp = &buf0h[(r0 + t + 8) * H0 + (c0 >> 1)];
        const float2 c01 = __half22float2(cp[2]);
        const float2 c23 = __half22float2(cp[3]);
        buf1h[(r0 + t) * H1 + (c0 >> 1)]     = pack2(c01.x - acc[t][0], c01.y - acc[t][1]);
        buf1h[(r0 + t) * H1 + (c0 >> 1) + 1] = pack2(c23.x - acc[t][2], c23.y - acc[t][3]);
      }
    }
    __syncthreads();

    // ---- pass B (0deg, vertical 17-tap, unchanged) ----
#pragma unroll 1
    for (int tt = tid; tt < 396; tt += 256) {
      const int rg = tt / 33, cg = tt - rg * 33;
      const int r0 = rg * 4, c0 = cg * 4;
      float acc[4][4] = {};
#pragma unroll
      for (int rr = 0; rr < 20; ++rr) {
        const __half2* lp = &buf1h[(r0 + rr) * H1 + (c0 >> 1)];
        const float2 a = __half22float2(lp[1]);
        const float2 b = __half22float2(lp[2]);
        const float win[4] = {a.x, a.y, b.x, b.y};
#pragma unroll
        for (int t = 0; t < 4; ++t) {
          const int i = rr - t;
          if (i >= 0 && i <= 16) {
            const float wv = w.wB[i];
            acc[t][0] = fmaf(wv, win[0], acc[t][0]);
            acc[t][1] = fmaf(wv, win[1], acc[t][1]);
            acc[t][2] = fmaf(wv, win[2], acc[t][2]);
            acc[t][3] = fmaf(wv, win[3], acc[t][3]);
          }
        }
      }
#pragma unroll
      for (int t = 0; t < 4; ++t) {
        const __half2* cp = &buf1h[(r0 + t + 8) * H1 + (c0 >> 1)];
        const float2 ca = __half22float2(cp[1]);
        const float2 cb = __half22float2(cp[2]);
        buf2h[(r0 + t) * H1 + (c0 >> 1)]     = pack2(ca.x - acc[t][0], ca.y - acc[t][1]);
        buf2h[(r0 + t) * H1 + (c0 >> 1) + 1] = pack2(cb.x - acc[t][2], cb.y - acc[t][3]);
      }
    }
    __syncthreads();

    // ---- pass C (+10deg): dot2 pairs; window half offsets js+c ----
    {
      const int tg = tid >> 5, tc = tid & 31;
      const int r0 = tg * 4, c0 = tc * 4;
      float acc[4][4] = {};
#pragma unroll
      for (int rr = 0; rr < 20; ++rr) {
        const unsigned* lp = (const unsigned*)&buf2h[(r0 + rr) * H1 + (c0 >> 1)];
        const uint2 qa = *(const uint2*)(lp);
        const uint2 qb = *(const uint2*)(lp + 2);
        unsigned p[7];
        p[0] = qa.x;  p[2] = qa.y;  p[4] = qb.x;  p[6] = qb.y;
        p[1] = __builtin_amdgcn_alignbit(qa.y, qa.x, 16);
        p[3] = __builtin_amdgcn_alignbit(qb.x, qa.y, 16);
        p[5] = __builtin_amdgcn_alignbit(qb.y, qb.x, 16);
#pragma unroll
        for (int t = 0; t < 4; ++t) {
          const int i = rr - t;
          if (i >= 0 && i <= 16) {
            const int js = js_fn(2, i);
            if (i != 8) {
              const unsigned w2 = w.uC[i];   // js in [0,3], js+3 <= 6
#pragma unroll
              for (int c = 0; c < 4; ++c)
                acc[t][c] = fdot2h(p[js + c], w2, acc[t][c]);
            } else {                          // js=1, taps 1..3 padded
#pragma unroll
              for (int c = 0; c < 4; ++c) {
                acc[t][c] = fdot2h(p[1 + c], w.uC[8], acc[t][c]);
                acc[t][c] = fdot2h(p[3 + c], w.uC8b, acc[t][c]);
              }
            }
          }
        }
      }
#pragma unroll
      for (int t = 0; t < 4; ++t) {
        const __half2* cp = &buf2h[(r0 + t + 8) * H1 + (c0 >> 1)];
        const float2 ca = __half22float2(cp[1]);
        const float2 cb = __half22float2(cp[2]);
        const int gy = y0 + r0 + t, gx = x0 + c0;
        const float4 yv = *(const float4*)(Yg + img + (size_t)gy * WW + gx);
        *(float4*)(Out + img + (size_t)gy * WW + gx) = make_float4(
            yv.x - ca.x + acc[t][0], yv.y - ca.y + acc[t][1],
            yv.z - cb.x + acc[t][2], yv.w - cb.y + acc[t][3]);
      }
    }
  } else {
    // ==================== BOUNDARY 64x16 (r13, proven) ====================
    __half2* buf0h = ldsh;
    __half2* buf1h = ldsh + 2560;
    __half2* buf2h = buf0h;

    const int u = t0 - NINT1;          // 0..623
    int x0, y0;
    if (u < 64)       { y0 = (u >> 5) * 16;          x0 = (u & 31) * 64; }
    else if (u < 128) { const int v = u - 64;
                        y0 = 2016 + (v >> 5) * 16;   x0 = (v & 31) * 64; }
    else              { const int v = u - 128;
                        const int side = v & 1, idx = v >> 1;
                        const int col = idx & 1, row = idx >> 1;
                        y0 = 32 + row * 16;
                        x0 = side ? (1920 + col * 64) : (col * 64); }

    const float* N0 = Nn;
    const float* N1 = Nn + (size_t)HH * WW;
    const float* N2 = Nn + 2 * (size_t)HH * WW;

#pragma unroll
    for (int s = 0; s < 5; ++s) {
      const int idx = s * 256 + tid;
      const int r = idx / 20, c4 = idx - r * 20;
      const int gy = y0 - 24 + r;
      const int gx = x0 - 8 + c4 * 4;
      float4 v = make_float4(0.f, 0.f, 0.f, 0.f);
      if (gy >= 0 && gy < HH) {
        const float* xr = Xg + img + (size_t)gy * WW;
        const float* yr = Yg + img + (size_t)gy * WW;
        if (gx >= 0 && gx + 4 <= WW) {
          const float4 xv = *(const float4*)(xr + gx);
          const float4 yv = *(const float4*)(yr + gx);
          v = make_float4(yv.x - xv.x, yv.y - xv.y, yv.z - xv.z, yv.w - xv.w);
        } else {
          float tv[4] = {0.f, 0.f, 0.f, 0.f};
#pragma unroll
          for (int e = 0; e < 4; ++e) {
            const int gxe = gx + e;
            if (gxe >= 0 && gxe < WW) tv[e] = yr[gxe] - xr[gxe];
          }
          v = make_float4(tv[0], tv[1], tv[2], tv[3]);
        }
      }
      buf0h[r * G0 + c4 * 2]     = pack2(v.x, v.y);
      buf0h[r * G0 + c4 * 2 + 1] = pack2(v.z, v.w);
    }
    __syncthreads();

    if (tid < 216) {
      const int rg = tid / 18, cg = tid - rg * 18;
      const int r0 = rg * 4, c0 = cg * 4;
      float acc[4][4] = {};
#pragma unroll
      for (int rr = 0; rr < 20; ++rr) {
        const __half2* lp = &buf0h[(r0 + rr) * G0 + (c0 >> 1)];
        const float2 p0 = __half22float2(lp[1]);
        const float2 p1 = __half22float2(lp[2]);
        const float2 p2 = __half22float2(lp[3]);
        const float2 p3 = __half22float2(lp[4]);
        const float win[8] = {p0.x, p0.y, p1.x, p1.y, p2.x, p2.y, p3.x, p3.y};
#pragma unroll
        for (int t = 0; t < 4; ++t) {
          const int i = rr - t;
          if (i >= 0 && i <= 16) {
            const int js = js_fn(0, i), nt = nt_fn(0, i);
#pragma unroll
            for (int jj = 0; jj < nt; ++jj) {
              const float wv = w.wA[i][js + jj];
#pragma unroll
              for (int c = 0; c < 4; ++c)
                acc[t][c] = fmaf(wv, win[c + js + jj], acc[t][c]);
            }
          }
        }
      }
#pragma unroll
      for (int t = 0; t < 4; ++t) {
        const int gy = y0 - 16 + r0 + t;
        const bool rok = (gy >= 0) && (gy < HH);
        const __half2* cp = &buf0h[(r0 + t + 8) * G0 + (c0 >> 1)];
        const float2 c01 = __half22float2(cp[2]);
        const float2 c23 = __half22float2(cp[3]);
        const float cenv[4] = {c01.x, c01.y, c23.x, c23.y};
        float d[4];
#pragma unroll
        for (int c = 0; c < 4; ++c) {
          const int gxc = x0 - 4 + c0 + c;
          const bool ok = rok && (gxc >= 0) && (gxc < WW);
          float r = 0.0f;
          if (ok) {
            const float n = N0[(size_t)gy * WW + gxc];
            r = cenv[c] - acc[t][c] * w.knA * fastrcp(n);
          }
          d[c] = r;
        }
        buf1h[(r0 + t) * G1 + (c0 >> 1)]     = pack2(d[0], d[1]);
        buf1h[(r0 + t) * G1 + (c0 >> 1) + 1] = pack2(d[2], d[3]);
      }
    }
    __syncthreads();

    if (tid < 136) {
      const int rg = tid / 17, cg = tid - rg * 17;
      const int r0 = rg * 4, c0 = cg * 4;
      float acc[4][4] = {};
#pragma unroll
      for (int rr = 0; rr < 20; ++rr) {
        const __half2* lp = &buf1h[(r0 + rr) * G1 + (c0 >> 1)];
        const float2 a = __half22float2(lp[1]);
        const float2 b = __half22float2(lp[2]);
        const float win[4] = {a.x, a.y, b.x, b.y};
#pragma unroll
        for (int t = 0; t < 4; ++t) {
          const int i = rr - t;
          if (i >= 0 && i <= 16) {
            const float wv = w.wB[i];
            acc[t][0] = fmaf(wv, win[0], acc[t][0]);
            acc[t][1] = fmaf(wv, win[1], acc[t][1]);
            acc[t][2] = fmaf(wv, win[2], acc[t][2]);
            acc[t][3] = fmaf(wv, win[3], acc[t][3]);
          }
        }
      }
#pragma unroll
      for (int t = 0; t < 4; ++t) {
        const int gy = y0 - 8 + r0 + t;
        const bool rok = (gy >= 0) && (gy < HH);
        const __half2* cp = &buf1h[(r0 + t + 8) * G1 + (c0 >> 1)];
        const float2 ca = __half22float2(cp[1]);
        const float2 cb = __half22float2(cp[2]);
        const float cenv[4] = {ca.x, ca.y, cb.x, cb.y};
        float d[4];
#pragma unroll
        for (int c = 0; c < 4; ++c) {
          const int gxc = x0 - 2 + c0 + c;
          const bool ok = rok && (gxc >= 0) && (gxc < WW);
          float r = 0.0f;
          if (ok) {
            const float n = N1[(size_t)gy * WW + gxc];
            r = cenv[c] - acc[t][c] * w.knB * fastrcp(n);
          }
          d[c] = r;
        }
        buf2h[(r0 + t) * G1 + (c0 >> 1)]     = pack2(d[0], d[1]);
        buf2h[(r0 + t) * G1 + (c0 >> 1) + 1] = pack2(d[2], d[3]);
      }
    }
    __syncthreads();

    if (tid < 64) {
      const int rg = tid >> 4, tc = tid & 15;
      const int r0 = rg * 4, c0 = tc * 4;
      float acc[4][4] = {};
#pragma unroll
      for (int rr = 0; rr < 20; ++rr) {
        const __half2* lp = &buf2h[(r0 + rr) * G1 + (c0 >> 1)];
        const float2 p0 = __half22float2(lp[0]);
        const float2 p1 = __half22float2(lp[1]);
        const float2 p2 = __half22float2(lp[2]);
        const float2 p3 = __half22float2(lp[3]);
        const float win[8] = {p0.x, p0.y, p1.x, p1.y, p2.x, p2.y, p3.x, p3.y};
#pragma unroll
        for (int t = 0; t < 4; ++t) {
          const int i = rr - t;
          if (i >= 0 && i <= 16) {
            const int js = js_fn(2, i), nt = nt_fn(2, i);
#pragma unroll
            for (int jj = 0; jj < nt; ++jj) {
              const float wv = w.wC[i][js + jj];
#pragma unroll
              for (int c = 0; c < 4; ++c)
                acc[t][c] = fmaf(wv, win[c + js + jj], acc[t][c]);
            }
          }
        }
      }
#pragma unroll
      for (int t = 0; t < 4; ++t) {
        const __half2* cp = &buf2h[(r0 + t + 8) * G1 + (c0 >> 1)];
        const float2 ca = __half22float2(cp[1]);
        const float2 cb = __half22float2(cp[2]);
        const int gy = y0 + r0 + t, gx = x0 + c0;
        const float4 yv = *(const float4*)(Yg + img + (size_t)gy * WW + gx);
        const float4 nv = *(const float4*)(N2 + (size_t)gy * WW + gx);
        *(float4*)(Out + img + (size_t)gy * WW + gx) = make_float4(
            yv.x - ca.x + acc[t][0] * w.knC * fastrcp(nv.x),
            yv.y - ca.y + acc[t][1] * w.knC * fastrcp(nv.y),
            yv.z - cb.x + acc[t][2] * w.knC * fastrcp(nv.z),
            yv.w - cb.y + acc[t][3] * w.knC * fastrcp(nv.w));
      }
    }
  }
}

// ===================== fallback path (r9, dense-capable, fp32) ==============
__global__ __launch_bounds__(256)
void diff_kernel(const float* __restrict__ X, const float* __restrict__ Y,
                 float* __restrict__ D, int n4)
{
  const int stride = gridDim.x * 256;
  for (int i = blockIdx.x * 256 + threadIdx.x; i < n4; i += stride) {
    const float4 x = ((const float4*)X)[i];
    const float4 y = ((const float4*)Y)[i];
    ((float4*)D)[i] = make_float4(y.x - x.x, y.y - x.y, y.z - x.z, y.w - x.w);
  }
}

template <int MODE>
__global__ __launch_bounds__(256, 3)
void conv_dense(const float* __restrict__ P0, const float* __restrict__ P1,
                const float* __restrict__ Nrm, float* __restrict__ Out, Wts wts)
{
  constexpr int LSTR = 148, LCW = 36, XOFF = 8, CH = 48 * LCW;
  __shared__ float lds[48 * 148];
  const int bx = blockIdx.x, by = blockIdx.y, bz = blockIdx.z;
  const int tid = threadIdx.x;
  const int x0 = bx * TSC, y0 = by * TSR;
  const size_t img = (size_t)bz * ((size_t)HH * WW);
  const float* A = P0 + img;
#pragma unroll
  for (int s = 0; s < (CH + 255) / 256; ++s) {
    const int idx = s * 256 + tid;
    if (idx < CH) {
      const int r = idx / LCW, c4 = idx - r * LCW;
      const int gy = y0 - 8 + r, gx = x0 - XOFF + c4 * 4;
      float4 v = make_float4(0.f, 0.f, 0.f, 0.f);
      if (gy >= 0 && gy < HH) {
        const float* ar = A + (size_t)gy * WW;
        if (gx >= 0 && gx + 4 <= WW) v = *(const float4*)(ar + gx);
        else {
          float tv[4] = {0.f, 0.f, 0.f, 0.f};
#pragma unroll
          for (int e = 0; e < 4; ++e) {
            const int gxe = gx + e;
            if (gxe >= 0 && gxe < WW) tv[e] = ar[gxe];
          }
          v = make_float4(tv[0], tv[1], tv[2], tv[3]);
        }
      }
      *(float4*)&lds[r * LSTR + c4 * 4] = v;
    }
  }
  __syncthreads();
  const int tc = tid & 31, tg = tid >> 5, lc = tc * 4;
  float acc[4][4] = {};
#pragma unroll
  for (int rr = 0; rr < 20; ++rr) {
    const float* lp = &lds[(tg * 4 + rr) * LSTR];
    const float4 w0 = *(const float4*)(lp + 4 + lc);
    const float4 w1 = *(const float4*)(lp + 8 + lc);
    const float4 w2 = *(const float4*)(lp + 12 + lc);
    const float win[8] = {w0.z, w0.w, w1.x, w1.y, w1.z, w1.w, w2.x, w2.y};
#pragma unroll
    for (int t = 0; t < 4; ++t) {
      const int i = rr - t;
      if (i >= 0 && i <= 16) {
#pragma unroll
        for (int jj = 0; jj < 5; ++jj) {
          const float wv = wts.w[i][jj];
#pragma unroll
          for (int c = 0; c < 4; ++c)
            acc[t][c] = fmaf(wv, win[c + jj], acc[t][c]);
        }
      }
    }
  }
  float* Ob = Out + img;
  const int gx = x0 + lc;
  const float kn = wts.knorm;
#pragma unroll
  for (int t = 0; t < 4; ++t) {
    const int yo = y0 + tg * 4 + t;
    const float4 cv = *(const float4*)&lds[(tg * 4 + t + 8) * LSTR + XOFF + lc];
    const float4 nv = *(const float4*)(Nrm + (size_t)yo * WW + gx);
    const float a0 = acc[t][0] * kn * fastrcp(nv.x);
    const float a1 = acc[t][1] * kn * fastrcp(nv.y);
    const float a2 = acc[t][2] * kn * fastrcp(nv.z);
    const float a3 = acc[t][3] * kn * fastrcp(nv.w);
    float4 o;
    if (MODE == 2) {
      const float4 yv = *(const float4*)(P1 + img + (size_t)yo * WW + gx);
      o = make_float4(yv.x - cv.x + a0, yv.y - cv.y + a1,
                      yv.z - cv.z + a2, yv.w - cv.w + a3);
    } else {
      o = make_float4(cv.x - a0, cv.y - a1, cv.z - a2, cv.w - a3);
    }
    *(float4*)(Ob + (size_t)yo * WW + gx) = o;
  }
}

// ---------------- host-side replication of _build_kernels ----------------
static void rotate33(const double* src, double* dst, double ang_deg) {
  const int n = 33;
  const double t = ang_deg * 3.14159265358979323846 / 180.0;
  const double cs = cos(t), sn = sin(t);
  for (int y = 0; y < n; ++y) {
    for (int x = 0; x < n; ++x) {
      const double y0 = y - 16.0, x0 = x - 16.0;
      const double sy = cs * y0 + sn * x0 + 16.0;
      const double sx = -sn * y0 + cs * x0 + 16.0;
      const double fy = floor(sy), fx = floor(sx);
      const int y0i = (int)fy, x0i = (int)fx;
      const double wy = sy - fy, wx = sx - fx;
      double o = 0.0;
      for (int dy = 0; dy < 2; ++dy)
        for (int dx = 0; dx < 2; ++dx) {
          const int yy = y0i + dy, xx = x0i + dx;
          if (yy < 0 || yy >= n || xx < 0 || xx >= n) continue;
          const double wgt = (dy ? wy : 1.0 - wy) * (dx ? wx : 1.0 - wx);
          o += wgt * src[yy * n + xx];
        }
      dst[y * n + x] = o;
    }
  }
}

static void build_K(float K[3][17][5]) {
  const double angs[3] = {-10.0, 0.0, 10.0};
  double base[33 * 33], rot[33 * 33];
  for (int i = 0; i < 33 * 33; ++i) base[i] = 0.0;
  for (int y = 0; y < 33; ++y) base[y * 33 + 16] = 1.0;
  for (int a = 0; a < 3; ++a) {
    if (a == 1) memcpy(rot, base, sizeof(rot));
    else        rotate33(base, rot, angs[a]);
    double k17[17][17];
    for (int y = 0; y < 17; ++y)
      for (int x = 0; x < 17; ++x) k17[y][x] = rot[(y + 8) * 33 + (x + 8)];
    int r = 0, c = 0;
    for (int y = 0; y < 17; ++y) { bool nz = false; for (int x = 0; x < 17; ++x) if (k17[y][x] != 0.0) nz = true; r += nz; }
    for (int x = 0; x < 17; ++x) { bool nz = false; for (int y = 0; y < 17; ++y) if (k17[y][x] != 0.0) nz = true; c += nz; }
    r = r / 2 * 2; c = c / 2 * 2;
    const int kh = r + 1, kw = c + 1;
    for (int y = 0; y < 17; ++y)
      for (int x = 0; x < 5; ++x) K[a][y][x] = 0.0f;
    if (kh <= 17 && kw <= 5) {
      const int oh = (17 - kh) / 2, ow = (5 - kw) / 2;
      for (int y = 0; y < kh; ++y)
        for (int x = 0; x < kw; ++x)
          K[a][oh + y][ow + x] = (float)k17[8 - r / 2 + y][8 - c / 2 + x];
    }
  }
}

static int pick_mode(int a, const float K[17][5]) {
  for (int i = 0; i < 17; ++i) {
    const int js = js_fn(a, i), nt = nt_fn(a, i);
    for (int j = 0; j < 5; ++j)
      if ((j < js || j >= js + nt) && K[i][j] != 0.0f) return 1;
  }
  return 0;
}

// host float -> half bits (rte, flush tiny to zero)
static unsigned short f2h(float f) {
  union { float f; uint32_t u; } v; v.f = f;
  const uint32_t u = v.u;
  const uint32_t s = (u >> 16) & 0x8000u;
  const int32_t  e = (int32_t)((u >> 23) & 0xffu) - 127 + 15;
  const uint32_t m = u & 0x7fffffu;
  if ((u & 0x7fffffffu) == 0) return (unsigned short)s;
  if (e >= 31) return (unsigned short)(s | 0x7bffu);
  if (e <= 0)  return (unsigned short)s;
  uint32_t h = s | ((uint32_t)e << 10) | (m >> 13);
  const uint32_t rem = m & 0x1fffu;
  if (rem > 0x1000u || (rem == 0x1000u && (h & 1u))) h++;
  return (unsigned short)h;
}
static unsigned pack_h2f(float a, float b) {
  return (unsigned)f2h(a) | ((unsigned)f2h(b) << 16);
}

extern "C" void kernel_launch(void* const* d_in, const int* in_sizes, int n_in,
                              void* d_out, int out_size, void* d_ws, size_t ws_size,
                              hipStream_t stream) {
  const float* X  = (const float*)d_in[0];
  const float* Y  = (const float*)d_in[1];
  const float* Nn = (const float*)d_in[3];
  float* out = (float*)d_out;
  float* tmp = (float*)d_ws;
  const size_t HW = (size_t)HH * WW;
  const int B = in_sizes[0] / (int)HW;   // 2

  float K[3][17][5];
  build_K(K);
  double ks[3];
  for (int a = 0; a < 3; ++a) {
    ks[a] = 0.0;
    for (int i = 0; i < 17; ++i)
      for (int j = 0; j < 5; ++j) ks[a] += K[a][i][j];
  }
  const int dense = pick_mode(0, K[0]) | pick_mode(1, K[1]) | pick_mode(2, K[2]);

  if (!dense) {
    W3 w;
    for (int i = 0; i < 17; ++i)
      for (int j = 0; j < 5; ++j) {
        w.wA[i][j] = (float)(K[0][i][j] / ks[0]);
        w.wC[i][j] = (float)(K[2][i][j] / ks[2]);
      }
    for (int i = 0; i < 17; ++i) w.wB[i] = (float)(K[1][i][2] / ks[1]);
    w.knA = (float)ks[0]; w.knB = (float)ks[1]; w.knC = (float)ks[2];
    for (int i = 0; i < 17; ++i) {
      const int ja = js_fn(0, i);
      const int jc = js_fn(2, i);
      w.uA[i] = pack_h2f(w.wA[i][ja], w.wA[i][ja + 1]);
      w.uC[i] = pack_h2f(w.wC[i][jc], w.wC[i][jc + 1]);
    }
    w.uA8b = pack_h2f(w.wA[8][js_fn(0, 8) + 2], 0.0f);
    w.uC8b = pack_h2f(w.wC[8][js_fn(2, 8) + 2], 0.0f);

    fused_all<<<dim3(TOT1 * B), dim3(256), 0, stream>>>(X, Y, Nn, out, w);
  } else {
    Wts w[3];
    for (int a = 0; a < 3; ++a) {
      for (int i = 0; i < 17; ++i)
        for (int j = 0; j < 5; ++j) w[a].w[i][j] = (float)(K[a][i][j] / ks[a]);
      w[a].knorm = (float)ks[a];
    }
    const int n4 = (int)(B * HW / 4);
    const int dg = (n4 + 255) / 256;
    diff_kernel<<<dim3(dg > 8192 ? 8192 : dg), dim3(256), 0, stream>>>(X, Y, tmp, n4);
    dim3 g(NBX, NBY, B), blk(256);
    conv_dense<1><<<g, blk, 0, stream>>>(tmp, nullptr, Nn,          out, w[0]);
    conv_dense<1><<<g, blk, 0, stream>>>(out, nullptr, Nn + HW,     tmp, w[1]);
    conv_dense<2><<<g, blk, 0, stream>>>(tmp, Y,       Nn + 2 * HW, out, w[2]);
  }
}

// Round 16
// 58.279 us; speedup vs baseline: 1.7602x; 1.1533x over previous
//
#include <hip/hip_runtime.h>
#include <hip/hip_fp16.h>
#include <math.h>
#include <string.h>
#include <stdint.h>

#define HH 2048
#define WW 2048
// interior tiling: 64x64 tiles, 32x32 grid
#define INBX 32
#define INBY 32
#define NINT1 ((INBX - 2) * (INBY - 2))  // 900 interior tiles per image
#define NBND 496                          // boundary 64x16 tiles per image
#define TOT1 (NINT1 + NBND)               // 1396 blocks per image

// half2 row strides (interior and boundary now share geometry widths)
#define H0 40   // buf0: 80 halfs/row (64+16)
#define H1 38   // buf1/2: 76 halfs/row
#define G0 40
#define G1 38

struct W3 {
  float wA[17][5]; float wC[17][5]; float wB[17];
  float knA, knB, knC;
  unsigned uA[17], uC[17], uA8b, uC8b;   // packed half2 weight pairs
};
struct Wts { float w[17][5]; float knorm; };   // fallback path

// angle index a: 0 -> -10deg, 1 -> 0deg, 2 -> +10deg
__host__ __device__ constexpr int js_fn(int a, int i) {
  return (a == 1) ? 2
       : (a == 2) ? ((i < 3) ? 0 : (i < 9) ? 1 : (i < 14) ? 2 : 3)
                  : ((i < 3) ? 3 : (i < 8) ? 2 : (i < 14) ? 1 : 0);
}
__host__ __device__ constexpr int nt_fn(int a, int i) {
  return (a == 1) ? 1 : (i == 8) ? 3 : 2;
}

__device__ __forceinline__ float fastrcp(float x) {
#if __has_builtin(__builtin_amdgcn_rcpf)
  return __builtin_amdgcn_rcpf(x);
#else
  return 1.0f / x;
#endif
}

__device__ __forceinline__ __half2 pack2(float a, float b) {
  return __float22half2_rn(make_float2(a, b));
}

typedef _Float16 h2vec __attribute__((ext_vector_type(2)));

// acc += win.x*wgt.x + win.y*wgt.y  (fp16 pairs, fp32 accumulate)
__device__ __forceinline__ float fdot2h(unsigned win, unsigned wgt, float acc) {
#if __has_builtin(__builtin_amdgcn_fdot2)
  return __builtin_amdgcn_fdot2(__builtin_bit_cast(h2vec, win),
                                __builtin_bit_cast(h2vec, wgt), acc, false);
#else
  const __half2 ha = __builtin_bit_cast(__half2, win);
  const __half2 hb = __builtin_bit_cast(__half2, wgt);
  const float2 fa = __half22float2(ha), fb = __half22float2(hb);
  return fmaf(fa.y, fb.y, fmaf(fa.x, fb.x, acc));
#endif
}

// ====== ONE dispatch: interior 64x64 (dot2) + boundary 64x16 blocks ======
__global__ __launch_bounds__(256, 4)
void fused_all(const float* __restrict__ Xg, const float* __restrict__ Yg,
               const float* __restrict__ Nn, float* __restrict__ Out, W3 w)
{
  __shared__ __half2 ldsh[8128];       // 32512 B -> 5 blocks/CU

  const int bid = blockIdx.x, nwg = gridDim.x;
  const int wg = ((nwg & 7) == 0) ? ((bid & 7) * (nwg >> 3) + (bid >> 3)) : bid;
  const int bz = wg / TOT1;
  const int t0 = wg - bz * TOT1;
  const int tid = threadIdx.x;
  const size_t img = (size_t)bz * ((size_t)HH * WW);

  if (t0 < NINT1) {
    // ==================== INTERIOR 64x64 (dot2 conv) ====================
    __half2* buf0h = ldsh;             // 112 x H0 = 4480
    __half2* buf1h = ldsh + 4480;      //  96 x H1 = 3648 (total 8128)
    __half2* buf2h = buf0h;            //  80 x H1 = 3040 <= 4480

    const int bx = 1 + t0 / (INBY - 2);
    const int by = 1 + t0 % (INBY - 2);   // by-fastest: vertical halo L2 hits
    const int x0 = bx * 64, y0 = by * 64;

    // ---- stage D0 = Y - X: 112 rows x 20 float4 (unchecked, in-bounds) ----
#pragma unroll
    for (int s = 0; s < 9; ++s) {
      const int idx = s * 256 + tid;
      if (idx < 112 * 20) {
        const int r = idx / 20, c4 = idx - r * 20;
        const size_t g = img + (size_t)(y0 - 24 + r) * WW + (x0 - 8 + c4 * 4);
        const float4 xv = *(const float4*)(Xg + g);
        const float4 yv = *(const float4*)(Yg + g);
        buf0h[r * H0 + c4 * 2]     = pack2(yv.x - xv.x, yv.y - xv.y);
        buf0h[r * H0 + c4 * 2 + 1] = pack2(yv.z - xv.z, yv.w - xv.w);
      }
    }
    __syncthreads();

    // ---- pass A (-10deg): D1 96 x 72 -> buf1 (dot2) ----
#pragma unroll 1
    for (int tt = tid; tt < 432; tt += 256) {      // 24 rg x 18 cg
      const int rg = tt / 18, cg = tt - rg * 18;
      const int r0 = rg * 4, c0 = cg * 4;
      float acc[4][4] = {};
#pragma unroll
      for (int rr = 0; rr < 20; ++rr) {
        const unsigned* lp = (const unsigned*)&buf0h[(r0 + rr) * H0 + (c0 >> 1)];
        const uint2 qa = *(const uint2*)(lp);
        const uint2 qb = *(const uint2*)(lp + 2);
        const unsigned a4 = lp[4];
        unsigned p[9];
        p[2] = qa.y;  p[4] = qb.x;  p[6] = qb.y;  p[8] = a4;
        p[3] = __builtin_amdgcn_alignbit(qb.x, qa.y, 16);
        p[5] = __builtin_amdgcn_alignbit(qb.y, qb.x, 16);
        p[7] = __builtin_amdgcn_alignbit(a4, qb.y, 16);
#pragma unroll
        for (int t = 0; t < 4; ++t) {
          const int i = rr - t;
          if (i >= 0 && i <= 16) {
            const int js = js_fn(0, i);
            if (i != 8) {
              const unsigned w2 = w.uA[i];
              const int b = js + 2;
#pragma unroll
              for (int c = 0; c < 4; ++c)
                acc[t][c] = fdot2h(p[b + c], w2, acc[t][c]);
            } else {
              const unsigned w2a = w.uA[8], w2b = w.uA8b;
#pragma unroll
              for (int c = 0; c < 4; ++c) {
                acc[t][c] = fdot2h(p[3 + c], w2a, acc[t][c]);
                acc[t][c] = fdot2h(p[5 + c], w2b, acc[t][c]);
              }
            }
          }
        }
      }
#pragma unroll
      for (int t = 0; t < 4; ++t) {
        const __half2* cp = &buf0h[(r0 + t + 8) * H0 + (c0 >> 1)];
        const float2 c01 = __half22float2(cp[2]);
        const float2 c23 = __half22float2(cp[3]);
        buf1h[(r0 + t) * H1 + (c0 >> 1)]     = pack2(c01.x - acc[t][0], c01.y - acc[t][1]);
        buf1h[(r0 + t) * H1 + (c0 >> 1) + 1] = pack2(c23.x - acc[t][2], c23.y - acc[t][3]);
      }
    }
    __syncthreads();

    // ---- pass B (0deg vertical): D2 80 x 68 -> buf2 ----
#pragma unroll 1
    for (int tt = tid; tt < 340; tt += 256) {      // 20 rg x 17 cg
      const int rg = tt / 17, cg = tt - rg * 17;
      const int r0 = rg * 4, c0 = cg * 4;
      float acc[4][4] = {};
#pragma unroll
      for (int rr = 0; rr < 20; ++rr) {
        const __half2* lp = &buf1h[(r0 + rr) * H1 + (c0 >> 1)];
        const float2 a = __half22float2(lp[1]);
        const float2 b = __half22float2(lp[2]);
        const float win[4] = {a.x, a.y, b.x, b.y};
#pragma unroll
        for (int t = 0; t < 4; ++t) {
          const int i = rr - t;
          if (i >= 0 && i <= 16) {
            const float wv = w.wB[i];
            acc[t][0] = fmaf(wv, win[0], acc[t][0]);
            acc[t][1] = fmaf(wv, win[1], acc[t][1]);
            acc[t][2] = fmaf(wv, win[2], acc[t][2]);
            acc[t][3] = fmaf(wv, win[3], acc[t][3]);
          }
        }
      }
#pragma unroll
      for (int t = 0; t < 4; ++t) {
        const __half2* cp = &buf1h[(r0 + t + 8) * H1 + (c0 >> 1)];
        const float2 ca = __half22float2(cp[1]);
        const float2 cb = __half22float2(cp[2]);
        buf2h[(r0 + t) * H1 + (c0 >> 1)]     = pack2(ca.x - acc[t][0], ca.y - acc[t][1]);
        buf2h[(r0 + t) * H1 + (c0 >> 1) + 1] = pack2(cb.x - acc[t][2], cb.y - acc[t][3]);
      }
    }
    __syncthreads();

    // ---- pass C (+10deg): out 64 x 64 (dot2), 256 tasks exactly ----
    {
      const int tg = tid >> 4, tc = tid & 15;
      const int r0 = tg * 4, c0 = tc * 4;
      float acc[4][4] = {};
#pragma unroll
      for (int rr = 0; rr < 20; ++rr) {
        const unsigned* lp = (const unsigned*)&buf2h[(r0 + rr) * H1 + (c0 >> 1)];
        const uint2 qa = *(const uint2*)(lp);
        const uint2 qb = *(const uint2*)(lp + 2);
        unsigned p[7];
        p[0] = qa.x;  p[2] = qa.y;  p[4] = qb.x;  p[6] = qb.y;
        p[1] = __builtin_amdgcn_alignbit(qa.y, qa.x, 16);
        p[3] = __builtin_amdgcn_alignbit(qb.x, qa.y, 16);
        p[5] = __builtin_amdgcn_alignbit(qb.y, qb.x, 16);
#pragma unroll
        for (int t = 0; t < 4; ++t) {
          const int i = rr - t;
          if (i >= 0 && i <= 16) {
            const int js = js_fn(2, i);
            if (i != 8) {
              const unsigned w2 = w.uC[i];
#pragma unroll
              for (int c = 0; c < 4; ++c)
                acc[t][c] = fdot2h(p[js + c], w2, acc[t][c]);
            } else {
#pragma unroll
              for (int c = 0; c < 4; ++c) {
                acc[t][c] = fdot2h(p[1 + c], w.uC[8], acc[t][c]);
                acc[t][c] = fdot2h(p[3 + c], w.uC8b, acc[t][c]);
              }
            }
          }
        }
      }
#pragma unroll
      for (int t = 0; t < 4; ++t) {
        const __half2* cp = &buf2h[(r0 + t + 8) * H1 + (c0 >> 1)];
        const float2 ca = __half22float2(cp[1]);
        const float2 cb = __half22float2(cp[2]);
        const int gy = y0 + r0 + t, gx = x0 + c0;
        const float4 yv = *(const float4*)(Yg + img + (size_t)gy * WW + gx);
        *(float4*)(Out + img + (size_t)gy * WW + gx) = make_float4(
            yv.x - ca.x + acc[t][0], yv.y - ca.y + acc[t][1],
            yv.z - cb.x + acc[t][2], yv.w - cb.y + acc[t][3]);
      }
    }
  } else {
    // ==================== BOUNDARY 64x16 (r13/r15, proven) ====================
    __half2* buf0h = ldsh;             // 64 x G0 = 2560
    __half2* buf1h = ldsh + 2560;      // 48 x G1 = 1824
    __half2* buf2h = buf0h;

    const int u = t0 - NINT1;          // 0..495 (ring of 64x64 tiling)
    int x0, y0;
    if (u < 128)      { y0 = (u >> 5) * 16;                x0 = (u & 31) * 64; }
    else if (u < 256) { const int v = u - 128;
                        y0 = 1984 + ((v >> 5) * 16);       x0 = (v & 31) * 64; }
    else              { const int v = u - 256;             // 240 side tiles
                        const int side = v & 1, row = v >> 1;  // row 0..119
                        y0 = 64 + row * 16;
                        x0 = side ? 1984 : 0; }

    const float* N0 = Nn;
    const float* N1 = Nn + (size_t)HH * WW;
    const float* N2 = Nn + 2 * (size_t)HH * WW;

#pragma unroll
    for (int s = 0; s < 5; ++s) {
      const int idx = s * 256 + tid;   // 64*20 = 1280 = 5*256 exactly
      const int r = idx / 20, c4 = idx - r * 20;
      const int gy = y0 - 24 + r;
      const int gx = x0 - 8 + c4 * 4;
      float4 v = make_float4(0.f, 0.f, 0.f, 0.f);
      if (gy >= 0 && gy < HH) {
        const float* xr = Xg + img + (size_t)gy * WW;
        const float* yr = Yg + img + (size_t)gy * WW;
        if (gx >= 0 && gx + 4 <= WW) {
          const float4 xv = *(const float4*)(xr + gx);
          const float4 yv = *(const float4*)(yr + gx);
          v = make_float4(yv.x - xv.x, yv.y - xv.y, yv.z - xv.z, yv.w - xv.w);
        } else {
          float tv[4] = {0.f, 0.f, 0.f, 0.f};
#pragma unroll
          for (int e = 0; e < 4; ++e) {
            const int gxe = gx + e;
            if (gxe >= 0 && gxe < WW) tv[e] = yr[gxe] - xr[gxe];
          }
          v = make_float4(tv[0], tv[1], tv[2], tv[3]);
        }
      }
      buf0h[r * G0 + c4 * 2]     = pack2(v.x, v.y);
      buf0h[r * G0 + c4 * 2 + 1] = pack2(v.z, v.w);
    }
    __syncthreads();

    if (tid < 216) {                    // pass A: 48 x 72, per-pixel N0
      const int rg = tid / 18, cg = tid - rg * 18;
      const int r0 = rg * 4, c0 = cg * 4;
      float acc[4][4] = {};
#pragma unroll
      for (int rr = 0; rr < 20; ++rr) {
        const __half2* lp = &buf0h[(r0 + rr) * G0 + (c0 >> 1)];
        const float2 p0 = __half22float2(lp[1]);
        const float2 p1 = __half22float2(lp[2]);
        const float2 p2 = __half22float2(lp[3]);
        const float2 p3 = __half22float2(lp[4]);
        const float win[8] = {p0.x, p0.y, p1.x, p1.y, p2.x, p2.y, p3.x, p3.y};
#pragma unroll
        for (int t = 0; t < 4; ++t) {
          const int i = rr - t;
          if (i >= 0 && i <= 16) {
            const int js = js_fn(0, i), nt = nt_fn(0, i);
#pragma unroll
            for (int jj = 0; jj < nt; ++jj) {
              const float wv = w.wA[i][js + jj];
#pragma unroll
              for (int c = 0; c < 4; ++c)
                acc[t][c] = fmaf(wv, win[c + js + jj], acc[t][c]);
            }
          }
        }
      }
#pragma unroll
      for (int t = 0; t < 4; ++t) {
        const int gy = y0 - 16 + r0 + t;
        const bool rok = (gy >= 0) && (gy < HH);
        const __half2* cp = &buf0h[(r0 + t + 8) * G0 + (c0 >> 1)];
        const float2 c01 = __half22float2(cp[2]);
        const float2 c23 = __half22float2(cp[3]);
        const float cenv[4] = {c01.x, c01.y, c23.x, c23.y};
        float d[4];
#pragma unroll
        for (int c = 0; c < 4; ++c) {
          const int gxc = x0 - 4 + c0 + c;
          const bool ok = rok && (gxc >= 0) && (gxc < WW);
          float r = 0.0f;
          if (ok) {
            const float n = N0[(size_t)gy * WW + gxc];
            r = cenv[c] - acc[t][c] * w.knA * fastrcp(n);
          }
          d[c] = r;
        }
        buf1h[(r0 + t) * G1 + (c0 >> 1)]     = pack2(d[0], d[1]);
        buf1h[(r0 + t) * G1 + (c0 >> 1) + 1] = pack2(d[2], d[3]);
      }
    }
    __syncthreads();

    if (tid < 136) {                    // pass B: 32 x 68, per-pixel N1
      const int rg = tid / 17, cg = tid - rg * 17;
      const int r0 = rg * 4, c0 = cg * 4;
      float acc[4][4] = {};
#pragma unroll
      for (int rr = 0; rr < 20; ++rr) {
        const __half2* lp = &buf1h[(r0 + rr) * G1 + (c0 >> 1)];
        const float2 a = __half22float2(lp[1]);
        const float2 b = __half22float2(lp[2]);
        const float win[4] = {a.x, a.y, b.x, b.y};
#pragma unroll
        for (int t = 0; t < 4; ++t) {
          const int i = rr - t;
          if (i >= 0 && i <= 16) {
            const float wv = w.wB[i];
            acc[t][0] = fmaf(wv, win[0], acc[t][0]);
            acc[t][1] = fmaf(wv, win[1], acc[t][1]);
            acc[t][2] = fmaf(wv, win[2], acc[t][2]);
            acc[t][3] = fmaf(wv, win[3], acc[t][3]);
          }
        }
      }
#pragma unroll
      for (int t = 0; t < 4; ++t) {
        const int gy = y0 - 8 + r0 + t;
        const bool rok = (gy >= 0) && (gy < HH);
        const __half2* cp = &buf1h[(r0 + t + 8) * G1 + (c0 >> 1)];
        const float2 ca = __half22float2(cp[1]);
        const float2 cb = __half22float2(cp[2]);
        const float cenv[4] = {ca.x, ca.y, cb.x, cb.y};
        float d[4];
#pragma unroll
        for (int c = 0; c < 4; ++c) {
          const int gxc = x0 - 2 + c0 + c;
          const bool ok = rok && (gxc >= 0) && (gxc < WW);
          float r = 0.0f;
          if (ok) {
            const float n = N1[(size_t)gy * WW + gxc];
            r = cenv[c] - acc[t][c] * w.knB * fastrcp(n);
          }
          d[c] = r;
        }
        buf2h[(r0 + t) * G1 + (c0 >> 1)]     = pack2(d[0], d[1]);
        buf2h[(r0 + t) * G1 + (c0 >> 1) + 1] = pack2(d[2], d[3]);
      }
    }
    __syncthreads();

    if (tid < 64) {                     // pass C: 16 x 64, per-pixel N2
      const int rg = tid >> 4, tc = tid & 15;
      const int r0 = rg * 4, c0 = tc * 4;
      float acc[4][4] = {};
#pragma unroll
      for (int rr = 0; rr < 20; ++rr) {
        const __half2* lp = &buf2h[(r0 + rr) * G1 + (c0 >> 1)];
        const float2 p0 = __half22float2(lp[0]);
        const float2 p1 = __half22float2(lp[1]);
        const float2 p2 = __half22float2(lp[2]);
        const float2 p3 = __half22float2(lp[3]);
        const float win[8] = {p0.x, p0.y, p1.x, p1.y, p2.x, p2.y, p3.x, p3.y};
#pragma unroll
        for (int t = 0; t < 4; ++t) {
          const int i = rr - t;
          if (i >= 0 && i <= 16) {
            const int js = js_fn(2, i), nt = nt_fn(2, i);
#pragma unroll
            for (int jj = 0; jj < nt; ++jj) {
              const float wv = w.wC[i][js + jj];
#pragma unroll
              for (int c = 0; c < 4; ++c)
                acc[t][c] = fmaf(wv, win[c + js + jj], acc[t][c]);
            }
          }
        }
      }
#pragma unroll
      for (int t = 0; t < 4; ++t) {
        const __half2* cp = &buf2h[(r0 + t + 8) * G1 + (c0 >> 1)];
        const float2 ca = __half22float2(cp[1]);
        const float2 cb = __half22float2(cp[2]);
        const int gy = y0 + r0 + t, gx = x0 + c0;
        const float4 yv = *(const float4*)(Yg + img + (size_t)gy * WW + gx);
        const float4 nv = *(const float4*)(N2 + (size_t)gy * WW + gx);
        *(float4*)(Out + img + (size_t)gy * WW + gx) = make_float4(
            yv.x - ca.x + acc[t][0] * w.knC * fastrcp(nv.x),
            yv.y - ca.y + acc[t][1] * w.knC * fastrcp(nv.y),
            yv.z - cb.x + acc[t][2] * w.knC * fastrcp(nv.z),
            yv.w - cb.y + acc[t][3] * w.knC * fastrcp(nv.w));
      }
    }
  }
}

// ===================== fallback path (r9, dense-capable, fp32) ==============
__global__ __launch_bounds__(256)
void diff_kernel(const float* __restrict__ X, const float* __restrict__ Y,
                 float* __restrict__ D, int n4)
{
  const int stride = gridDim.x * 256;
  for (int i = blockIdx.x * 256 + threadIdx.x; i < n4; i += stride) {
    const float4 x = ((const float4*)X)[i];
    const float4 y = ((const float4*)Y)[i];
    ((float4*)D)[i] = make_float4(y.x - x.x, y.y - x.y, y.z - x.z, y.w - x.w);
  }
}

template <int MODE>
__global__ __launch_bounds__(256, 3)
void conv_dense(const float* __restrict__ P0, const float* __restrict__ P1,
                const float* __restrict__ Nrm, float* __restrict__ Out, Wts wts)
{
  constexpr int DTSC = 128, DTSR = 32;
  constexpr int LSTR = 148, LCW = 36, XOFF = 8, CH = 48 * LCW;
  __shared__ float lds[48 * 148];
  const int bx = blockIdx.x, by = blockIdx.y, bz = blockIdx.z;
  const int tid = threadIdx.x;
  const int x0 = bx * DTSC, y0 = by * DTSR;
  const size_t img = (size_t)bz * ((size_t)HH * WW);
  const float* A = P0 + img;
#pragma unroll
  for (int s = 0; s < (CH + 255) / 256; ++s) {
    const int idx = s * 256 + tid;
    if (idx < CH) {
      const int r = idx / LCW, c4 = idx - r * LCW;
      const int gy = y0 - 8 + r, gx = x0 - XOFF + c4 * 4;
      float4 v = make_float4(0.f, 0.f, 0.f, 0.f);
      if (gy >= 0 && gy < HH) {
        const float* ar = A + (size_t)gy * WW;
        if (gx >= 0 && gx + 4 <= WW) v = *(const float4*)(ar + gx);
        else {
          float tv[4] = {0.f, 0.f, 0.f, 0.f};
#pragma unroll
          for (int e = 0; e < 4; ++e) {
            const int gxe = gx + e;
            if (gxe >= 0 && gxe < WW) tv[e] = ar[gxe];
          }
          v = make_float4(tv[0], tv[1], tv[2], tv[3]);
        }
      }
      *(float4*)&lds[r * LSTR + c4 * 4] = v;
    }
  }
  __syncthreads();
  const int tc = tid & 31, tg = tid >> 5, lc = tc * 4;
  float acc[4][4] = {};
#pragma unroll
  for (int rr = 0; rr < 20; ++rr) {
    const float* lp = &lds[(tg * 4 + rr) * LSTR];
    const float4 w0 = *(const float4*)(lp + 4 + lc);
    const float4 w1 = *(const float4*)(lp + 8 + lc);
    const float4 w2 = *(const float4*)(lp + 12 + lc);
    const float win[8] = {w0.z, w0.w, w1.x, w1.y, w1.z, w1.w, w2.x, w2.y};
#pragma unroll
    for (int t = 0; t < 4; ++t) {
      const int i = rr - t;
      if (i >= 0 && i <= 16) {
#pragma unroll
        for (int jj = 0; jj < 5; ++jj) {
          const float wv = wts.w[i][jj];
#pragma unroll
          for (int c = 0; c < 4; ++c)
            acc[t][c] = fmaf(wv, win[c + jj], acc[t][c]);
        }
      }
    }
  }
  float* Ob = Out + img;
  const int gx = x0 + lc;
  const float kn = wts.knorm;
#pragma unroll
  for (int t = 0; t < 4; ++t) {
    const int yo = y0 + tg * 4 + t;
    const float4 cv = *(const float4*)&lds[(tg * 4 + t + 8) * LSTR + XOFF + lc];
    const float4 nv = *(const float4*)(Nrm + (size_t)yo * WW + gx);
    const float a0 = acc[t][0] * kn * fastrcp(nv.x);
    const float a1 = acc[t][1] * kn * fastrcp(nv.y);
    const float a2 = acc[t][2] * kn * fastrcp(nv.z);
    const float a3 = acc[t][3] * kn * fastrcp(nv.w);
    float4 o;
    if (MODE == 2) {
      const float4 yv = *(const float4*)(P1 + img + (size_t)yo * WW + gx);
      o = make_float4(yv.x - cv.x + a0, yv.y - cv.y + a1,
                      yv.z - cv.z + a2, yv.w - cv.w + a3);
    } else {
      o = make_float4(cv.x - a0, cv.y - a1, cv.z - a2, cv.w - a3);
    }
    *(float4*)(Ob + (size_t)yo * WW + gx) = o;
  }
}

// ---------------- host-side replication of _build_kernels ----------------
static void rotate33(const double* src, double* dst, double ang_deg) {
  const int n = 33;
  const double t = ang_deg * 3.14159265358979323846 / 180.0;
  const double cs = cos(t), sn = sin(t);
  for (int y = 0; y < n; ++y) {
    for (int x = 0; x < n; ++x) {
      const double y0 = y - 16.0, x0 = x - 16.0;
      const double sy = cs * y0 + sn * x0 + 16.0;
      const double sx = -sn * y0 + cs * x0 + 16.0;
      const double fy = floor(sy), fx = floor(sx);
      const int y0i = (int)fy, x0i = (int)fx;
      const double wy = sy - fy, wx = sx - fx;
      double o = 0.0;
      for (int dy = 0; dy < 2; ++dy)
        for (int dx = 0; dx < 2; ++dx) {
          const int yy = y0i + dy, xx = x0i + dx;
          if (yy < 0 || yy >= n || xx < 0 || xx >= n) continue;
          const double wgt = (dy ? wy : 1.0 - wy) * (dx ? wx : 1.0 - wx);
          o += wgt * src[yy * n + xx];
        }
      dst[y * n + x] = o;
    }
  }
}

static void build_K(float K[3][17][5]) {
  const double angs[3] = {-10.0, 0.0, 10.0};
  double base[33 * 33], rot[33 * 33];
  for (int i = 0; i < 33 * 33; ++i) base[i] = 0.0;
  for (int y = 0; y < 33; ++y) base[y * 33 + 16] = 1.0;
  for (int a = 0; a < 3; ++a) {
    if (a == 1) memcpy(rot, base, sizeof(rot));
    else        rotate33(base, rot, angs[a]);
    double k17[17][17];
    for (int y = 0; y < 17; ++y)
      for (int x = 0; x < 17; ++x) k17[y][x] = rot[(y + 8) * 33 + (x + 8)];
    int r = 0, c = 0;
    for (int y = 0; y < 17; ++y) { bool nz = false; for (int x = 0; x < 17; ++x) if (k17[y][x] != 0.0) nz = true; r += nz; }
    for (int x = 0; x < 17; ++x) { bool nz = false; for (int y = 0; y < 17; ++y) if (k17[y][x] != 0.0) nz = true; c += nz; }
    r = r / 2 * 2; c = c / 2 * 2;
    const int kh = r + 1, kw = c + 1;
    for (int y = 0; y < 17; ++y)
      for (int x = 0; x < 5; ++x) K[a][y][x] = 0.0f;
    if (kh <= 17 && kw <= 5) {
      const int oh = (17 - kh) / 2, ow = (5 - kw) / 2;
      for (int y = 0; y < kh; ++y)
        for (int x = 0; x < kw; ++x)
          K[a][oh + y][ow + x] = (float)k17[8 - r / 2 + y][8 - c / 2 + x];
    }
  }
}

static int pick_mode(int a, const float K[17][5]) {
  for (int i = 0; i < 17; ++i) {
    const int js = js_fn(a, i), nt = nt_fn(a, i);
    for (int j = 0; j < 5; ++j)
      if ((j < js || j >= js + nt) && K[i][j] != 0.0f) return 1;
  }
  return 0;
}

// host float -> half bits (rte)
static unsigned short f2h(float f) {
  union { float f; uint32_t u; } v; v.f = f;
  const uint32_t u = v.u;
  const uint32_t s = (u >> 16) & 0x8000u;
  const int32_t  e = (int32_t)((u >> 23) & 0xffu) - 127 + 15;
  const uint32_t m = u & 0x7fffffu;
  if ((u & 0x7fffffffu) == 0) return (unsigned short)s;
  if (e >= 31) return (unsigned short)(s | 0x7bffu);
  if (e <= 0)  return (unsigned short)s;
  uint32_t h = s | ((uint32_t)e << 10) | (m >> 13);
  const uint32_t rem = m & 0x1fffu;
  if (rem > 0x1000u || (rem == 0x1000u && (h & 1u))) h++;
  return (unsigned short)h;
}
static unsigned pack_h2f(float a, float b) {
  return (unsigned)f2h(a) | ((unsigned)f2h(b) << 16);
}

extern "C" void kernel_launch(void* const* d_in, const int* in_sizes, int n_in,
                              void* d_out, int out_size, void* d_ws, size_t ws_size,
                              hipStream_t stream) {
  const float* X  = (const float*)d_in[0];
  const float* Y  = (const float*)d_in[1];
  const float* Nn = (const float*)d_in[3];
  float* out = (float*)d_out;
  float* tmp = (float*)d_ws;
  const size_t HW = (size_t)HH * WW;
  const int B = in_sizes[0] / (int)HW;   // 2

  float K[3][17][5];
  build_K(K);
  double ks[3];
  for (int a = 0; a < 3; ++a) {
    ks[a] = 0.0;
    for (int i = 0; i < 17; ++i)
      for (int j = 0; j < 5; ++j) ks[a] += K[a][i][j];
  }
  const int dense = pick_mode(0, K[0]) | pick_mode(1, K[1]) | pick_mode(2, K[2]);

  if (!dense) {
    W3 w;
    for (int i = 0; i < 17; ++i)
      for (int j = 0; j < 5; ++j) {
        w.wA[i][j] = (float)(K[0][i][j] / ks[0]);
        w.wC[i][j] = (float)(K[2][i][j] / ks[2]);
      }
    for (int i = 0; i < 17; ++i) w.wB[i] = (float)(K[1][i][2] / ks[1]);
    w.knA = (float)ks[0]; w.knB = (float)ks[1]; w.knC = (float)ks[2];
    for (int i = 0; i < 17; ++i) {
      const int ja = js_fn(0, i);
      const int jc = js_fn(2, i);
      w.uA[i] = pack_h2f(w.wA[i][ja], w.wA[i][ja + 1]);
      w.uC[i] = pack_h2f(w.wC[i][jc], w.wC[i][jc + 1]);
    }
    w.uA8b = pack_h2f(w.wA[8][js_fn(0, 8) + 2], 0.0f);
    w.uC8b = pack_h2f(w.wC[8][js_fn(2, 8) + 2], 0.0f);

    fused_all<<<dim3(TOT1 * B), dim3(256), 0, stream>>>(X, Y, Nn, out, w);
  } else {
    Wts w[3];
    for (int a = 0; a < 3; ++a) {
      for (int i = 0; i < 17; ++i)
        for (int j = 0; j < 5; ++j) w[a].w[i][j] = (float)(K[a][i][j] / ks[a]);
      w[a].knorm = (float)ks[a];
    }
    const int n4 = (int)(B * HW / 4);
    const int dg = (n4 + 255) / 256;
    diff_kernel<<<dim3(dg > 8192 ? 8192 : dg), dim3(256), 0, stream>>>(X, Y, tmp, n4);
    dim3 g(16, 64, B), blk(256);
    conv_dense<1><<<g, blk, 0, stream>>>(tmp, nullptr, Nn,          out, w[0]);
    conv_dense<1><<<g, blk, 0, stream>>>(out, nullptr, Nn + HW,     tmp, w[1]);
    conv_dense<2><<<g, blk, 0, stream>>>(tmp, Y,       Nn + 2 * HW, out, w[2]);
  }
}

// Round 17
// 55.539 us; speedup vs baseline: 1.8470x; 1.0493x over previous
//
#include <hip/hip_runtime.h>
#include <hip/hip_fp16.h>
#include <math.h>
#include <string.h>
#include <stdint.h>

#define HH 2048
#define WW 2048
// interior tiling: 64x64 tiles, 32x32 grid
#define INBX 32
#define INBY 32
#define NINT1 ((INBX - 2) * (INBY - 2))  // 900 interior tiles per image
#define NBND 496                          // boundary 64x16 tiles per image
#define TOT1 (NINT1 + NBND)               // 1396 blocks per image

// interior strides (h2 units): H0 padded 42 so 4-row stride (168 dw) !== 0 mod 32
#define H0 42   // buf0: 80 halfs used, 84 alloc
#define H1 36   // buf1/2: 68 halfs used, 72 alloc
// boundary strides (unchanged, proven)
#define G0 40
#define G1 38

struct W3 {
  float wA[17][5]; float wC[17][5]; float wB[17];
  float knA, knB, knC;
  unsigned uA[17], uC[17], uA8b, uC8b;   // packed half2 weight pairs
};
struct Wts { float w[17][5]; float knorm; };   // fallback path

// angle index a: 0 -> -10deg, 1 -> 0deg, 2 -> +10deg
__host__ __device__ constexpr int js_fn(int a, int i) {
  return (a == 1) ? 2
       : (a == 2) ? ((i < 3) ? 0 : (i < 9) ? 1 : (i < 14) ? 2 : 3)
                  : ((i < 3) ? 3 : (i < 8) ? 2 : (i < 14) ? 1 : 0);
}
__host__ __device__ constexpr int nt_fn(int a, int i) {
  return (a == 1) ? 1 : (i == 8) ? 3 : 2;
}

__device__ __forceinline__ float fastrcp(float x) {
#if __has_builtin(__builtin_amdgcn_rcpf)
  return __builtin_amdgcn_rcpf(x);
#else
  return 1.0f / x;
#endif
}

__device__ __forceinline__ __half2 pack2(float a, float b) {
  return __float22half2_rn(make_float2(a, b));
}

typedef _Float16 h2vec __attribute__((ext_vector_type(2)));

// acc += win.x*wgt.x + win.y*wgt.y  (fp16 pairs, fp32 accumulate)
__device__ __forceinline__ float fdot2h(unsigned win, unsigned wgt, float acc) {
#if __has_builtin(__builtin_amdgcn_fdot2)
  return __builtin_amdgcn_fdot2(__builtin_bit_cast(h2vec, win),
                                __builtin_bit_cast(h2vec, wgt), acc, false);
#else
  const __half2 ha = __builtin_bit_cast(__half2, win);
  const __half2 hb = __builtin_bit_cast(__half2, wgt);
  const float2 fa = __half22float2(ha), fb = __half22float2(hb);
  return fmaf(fa.y, fb.y, fmaf(fa.x, fb.x, acc));
#endif
}

// ====== ONE dispatch: interior 64x64 (dot2) + boundary 64x16 blocks ======
// Geometry (interior, tile at x0,y0):
//  buf0 (D0): 112 rows (gy = y0-24+r) x 80 halfs (gx = x0-8+h), stride H0
//  buf1 (D1):  96 rows (gy = y0-16+r) x 68 halfs (gx = x0-2+h), stride H1
//  buf2 (D2):  80 rows (gy = y0-8+r)  x 68 halfs (gx = x0-2+h), stride H1, = buf0
__global__ __launch_bounds__(256, 4)
void fused_all(const float* __restrict__ Xg, const float* __restrict__ Yg,
               const float* __restrict__ Nn, float* __restrict__ Out, W3 w)
{
  __shared__ __half2 ldsh[8160];       // 32640 B -> 5 blocks/CU

  const int bid = blockIdx.x, nwg = gridDim.x;
  const int wg = ((nwg & 7) == 0) ? ((bid & 7) * (nwg >> 3) + (bid >> 3)) : bid;
  const int bz = wg / TOT1;
  const int t0 = wg - bz * TOT1;
  const int tid = threadIdx.x;
  const size_t img = (size_t)bz * ((size_t)HH * WW);

  if (t0 < NINT1) {
    // ==================== INTERIOR 64x64 (dot2 conv) ====================
    __half2* buf0h = ldsh;             // 112 x 42 = 4704
    __half2* buf1h = ldsh + 4704;      //  96 x 36 = 3456 (total 8160)
    __half2* buf2h = buf0h;            //  80 x 36 = 2880 <= 4704

    const int bx = 1 + t0 / (INBY - 2);
    const int by = 1 + t0 % (INBY - 2);   // by-fastest: vertical halo L2 hits
    const int x0 = bx * 64, y0 = by * 64;

    // ---- stage D0 = Y - X: 112 rows x 20 float4 (unchecked, in-bounds) ----
#pragma unroll
    for (int s = 0; s < 9; ++s) {
      const int idx = s * 256 + tid;
      if (idx < 112 * 20) {
        const int r = idx / 20, c4 = idx - r * 20;
        const size_t g = img + (size_t)(y0 - 24 + r) * WW + (x0 - 8 + c4 * 4);
        const float4 xv = *(const float4*)(Xg + g);
        const float4 yv = *(const float4*)(Yg + g);
        buf0h[r * H0 + c4 * 2]     = pack2(yv.x - xv.x, yv.y - xv.y);
        buf0h[r * H0 + c4 * 2 + 1] = pack2(yv.z - xv.z, yv.w - xv.w);
      }
    }
    __syncthreads();

    // ---- pass A (-10deg): D1 96 x 68 -> buf1 ----
    // out half h = c0+cc (gx = x0-2+h); window pair start s = cc+js at
    // buf0 half c0+4+s; dwords q0..q3 = lp[2..5]; cen at buf0 half c0+6+cc.
#pragma unroll 1
    for (int tt = tid; tt < 408; tt += 256) {      // 24 rg x 17 cg
      const int rg = tt / 17, cg = tt - rg * 17;
      const int r0 = rg * 4, c0 = cg * 4;
      float acc[4][4] = {};
#pragma unroll
      for (int rr = 0; rr < 20; ++rr) {
        const unsigned* lp = (const unsigned*)&buf0h[(r0 + rr) * H0 + (c0 >> 1)];
        const uint2 qa = *(const uint2*)(lp + 2);
        const uint2 qb = *(const uint2*)(lp + 4);
        unsigned p[7];
        p[0] = qa.x;  p[2] = qa.y;  p[4] = qb.x;  p[6] = qb.y;
        p[1] = __builtin_amdgcn_alignbit(qa.y, qa.x, 16);
        p[3] = __builtin_amdgcn_alignbit(qb.x, qa.y, 16);
        p[5] = __builtin_amdgcn_alignbit(qb.y, qb.x, 16);
#pragma unroll
        for (int t = 0; t < 4; ++t) {
          const int i = rr - t;
          if (i >= 0 && i <= 16) {
            const int js = js_fn(0, i);
            if (i != 8) {
              const unsigned w2 = w.uA[i];
#pragma unroll
              for (int c = 0; c < 4; ++c)
                acc[t][c] = fdot2h(p[js + c], w2, acc[t][c]);
            } else {
              const unsigned w2a = w.uA[8], w2b = w.uA8b;   // js=1
#pragma unroll
              for (int c = 0; c < 4; ++c) {
                acc[t][c] = fdot2h(p[1 + c], w2a, acc[t][c]);
                acc[t][c] = fdot2h(p[3 + c], w2b, acc[t][c]);
              }
            }
          }
        }
      }
#pragma unroll
      for (int t = 0; t < 4; ++t) {
        const unsigned* cp = (const unsigned*)&buf0h[(r0 + t + 8) * H0 + (c0 >> 1)];
        const float2 c01 = __half22float2(__builtin_bit_cast(__half2, cp[3]));
        const float2 c23 = __half22float2(__builtin_bit_cast(__half2, cp[4]));
        buf1h[(r0 + t) * H1 + (c0 >> 1)]     = pack2(c01.x - acc[t][0], c01.y - acc[t][1]);
        buf1h[(r0 + t) * H1 + (c0 >> 1) + 1] = pack2(c23.x - acc[t][2], c23.y - acc[t][3]);
      }
    }
    __syncthreads();

    // ---- pass B (0deg vertical): D2 80 x 68 -> buf2 (same col mapping) ----
#pragma unroll 1
    for (int tt = tid; tt < 340; tt += 256) {      // 20 rg x 17 cg
      const int rg = tt / 17, cg = tt - rg * 17;
      const int r0 = rg * 4, c0 = cg * 4;
      float acc[4][4] = {};
#pragma unroll
      for (int rr = 0; rr < 20; ++rr) {
        const __half2* lp = &buf1h[(r0 + rr) * H1 + (c0 >> 1)];
        const float2 a = __half22float2(lp[0]);
        const float2 b = __half22float2(lp[1]);
        const float win[4] = {a.x, a.y, b.x, b.y};
#pragma unroll
        for (int t = 0; t < 4; ++t) {
          const int i = rr - t;
          if (i >= 0 && i <= 16) {
            const float wv = w.wB[i];
            acc[t][0] = fmaf(wv, win[0], acc[t][0]);
            acc[t][1] = fmaf(wv, win[1], acc[t][1]);
            acc[t][2] = fmaf(wv, win[2], acc[t][2]);
            acc[t][3] = fmaf(wv, win[3], acc[t][3]);
          }
        }
      }
#pragma unroll
      for (int t = 0; t < 4; ++t) {
        const __half2* cp = &buf1h[(r0 + t + 8) * H1 + (c0 >> 1)];
        const float2 ca = __half22float2(cp[0]);
        const float2 cb = __half22float2(cp[1]);
        buf2h[(r0 + t) * H1 + (c0 >> 1)]     = pack2(ca.x - acc[t][0], ca.y - acc[t][1]);
        buf2h[(r0 + t) * H1 + (c0 >> 1) + 1] = pack2(cb.x - acc[t][2], cb.y - acc[t][3]);
      }
    }
    __syncthreads();

    // ---- pass C (+10deg): out 64 x 64, 256 tasks exactly ----
    // out col x0+c0+cc; window pair start s = cc+js at D2 half c0+s;
    // dwords q0..q3 = lp[0..3]; cen at D2 half c0+2+cc -> cp[1], cp[2].
    {
      const int tg = tid >> 4, tc = tid & 15;
      const int r0 = tg * 4, c0 = tc * 4;
      float acc[4][4] = {};
#pragma unroll
      for (int rr = 0; rr < 20; ++rr) {
        const unsigned* lp = (const unsigned*)&buf2h[(r0 + rr) * H1 + (c0 >> 1)];
        const uint2 qa = *(const uint2*)(lp);
        const uint2 qb = *(const uint2*)(lp + 2);
        unsigned p[7];
        p[0] = qa.x;  p[2] = qa.y;  p[4] = qb.x;  p[6] = qb.y;
        p[1] = __builtin_amdgcn_alignbit(qa.y, qa.x, 16);
        p[3] = __builtin_amdgcn_alignbit(qb.x, qa.y, 16);
        p[5] = __builtin_amdgcn_alignbit(qb.y, qb.x, 16);
#pragma unroll
        for (int t = 0; t < 4; ++t) {
          const int i = rr - t;
          if (i >= 0 && i <= 16) {
            const int js = js_fn(2, i);
            if (i != 8) {
              const unsigned w2 = w.uC[i];
#pragma unroll
              for (int c = 0; c < 4; ++c)
                acc[t][c] = fdot2h(p[js + c], w2, acc[t][c]);
            } else {                          // js=1
#pragma unroll
              for (int c = 0; c < 4; ++c) {
                acc[t][c] = fdot2h(p[1 + c], w.uC[8], acc[t][c]);
                acc[t][c] = fdot2h(p[3 + c], w.uC8b, acc[t][c]);
              }
            }
          }
        }
      }
#pragma unroll
      for (int t = 0; t < 4; ++t) {
        const __half2* cp = &buf2h[(r0 + t + 8) * H1 + (c0 >> 1)];
        const float2 ca = __half22float2(cp[1]);
        const float2 cb = __half22float2(cp[2]);
        const int gy = y0 + r0 + t, gx = x0 + c0;
        const float4 yv = *(const float4*)(Yg + img + (size_t)gy * WW + gx);
        *(float4*)(Out + img + (size_t)gy * WW + gx) = make_float4(
            yv.x - ca.x + acc[t][0], yv.y - ca.y + acc[t][1],
            yv.z - cb.x + acc[t][2], yv.w - cb.y + acc[t][3]);
      }
    }
  } else {
    // ==================== BOUNDARY 64x16 (r13/r15, proven) ====================
    __half2* buf0h = ldsh;             // 64 x G0 = 2560
    __half2* buf1h = ldsh + 2560;      // 48 x G1 = 1824
    __half2* buf2h = buf0h;

    const int u = t0 - NINT1;          // 0..495 (ring of 64x64 tiling)
    int x0, y0;
    if (u < 128)      { y0 = (u >> 5) * 16;                x0 = (u & 31) * 64; }
    else if (u < 256) { const int v = u - 128;
                        y0 = 1984 + ((v >> 5) * 16);       x0 = (v & 31) * 64; }
    else              { const int v = u - 256;             // 240 side tiles
                        const int side = v & 1, row = v >> 1;  // row 0..119
                        y0 = 64 + row * 16;
                        x0 = side ? 1984 : 0; }

    const float* N0 = Nn;
    const float* N1 = Nn + (size_t)HH * WW;
    const float* N2 = Nn + 2 * (size_t)HH * WW;

#pragma unroll
    for (int s = 0; s < 5; ++s) {
      const int idx = s * 256 + tid;   // 64*20 = 1280 = 5*256 exactly
      const int r = idx / 20, c4 = idx - r * 20;
      const int gy = y0 - 24 + r;
      const int gx = x0 - 8 + c4 * 4;
      float4 v = make_float4(0.f, 0.f, 0.f, 0.f);
      if (gy >= 0 && gy < HH) {
        const float* xr = Xg + img + (size_t)gy * WW;
        const float* yr = Yg + img + (size_t)gy * WW;
        if (gx >= 0 && gx + 4 <= WW) {
          const float4 xv = *(const float4*)(xr + gx);
          const float4 yv = *(const float4*)(yr + gx);
          v = make_float4(yv.x - xv.x, yv.y - xv.y, yv.z - xv.z, yv.w - xv.w);
        } else {
          float tv[4] = {0.f, 0.f, 0.f, 0.f};
#pragma unroll
          for (int e = 0; e < 4; ++e) {
            const int gxe = gx + e;
            if (gxe >= 0 && gxe < WW) tv[e] = yr[gxe] - xr[gxe];
          }
          v = make_float4(tv[0], tv[1], tv[2], tv[3]);
        }
      }
      buf0h[r * G0 + c4 * 2]     = pack2(v.x, v.y);
      buf0h[r * G0 + c4 * 2 + 1] = pack2(v.z, v.w);
    }
    __syncthreads();

    if (tid < 216) {                    // pass A: 48 x 72, per-pixel N0
      const int rg = tid / 18, cg = tid - rg * 18;
      const int r0 = rg * 4, c0 = cg * 4;
      float acc[4][4] = {};
#pragma unroll
      for (int rr = 0; rr < 20; ++rr) {
        const __half2* lp = &buf0h[(r0 + rr) * G0 + (c0 >> 1)];
        const float2 p0 = __half22float2(lp[1]);
        const float2 p1 = __half22float2(lp[2]);
        const float2 p2 = __half22float2(lp[3]);
        const float2 p3 = __half22float2(lp[4]);
        const float win[8] = {p0.x, p0.y, p1.x, p1.y, p2.x, p2.y, p3.x, p3.y};
#pragma unroll
        for (int t = 0; t < 4; ++t) {
          const int i = rr - t;
          if (i >= 0 && i <= 16) {
            const int js = js_fn(0, i), nt = nt_fn(0, i);
#pragma unroll
            for (int jj = 0; jj < nt; ++jj) {
              const float wv = w.wA[i][js + jj];
#pragma unroll
              for (int c = 0; c < 4; ++c)
                acc[t][c] = fmaf(wv, win[c + js + jj], acc[t][c]);
            }
          }
        }
      }
#pragma unroll
      for (int t = 0; t < 4; ++t) {
        const int gy = y0 - 16 + r0 + t;
        const bool rok = (gy >= 0) && (gy < HH);
        const __half2* cp = &buf0h[(r0 + t + 8) * G0 + (c0 >> 1)];
        const float2 c01 = __half22float2(cp[2]);
        const float2 c23 = __half22float2(cp[3]);
        const float cenv[4] = {c01.x, c01.y, c23.x, c23.y};
        float d[4];
#pragma unroll
        for (int c = 0; c < 4; ++c) {
          const int gxc = x0 - 4 + c0 + c;
          const bool ok = rok && (gxc >= 0) && (gxc < WW);
          float r = 0.0f;
          if (ok) {
            const float n = N0[(size_t)gy * WW + gxc];
            r = cenv[c] - acc[t][c] * w.knA * fastrcp(n);
          }
          d[c] = r;
        }
        buf1h[(r0 + t) * G1 + (c0 >> 1)]     = pack2(d[0], d[1]);
        buf1h[(r0 + t) * G1 + (c0 >> 1) + 1] = pack2(d[2], d[3]);
      }
    }
    __syncthreads();

    if (tid < 136) {                    // pass B: 32 x 68, per-pixel N1
      const int rg = tid / 17, cg = tid - rg * 17;
      const int r0 = rg * 4, c0 = cg * 4;
      float acc[4][4] = {};
#pragma unroll
      for (int rr = 0; rr < 20; ++rr) {
        const __half2* lp = &buf1h[(r0 + rr) * G1 + (c0 >> 1)];
        const float2 a = __half22float2(lp[1]);
        const float2 b = __half22float2(lp[2]);
        const float win[4] = {a.x, a.y, b.x, b.y};
#pragma unroll
        for (int t = 0; t < 4; ++t) {
          const int i = rr - t;
          if (i >= 0 && i <= 16) {
            const float wv = w.wB[i];
            acc[t][0] = fmaf(wv, win[0], acc[t][0]);
            acc[t][1] = fmaf(wv, win[1], acc[t][1]);
            acc[t][2] = fmaf(wv, win[2], acc[t][2]);
            acc[t][3] = fmaf(wv, win[3], acc[t][3]);
          }
        }
      }
#pragma unroll
      for (int t = 0; t < 4; ++t) {
        const int gy = y0 - 8 + r0 + t;
        const bool rok = (gy >= 0) && (gy < HH);
        const __half2* cp = &buf1h[(r0 + t + 8) * G1 + (c0 >> 1)];
        const float2 ca = __half22float2(cp[1]);
        const float2 cb = __half22float2(cp[2]);
        const float cenv[4] = {ca.x, ca.y, cb.x, cb.y};
        float d[4];
#pragma unroll
        for (int c = 0; c < 4; ++c) {
          const int gxc = x0 - 2 + c0 + c;
          const bool ok = rok && (gxc >= 0) && (gxc < WW);
          float r = 0.0f;
          if (ok) {
            const float n = N1[(size_t)gy * WW + gxc];
            r = cenv[c] - acc[t][c] * w.knB * fastrcp(n);
          }
          d[c] = r;
        }
        buf2h[(r0 + t) * G1 + (c0 >> 1)]     = pack2(d[0], d[1]);
        buf2h[(r0 + t) * G1 + (c0 >> 1) + 1] = pack2(d[2], d[3]);
      }
    }
    __syncthreads();

    if (tid < 64) {                     // pass C: 16 x 64, per-pixel N2
      const int rg = tid >> 4, tc = tid & 15;
      const int r0 = rg * 4, c0 = tc * 4;
      float acc[4][4] = {};
#pragma unroll
      for (int rr = 0; rr < 20; ++rr) {
        const __half2* lp = &buf2h[(r0 + rr) * G1 + (c0 >> 1)];
        const float2 p0 = __half22float2(lp[0]);
        const float2 p1 = __half22float2(lp[1]);
        const float2 p2 = __half22float2(lp[2]);
        const float2 p3 = __half22float2(lp[3]);
        const float win[8] = {p0.x, p0.y, p1.x, p1.y, p2.x, p2.y, p3.x, p3.y};
#pragma unroll
        for (int t = 0; t < 4; ++t) {
          const int i = rr - t;
          if (i >= 0 && i <= 16) {
            const int js = js_fn(2, i), nt = nt_fn(2, i);
#pragma unroll
            for (int jj = 0; jj < nt; ++jj) {
              const float wv = w.wC[i][js + jj];
#pragma unroll
              for (int c = 0; c < 4; ++c)
                acc[t][c] = fmaf(wv, win[c + js + jj], acc[t][c]);
            }
          }
        }
      }
#pragma unroll
      for (int t = 0; t < 4; ++t) {
        const __half2* cp = &buf2h[(r0 + t + 8) * G1 + (c0 >> 1)];
        const float2 ca = __half22float2(cp[1]);
        const float2 cb = __half22float2(cp[2]);
        const int gy = y0 + r0 + t, gx = x0 + c0;
        const float4 yv = *(const float4*)(Yg + img + (size_t)gy * WW + gx);
        const float4 nv = *(const float4*)(N2 + (size_t)gy * WW + gx);
        *(float4*)(Out + img + (size_t)gy * WW + gx) = make_float4(
            yv.x - ca.x + acc[t][0] * w.knC * fastrcp(nv.x),
            yv.y - ca.y + acc[t][1] * w.knC * fastrcp(nv.y),
            yv.z - cb.x + acc[t][2] * w.knC * fastrcp(nv.z),
            yv.w - cb.y + acc[t][3] * w.knC * fastrcp(nv.w));
      }
    }
  }
}

// ===================== fallback path (r9, dense-capable, fp32) ==============
__global__ __launch_bounds__(256)
void diff_kernel(const float* __restrict__ X, const float* __restrict__ Y,
                 float* __restrict__ D, int n4)
{
  const int stride = gridDim.x * 256;
  for (int i = blockIdx.x * 256 + threadIdx.x; i < n4; i += stride) {
    const float4 x = ((const float4*)X)[i];
    const float4 y = ((const float4*)Y)[i];
    ((float4*)D)[i] = make_float4(y.x - x.x, y.y - x.y, y.z - x.z, y.w - x.w);
  }
}

template <int MODE>
__global__ __launch_bounds__(256, 3)
void conv_dense(const float* __restrict__ P0, const float* __restrict__ P1,
                const float* __restrict__ Nrm, float* __restrict__ Out, Wts wts)
{
  constexpr int DTSC = 128, DTSR = 32;
  constexpr int LSTR = 148, LCW = 36, XOFF = 8, CH = 48 * LCW;
  __shared__ float lds[48 * 148];
  const int bx = blockIdx.x, by = blockIdx.y, bz = blockIdx.z;
  const int tid = threadIdx.x;
  const int x0 = bx * DTSC, y0 = by * DTSR;
  const size_t img = (size_t)bz * ((size_t)HH * WW);
  const float* A = P0 + img;
#pragma unroll
  for (int s = 0; s < (CH + 255) / 256; ++s) {
    const int idx = s * 256 + tid;
    if (idx < CH) {
      const int r = idx / LCW, c4 = idx - r * LCW;
      const int gy = y0 - 8 + r, gx = x0 - XOFF + c4 * 4;
      float4 v = make_float4(0.f, 0.f, 0.f, 0.f);
      if (gy >= 0 && gy < HH) {
        const float* ar = A + (size_t)gy * WW;
        if (gx >= 0 && gx + 4 <= WW) v = *(const float4*)(ar + gx);
        else {
          float tv[4] = {0.f, 0.f, 0.f, 0.f};
#pragma unroll
          for (int e = 0; e < 4; ++e) {
            const int gxe = gx + e;
            if (gxe >= 0 && gxe < WW) tv[e] = ar[gxe];
          }
          v = make_float4(tv[0], tv[1], tv[2], tv[3]);
        }
      }
      *(float4*)&lds[r * LSTR + c4 * 4] = v;
    }
  }
  __syncthreads();
  const int tc = tid & 31, tg = tid >> 5, lc = tc * 4;
  float acc[4][4] = {};
#pragma unroll
  for (int rr = 0; rr < 20; ++rr) {
    const float* lp = &lds[(tg * 4 + rr) * LSTR];
    const float4 w0 = *(const float4*)(lp + 4 + lc);
    const float4 w1 = *(const float4*)(lp + 8 + lc);
    const float4 w2 = *(const float4*)(lp + 12 + lc);
    const float win[8] = {w0.z, w0.w, w1.x, w1.y, w1.z, w1.w, w2.x, w2.y};
#pragma unroll
    for (int t = 0; t < 4; ++t) {
      const int i = rr - t;
      if (i >= 0 && i <= 16) {
#pragma unroll
        for (int jj = 0; jj < 5; ++jj) {
          const float wv = wts.w[i][jj];
#pragma unroll
          for (int c = 0; c < 4; ++c)
            acc[t][c] = fmaf(wv, win[c + jj], acc[t][c]);
        }
      }
    }
  }
  float* Ob = Out + img;
  const int gx = x0 + lc;
  const float kn = wts.knorm;
#pragma unroll
  for (int t = 0; t < 4; ++t) {
    const int yo = y0 + tg * 4 + t;
    const float4 cv = *(const float4*)&lds[(tg * 4 + t + 8) * LSTR + XOFF + lc];
    const float4 nv = *(const float4*)(Nrm + (size_t)yo * WW + gx);
    const float a0 = acc[t][0] * kn * fastrcp(nv.x);
    const float a1 = acc[t][1] * kn * fastrcp(nv.y);
    const float a2 = acc[t][2] * kn * fastrcp(nv.z);
    const float a3 = acc[t][3] * kn * fastrcp(nv.w);
    float4 o;
    if (MODE == 2) {
      const float4 yv = *(const float4*)(P1 + img + (size_t)yo * WW + gx);
      o = make_float4(yv.x - cv.x + a0, yv.y - cv.y + a1,
                      yv.z - cv.z + a2, yv.w - cv.w + a3);
    } else {
      o = make_float4(cv.x - a0, cv.y - a1, cv.z - a2, cv.w - a3);
    }
    *(float4*)(Ob + (size_t)yo * WW + gx) = o;
  }
}

// ---------------- host-side replication of _build_kernels ----------------
static void rotate33(const double* src, double* dst, double ang_deg) {
  const int n = 33;
  const double t = ang_deg * 3.14159265358979323846 / 180.0;
  const double cs = cos(t), sn = sin(t);
  for (int y = 0; y < n; ++y) {
    for (int x = 0; x < n; ++x) {
      const double y0 = y - 16.0, x0 = x - 16.0;
      const double sy = cs * y0 + sn * x0 + 16.0;
      const double sx = -sn * y0 + cs * x0 + 16.0;
      const double fy = floor(sy), fx = floor(sx);
      const int y0i = (int)fy, x0i = (int)fx;
      const double wy = sy - fy, wx = sx - fx;
      double o = 0.0;
      for (int dy = 0; dy < 2; ++dy)
        for (int dx = 0; dx < 2; ++dx) {
          const int yy = y0i + dy, xx = x0i + dx;
          if (yy < 0 || yy >= n || xx < 0 || xx >= n) continue;
          const double wgt = (dy ? wy : 1.0 - wy) * (dx ? wx : 1.0 - wx);
          o += wgt * src[yy * n + xx];
        }
      dst[y * n + x] = o;
    }
  }
}

static void build_K(float K[3][17][5]) {
  const double angs[3] = {-10.0, 0.0, 10.0};
  double base[33 * 33], rot[33 * 33];
  for (int i = 0; i < 33 * 33; ++i) base[i] = 0.0;
  for (int y = 0; y < 33; ++y) base[y * 33 + 16] = 1.0;
  for (int a = 0; a < 3; ++a) {
    if (a == 1) memcpy(rot, base, sizeof(rot));
    else        rotate33(base, rot, angs[a]);
    double k17[17][17];
    for (int y = 0; y < 17; ++y)
      for (int x = 0; x < 17; ++x) k17[y][x] = rot[(y + 8) * 33 + (x + 8)];
    int r = 0, c = 0;
    for (int y = 0; y < 17; ++y) { bool nz = false; for (int x = 0; x < 17; ++x) if (k17[y][x] != 0.0) nz = true; r += nz; }
    for (int x = 0; x < 17; ++x) { bool nz = false; for (int y = 0; y < 17; ++y) if (k17[y][x] != 0.0) nz = true; c += nz; }
    r = r / 2 * 2; c = c / 2 * 2;
    const int kh = r + 1, kw = c + 1;
    for (int y = 0; y < 17; ++y)
      for (int x = 0; x < 5; ++x) K[a][y][x] = 0.0f;
    if (kh <= 17 && kw <= 5) {
      const int oh = (17 - kh) / 2, ow = (5 - kw) / 2;
      for (int y = 0; y < kh; ++y)
        for (int x = 0; x < kw; ++x)
          K[a][oh + y][ow + x] = (float)k17[8 - r / 2 + y][8 - c / 2 + x];
    }
  }
}

static int pick_mode(int a, const float K[17][5]) {
  for (int i = 0; i < 17; ++i) {
    const int js = js_fn(a, i), nt = nt_fn(a, i);
    for (int j = 0; j < 5; ++j)
      if ((j < js || j >= js + nt) && K[i][j] != 0.0f) return 1;
  }
  return 0;
}

// host float -> half bits (rte)
static unsigned short f2h(float f) {
  union { float f; uint32_t u; } v; v.f = f;
  const uint32_t u = v.u;
  const uint32_t s = (u >> 16) & 0x8000u;
  const int32_t  e = (int32_t)((u >> 23) & 0xffu) - 127 + 15;
  const uint32_t m = u & 0x7fffffu;
  if ((u & 0x7fffffffu) == 0) return (unsigned short)s;
  if (e >= 31) return (unsigned short)(s | 0x7bffu);
  if (e <= 0)  return (unsigned short)s;
  uint32_t h = s | ((uint32_t)e << 10) | (m >> 13);
  const uint32_t rem = m & 0x1fffu;
  if (rem > 0x1000u || (rem == 0x1000u && (h & 1u))) h++;
  return (unsigned short)h;
}
static unsigned pack_h2f(float a, float b) {
  return (unsigned)f2h(a) | ((unsigned)f2h(b) << 16);
}

extern "C" void kernel_launch(void* const* d_in, const int* in_sizes, int n_in,
                              void* d_out, int out_size, void* d_ws, size_t ws_size,
                              hipStream_t stream) {
  const float* X  = (const float*)d_in[0];
  const float* Y  = (const float*)d_in[1];
  const float* Nn = (const float*)d_in[3];
  float* out = (float*)d_out;
  float* tmp = (float*)d_ws;
  const size_t HW = (size_t)HH * WW;
  const int B = in_sizes[0] / (int)HW;   // 2

  float K[3][17][5];
  build_K(K);
  double ks[3];
  for (int a = 0; a < 3; ++a) {
    ks[a] = 0.0;
    for (int i = 0; i < 17; ++i)
      for (int j = 0; j < 5; ++j) ks[a] += K[a][i][j];
  }
  const int dense = pick_mode(0, K[0]) | pick_mode(1, K[1]) | pick_mode(2, K[2]);

  if (!dense) {
    W3 w;
    for (int i = 0; i < 17; ++i)
      for (int j = 0; j < 5; ++j) {
        w.wA[i][j] = (float)(K[0][i][j] / ks[0]);
        w.wC[i][j] = (float)(K[2][i][j] / ks[2]);
      }
    for (int i = 0; i < 17; ++i) w.wB[i] = (float)(K[1][i][2] / ks[1]);
    w.knA = (float)ks[0]; w.knB = (float)ks[1]; w.knC = (float)ks[2];
    for (int i = 0; i < 17; ++i) {
      const int ja = js_fn(0, i);
      const int jc = js_fn(2, i);
      w.uA[i] = pack_h2f(w.wA[i][ja], w.wA[i][ja + 1]);
      w.uC[i] = pack_h2f(w.wC[i][jc], w.wC[i][jc + 1]);
    }
    w.uA8b = pack_h2f(w.wA[8][js_fn(0, 8) + 2], 0.0f);
    w.uC8b = pack_h2f(w.wC[8][js_fn(2, 8) + 2], 0.0f);

    fused_all<<<dim3(TOT1 * B), dim3(256), 0, stream>>>(X, Y, Nn, out, w);
  } else {
    Wts w[3];
    for (int a = 0; a < 3; ++a) {
      for (int i = 0; i < 17; ++i)
        for (int j = 0; j < 5; ++j) w[a].w[i][j] = (float)(K[a][i][j] / ks[a]);
      w[a].knorm = (float)ks[a];
    }
    const int n4 = (int)(B * HW / 4);
    const int dg = (n4 + 255) / 256;
    diff_kernel<<<dim3(dg > 8192 ? 8192 : dg), dim3(256), 0, stream>>>(X, Y, tmp, n4);
    dim3 g(16, 64, B), blk(256);
    conv_dense<1><<<g, blk, 0, stream>>>(tmp, nullptr, Nn,          out, w[0]);
    conv_dense<1><<<g, blk, 0, stream>>>(out, nullptr, Nn + HW,     tmp, w[1]);
    conv_dense<2><<<g, blk, 0, stream>>>(tmp, Y,       Nn + 2 * HW, out, w[2]);
  }
}